// Round 3
// baseline (4502.718 us; speedup 1.0000x reference)
//
#include <hip/hip_runtime.h>
#include <hip/hip_bf16.h>
#include <math.h>

// ---- static config (matches reference) ----
#define B_      8
#define DIMC    512
#define SEQ_    784
#define HEADS_  8
#define DH_     64
#define NTOK    (B_*SEQ_)      // 6272
#define QLD     1560           // q(512) | k(512) | v(512) | gates(24)
#define WIN_    196
#define CBS_    392
#define CST_    196
#define NC_     3
#define EPSF    1e-5f
#define FF_     2048

// ---------------- wave helpers (64-lane) ----------------
__device__ __forceinline__ float wsum(float x){
#pragma unroll
  for (int o = 32; o; o >>= 1) x += __shfl_xor(x, o, 64);
  return x;
}
__device__ __forceinline__ float wmax(float x){
#pragma unroll
  for (int o = 32; o; o >>= 1) x = fmaxf(x, __shfl_xor(x, o, 64));
  return x;
}
__device__ __forceinline__ float geluf(float x){
  return 0.5f * x * (1.0f + erff(x * 0.70710678118654752f));
}
__device__ __forceinline__ float sigmoidf_(float x){
  return 1.0f / (1.0f + expf(-x));
}

// ---------------- init: x[b,c,h,w] (f32) -> X[b,p,c] (f32) + pos ----------------
__global__ __launch_bounds__(256) void k_init(const float* __restrict__ xin,
                                              const float* __restrict__ pos,
                                              float* __restrict__ X){
  int idx = blockIdx.x * 256 + threadIdx.x;       // over NTOK*512 (exact)
  int c = idx & 511;
  int t = idx >> 9;          // b*784 + p
  int p = t % SEQ_;
  int b = t / SEQ_;
  float v = xin[((long)(b * DIMC + c)) * SEQ_ + p];
  X[idx] = v + pos[p];
}

// ---------------- final: X[b,p,c] -> out[b,c,h,w] f32 ----------------
__global__ __launch_bounds__(256) void k_final(const float* __restrict__ X,
                                               float* __restrict__ out){
  int idx = blockIdx.x * 256 + threadIdx.x;       // over B*DIMC*SEQ (exact)
  int p = idx % SEQ_;
  int t = idx / SEQ_;        // b*512 + c
  int c = t & 511;
  int b = t >> 9;
  out[idx] = X[((long)(b * SEQ_ + p)) * DIMC + c];
}

// ---------------- RMSNorm over channel dim, one block per token ----------------
__global__ __launch_bounds__(256) void k_rms(const float* __restrict__ X,
                                             const float* __restrict__ g,
                                             float* __restrict__ XR){
  int tok = blockIdx.x;
  int tid = threadIdx.x;
  const float* xr = X + (long)tok * DIMC;
  float v0 = xr[tid], v1 = xr[tid + 256];
  float ss = v0 * v0 + v1 * v1;
  ss = wsum(ss);
  __shared__ float red[4];
  if ((tid & 63) == 0) red[tid >> 6] = ss;
  __syncthreads();
  float tot = red[0] + red[1] + red[2] + red[3];
  float r = rsqrtf(tot * (1.0f / DIMC) + EPSF);
  XR[(long)tok * DIMC + tid]       = v0 * r * g[tid];
  XR[(long)tok * DIMC + tid + 256] = v1 * r * g[tid + 256];
}

// ---------------- LayerNorm over channel dim ----------------
__global__ __launch_bounds__(256) void k_ln(const float* __restrict__ X,
                                            const float* __restrict__ g,
                                            const float* __restrict__ bb,
                                            float* __restrict__ XN){
  int tok = blockIdx.x;
  int tid = threadIdx.x;
  const float* xr = X + (long)tok * DIMC;
  float v0 = xr[tid], v1 = xr[tid + 256];
  float s = v0 + v1;
  float q = v0 * v0 + v1 * v1;
  s = wsum(s); q = wsum(q);
  __shared__ float r1[4], r2[4];
  if ((tid & 63) == 0){ r1[tid >> 6] = s; r2[tid >> 6] = q; }
  __syncthreads();
  float ts = r1[0] + r1[1] + r1[2] + r1[3];
  float tq = r2[0] + r2[1] + r2[2] + r2[3];
  float mean = ts * (1.0f / DIMC);
  float var  = tq * (1.0f / DIMC) - mean * mean;
  float rinv = rsqrtf(var + EPSF);
  XN[(long)tok * DIMC + tid]       = (v0 - mean) * rinv * g[tid]       + bb[tid];
  XN[(long)tok * DIMC + tid + 256] = (v1 - mean) * rinv * g[tid + 256] + bb[tid + 256];
}

// ---------------- generic tiled GEMM: C[M,ldc] (+ccol) = act(A[M,K] @ B + bias) + res ----
// BT=false: B is [K,N] (B[k*N+n]); BT=true: B is [N,K] (B[n*K+k]). All f32.
template<bool BT, int ACT>
__global__ __launch_bounds__(256) void k_gemm(const float* __restrict__ A,
                                              const float* __restrict__ Bm,
                                              float* __restrict__ C,
                                              const float* __restrict__ bias,
                                              const float* __restrict__ res,
                                              int M, int N, int K, int ldc, int ccol){
  __shared__ float As[16][65];
  __shared__ float Bs[16][65];
  int tid = threadIdx.x;
  int bm = blockIdx.y * 64, bn = blockIdx.x * 64;
  int tx = tid & 15, ty = tid >> 4;
  float acc[4][4] = {};
  int alm = tid >> 2;           // 0..63 : row in A tile
  int alk = (tid & 3) * 4;      // k offset

  for (int k0 = 0; k0 < K; k0 += 16){
    // A tile (M multiple of 64, K multiple of 16 here)
    const float* ap = A + (long)(bm + alm) * K + k0 + alk;
    float a0 = ap[0], a1 = ap[1], a2 = ap[2], a3 = ap[3];
    As[alk + 0][alm] = a0; As[alk + 1][alm] = a1;
    As[alk + 2][alm] = a2; As[alk + 3][alm] = a3;
    if (!BT){
      int blk = tid >> 4;             // 0..15 : k row
      int bln = (tid & 15) * 4;       // 0..60 : n
      const float* bp = Bm + (long)(k0 + blk) * N + bn + bln;
      float b0 = (bn + bln + 0 < N) ? bp[0] : 0.0f;
      float b1 = (bn + bln + 1 < N) ? bp[1] : 0.0f;
      float b2 = (bn + bln + 2 < N) ? bp[2] : 0.0f;
      float b3 = (bn + bln + 3 < N) ? bp[3] : 0.0f;
      Bs[blk][bln + 0] = b0; Bs[blk][bln + 1] = b1;
      Bs[blk][bln + 2] = b2; Bs[blk][bln + 3] = b3;
    } else {
      int bln = tid >> 2;             // 0..63 : n
      int blk = (tid & 3) * 4;        // k offset
      int n = bn + bln;
      bool ok = n < N;
      const float* bp = Bm + (long)(ok ? n : 0) * K + k0 + blk;
      float b0 = ok ? bp[0] : 0.0f;
      float b1 = ok ? bp[1] : 0.0f;
      float b2 = ok ? bp[2] : 0.0f;
      float b3 = ok ? bp[3] : 0.0f;
      Bs[blk + 0][bln] = b0; Bs[blk + 1][bln] = b1;
      Bs[blk + 2][bln] = b2; Bs[blk + 3][bln] = b3;
    }
    __syncthreads();
#pragma unroll
    for (int k = 0; k < 16; k++){
      float av[4], bv[4];
#pragma unroll
      for (int ii = 0; ii < 4; ii++) av[ii] = As[k][ty * 4 + ii];
#pragma unroll
      for (int jj = 0; jj < 4; jj++) bv[jj] = Bs[k][tx * 4 + jj];
#pragma unroll
      for (int ii = 0; ii < 4; ii++)
#pragma unroll
        for (int jj = 0; jj < 4; jj++)
          acc[ii][jj] += av[ii] * bv[jj];
    }
    __syncthreads();
  }
#pragma unroll
  for (int ii = 0; ii < 4; ii++){
    long m = bm + ty * 4 + ii;
#pragma unroll
    for (int jj = 0; jj < 4; jj++){
      int n = bn + tx * 4 + jj;
      if (n < N){
        float v = acc[ii][jj];
        if (bias) v += bias[n];
        if (ACT == 1) v = geluf(v);
        long off = m * (long)ldc + ccol + n;
        if (res) v += res[off];
        C[off] = v;
      }
    }
  }
}

// ---------------- compressed-block mean pooling of K and V ----------------
// grid = B*NC, block = 512 (one thread per h*64+d)
__global__ __launch_bounds__(512) void k_cpool(const float* __restrict__ qkvg,
                                               float* __restrict__ ck,
                                               float* __restrict__ cv){
  int bj = blockIdx.x;
  int j = bj % NC_;
  int b = bj / NC_;
  int c = threadIdx.x;
  const float* base = qkvg + ((long)b * SEQ_ + (long)j * CST_) * QLD + c;
  float sk = 0.0f, sv = 0.0f;
  for (int t = 0; t < CBS_; t++){
    sk += base[512  + (long)t * QLD];
    sv += base[1024 + (long)t * QLD];
  }
  ck[bj * DIMC + c] = sk * (1.0f / CBS_);
  cv[bj * DIMC + c] = sv * (1.0f / CBS_);
}

// ---------------- fused NSA attention: one wave per (b,h,i) query row ----------------
__global__ __launch_bounds__(256) void k_attn(const float* __restrict__ qkvg,
                                              const float* __restrict__ ck,
                                              const float* __restrict__ cv,
                                              float* __restrict__ oattn){
  int wave = threadIdx.x >> 6;
  int lane = threadIdx.x & 63;
  int row  = blockIdx.x * 4 + wave;    // (b*H + h)*SEQ + i ; exact coverage
  int i  = row % SEQ_;
  int bh = row / SEQ_;
  int h  = bh % HEADS_;
  int b  = bh / HEADS_;

  __shared__ float qs_all[4][DH_];
  __shared__ float sbuf_all[4][SEQ_];
  __shared__ float pbuf_all[4][SEQ_];
  float* qs   = qs_all[wave];
  float* sbuf = sbuf_all[wave];
  float* pbuf = pbuf_all[wave];

  const float scale = 0.125f;   // 64^-0.5
  long tokoff = (long)(b * SEQ_ + i) * QLD;
  int hc = h * DH_ + lane;

  float qd = qkvg[tokoff + hc];
  qs[lane] = qd;

  // ---- compressed branch (3 blocks) ----
  const float* CKp = ck + (long)b * NC_ * DIMC + hc;
  const float* CVp = cv + (long)b * NC_ * DIMC + hc;
  float sc0 = wsum(qd * CKp[0 * DIMC]) * scale;
  float sc1 = wsum(qd * CKp[1 * DIMC]) * scale;
  float sc2 = wsum(qd * CKp[2 * DIMC]) * scale;
  float m3 = fmaxf(sc0, fmaxf(sc1, sc2));
  float e0 = expf(sc0 - m3), e1 = expf(sc1 - m3), e2 = expf(sc2 - m3);
  float inv3 = 1.0f / (e0 + e1 + e2);
  float p0 = e0 * inv3, p1 = e1 * inv3, p2 = e2 * inv3;
  float outc = p0 * CVp[0 * DIMC] + p1 * CVp[1 * DIMC] + p2 * CVp[2 * DIMC];
  // OVERLAP = [[1,0],[0.5,0.5],[0,1]] ; top-1 with tie -> lower index
  float imp0 = p0 + 0.5f * p1;
  float imp1 = 0.5f * p1 + p2;
  int sel = (imp1 > imp0) ? 1 : 0;

  // ---- full fine scores sf[i, 0..783] into LDS ----
  const float* kbase = qkvg + (long)b * SEQ_ * QLD + 512 + h * DH_;
  for (int c0 = 0; c0 < SEQ_; c0 += 64){
    int t = c0 + lane;
    if (t < SEQ_){
      const float* kr = kbase + (long)t * QLD;
      float s = 0.0f;
#pragma unroll 16
      for (int d = 0; d < DH_; d++) s += qs[d] * kr[d];
      sbuf[t] = s * scale;
    }
  }

  const float* vbase = qkvg + (long)b * SEQ_ * QLD + 1024 + h * DH_ + lane;

  // ---- sliding-window branch: |i-t| < 196 ----
  float outw;
  {
    int lo = i - (WIN_ - 1); if (lo < 0) lo = 0;
    int hi = i + (WIN_ - 1); if (hi > SEQ_ - 1) hi = SEQ_ - 1;
    float m = -3.4e38f;
    for (int t = lo + lane; t <= hi; t += 64) m = fmaxf(m, sbuf[t]);
    m = wmax(m);
    float l = 0.0f;
    for (int t = lo + lane; t <= hi; t += 64){
      float p = expf(sbuf[t] - m);
      pbuf[t] = p;
      l += p;
    }
    l = wsum(l);
    float acc = 0.0f;
#pragma unroll 4
    for (int t = lo; t <= hi; t++) acc += pbuf[t] * vbase[(long)t * QLD];
    outw = acc / l;
  }

  // ---- selection branch: tokens [sel*392, sel*392+392) ----
  float outs;
  {
    int lo = sel * 392;
    int hi = lo + 391;
    float m = -3.4e38f;
    for (int t = lo + lane; t <= hi; t += 64) m = fmaxf(m, sbuf[t]);
    m = wmax(m);
    float l = 0.0f;
    for (int t = lo + lane; t <= hi; t += 64){
      float p = expf(sbuf[t] - m);
      pbuf[t] = p;
      l += p;
    }
    l = wsum(l);
    float acc = 0.0f;
#pragma unroll 4
    for (int t = lo; t <= hi; t++) acc += pbuf[t] * vbase[(long)t * QLD];
    outs = acc / l;
  }

  // ---- gates + combine ----
  const float* grow = qkvg + tokoff + 1536 + h * 3;
  float g0 = sigmoidf_(grow[0]);
  float g1 = sigmoidf_(grow[1]);
  float g2 = sigmoidf_(grow[2]);
  oattn[(long)(b * SEQ_ + i) * DIMC + hc] = g0 * outc + g1 * outs + g2 * outw;
}

// ---------------- host launcher ----------------
extern "C" void kernel_launch(void* const* d_in, const int* in_sizes, int n_in,
                              void* d_out, int out_size, void* d_ws, size_t ws_size,
                              hipStream_t stream){
  const float* xin  = (const float*)d_in[0];
  const float* pos  = (const float*)d_in[1];
  const float* angm = (const float*)d_in[2];
  const float* Wq   = (const float*)d_in[3];
  const float* Wk   = (const float*)d_in[4];
  const float* Wv   = (const float*)d_in[5];
  const float* Wo   = (const float*)d_in[6];
  const float* Wg   = (const float*)d_in[7];
  const float* fng  = (const float*)d_in[8];
  const float* fnb  = (const float*)d_in[9];
  const float* fw1  = (const float*)d_in[10];
  const float* fb1  = (const float*)d_in[11];
  const float* fw2  = (const float*)d_in[12];
  const float* fb2  = (const float*)d_in[13];

  float* X   = (float*)d_ws;                       // [NTOK,512]
  float* XR  = X  + (long)NTOK * DIMC;             // [NTOK,512] (xr / xn)
  float* OA  = XR + (long)NTOK * DIMC;             // [NTOK,512] attention out
  float* BUF = OA + (long)NTOK * DIMC;             // [NTOK,2048] (qkvg @1560 / h1 @2048)
  float* CK  = BUF + (long)NTOK * FF_;             // [B,3,512]
  float* CV  = CK  + (long)B_ * NC_ * DIMC;        // [B,3,512]

  k_init<<<12544, 256, 0, stream>>>(xin, pos, X);

  for (int l = 0; l < 2; l++){
    long wOff  = (long)l * DIMC * DIMC;      // 512*512
    long wgOff = (long)l * DIMC * 24;
    long fwOff = (long)l * FF_ * DIMC;       // 2048*512

    k_rms<<<NTOK, 256, 0, stream>>>(X, angm + (long)l * DIMC, XR);

    dim3 g512(512 / 64, NTOK / 64);
    dim3 g24(1, NTOK / 64);
    dim3 g2048(FF_ / 64, NTOK / 64);

    k_gemm<false, 0><<<g512, 256, 0, stream>>>(XR, Wq + wOff, BUF, nullptr, nullptr,
                                               NTOK, 512, 512, QLD, 0);
    k_gemm<false, 0><<<g512, 256, 0, stream>>>(XR, Wk + wOff, BUF, nullptr, nullptr,
                                               NTOK, 512, 512, QLD, 512);
    k_gemm<false, 0><<<g512, 256, 0, stream>>>(XR, Wv + wOff, BUF, nullptr, nullptr,
                                               NTOK, 512, 512, QLD, 1024);
    k_gemm<false, 0><<<g24, 256, 0, stream>>>(XR, Wg + wgOff, BUF, nullptr, nullptr,
                                              NTOK, 24, 512, QLD, 1536);

    k_cpool<<<B_ * NC_, 512, 0, stream>>>(BUF, CK, CV);
    k_attn<<<(B_ * HEADS_ * SEQ_) / 4, 256, 0, stream>>>(BUF, CK, CV, OA);

    k_gemm<false, 0><<<g512, 256, 0, stream>>>(OA, Wo + wOff, X, nullptr, X,
                                               NTOK, 512, 512, 512, 0);

    k_ln<<<NTOK, 256, 0, stream>>>(X, fng + (long)l * DIMC, fnb + (long)l * DIMC, XR);

    k_gemm<true, 1><<<g2048, 256, 0, stream>>>(XR, fw1 + fwOff, BUF, fb1 + (long)l * FF_,
                                               nullptr, NTOK, FF_, 512, FF_, 0);
    k_gemm<true, 0><<<g512, 256, 0, stream>>>(BUF, fw2 + fwOff, X, fb2 + (long)l * DIMC,
                                              X, NTOK, 512, FF_, 512, 0);
  }

  k_final<<<12544, 256, 0, stream>>>(X, (float*)d_out);
}

// Round 4
// 4107.023 us; speedup vs baseline: 1.0963x; 1.0963x over previous
//
#include <hip/hip_runtime.h>
#include <hip/hip_bf16.h>
#include <math.h>

// ---- static config (matches reference) ----
#define B_      8
#define DIMC    512
#define SEQ_    784
#define HEADS_  8
#define DH_     64
#define NTOK    (B_*SEQ_)      // 6272
#define QLD     1560           // q(512) | k(512) | v(512) | gates(24)
#define WIN_    196
#define CBS_    392
#define CST_    196
#define NC_     3
#define EPSF    1e-5f
#define FF_     2048
// attention tiling
#define TQ_     28             // queries per block (28*28 = 784)
#define CH_     56             // K/V rows per LDS chunk (56*14 = 784)
#define NCH_    14

// ---------------- wave helpers (64-lane) ----------------
__device__ __forceinline__ float wsum(float x){
#pragma unroll
  for (int o = 32; o; o >>= 1) x += __shfl_xor(x, o, 64);
  return x;
}
__device__ __forceinline__ float geluf(float x){
  return 0.5f * x * (1.0f + erff(x * 0.70710678118654752f));
}
__device__ __forceinline__ float sigmoidf_(float x){
  return 1.0f / (1.0f + __expf(-x));
}

// ---------------- init: x[b,c,h,w] (f32) -> X[b,p,c] (f32) + pos ----------------
__global__ __launch_bounds__(256) void k_init(const float* __restrict__ xin,
                                              const float* __restrict__ pos,
                                              float* __restrict__ X){
  int idx = blockIdx.x * 256 + threadIdx.x;       // over NTOK*512 (exact)
  int c = idx & 511;
  int t = idx >> 9;          // b*784 + p
  int p = t % SEQ_;
  int b = t / SEQ_;
  float v = xin[((long)(b * DIMC + c)) * SEQ_ + p];
  X[idx] = v + pos[p];
}

// ---------------- final: X[b,p,c] -> out[b,c,h,w] f32 ----------------
__global__ __launch_bounds__(256) void k_final(const float* __restrict__ X,
                                               float* __restrict__ out){
  int idx = blockIdx.x * 256 + threadIdx.x;       // over B*DIMC*SEQ (exact)
  int p = idx % SEQ_;
  int t = idx / SEQ_;        // b*512 + c
  int c = t & 511;
  int b = t >> 9;
  out[idx] = X[((long)(b * SEQ_ + p)) * DIMC + c];
}

// ---------------- RMSNorm over channel dim, one block per token ----------------
__global__ __launch_bounds__(256) void k_rms(const float* __restrict__ X,
                                             const float* __restrict__ g,
                                             float* __restrict__ XR){
  int tok = blockIdx.x;
  int tid = threadIdx.x;
  const float* xr = X + (long)tok * DIMC;
  float v0 = xr[tid], v1 = xr[tid + 256];
  float ss = v0 * v0 + v1 * v1;
  ss = wsum(ss);
  __shared__ float red[4];
  if ((tid & 63) == 0) red[tid >> 6] = ss;
  __syncthreads();
  float tot = red[0] + red[1] + red[2] + red[3];
  float r = rsqrtf(tot * (1.0f / DIMC) + EPSF);
  XR[(long)tok * DIMC + tid]       = v0 * r * g[tid];
  XR[(long)tok * DIMC + tid + 256] = v1 * r * g[tid + 256];
}

// ---------------- LayerNorm over channel dim ----------------
__global__ __launch_bounds__(256) void k_ln(const float* __restrict__ X,
                                            const float* __restrict__ g,
                                            const float* __restrict__ bb,
                                            float* __restrict__ XN){
  int tok = blockIdx.x;
  int tid = threadIdx.x;
  const float* xr = X + (long)tok * DIMC;
  float v0 = xr[tid], v1 = xr[tid + 256];
  float s = v0 + v1;
  float q = v0 * v0 + v1 * v1;
  s = wsum(s); q = wsum(q);
  __shared__ float r1[4], r2[4];
  if ((tid & 63) == 0){ r1[tid >> 6] = s; r2[tid >> 6] = q; }
  __syncthreads();
  float ts = r1[0] + r1[1] + r1[2] + r1[3];
  float tq = r2[0] + r2[1] + r2[2] + r2[3];
  float mean = ts * (1.0f / DIMC);
  float var  = tq * (1.0f / DIMC) - mean * mean;
  float rinv = rsqrtf(var + EPSF);
  XN[(long)tok * DIMC + tid]       = (v0 - mean) * rinv * g[tid]       + bb[tid];
  XN[(long)tok * DIMC + tid + 256] = (v1 - mean) * rinv * g[tid + 256] + bb[tid + 256];
}

// ---------------- generic tiled GEMM: C[M,ldc] (+ccol) = act(A[M,K] @ B + bias) + res ----
// BT=false: B is [K,N] (B[k*N+n]); BT=true: B is [N,K] (B[n*K+k]). All f32.
template<bool BT, int ACT>
__global__ __launch_bounds__(256) void k_gemm(const float* __restrict__ A,
                                              const float* __restrict__ Bm,
                                              float* __restrict__ C,
                                              const float* __restrict__ bias,
                                              const float* __restrict__ res,
                                              int M, int N, int K, int ldc, int ccol){
  __shared__ float As[16][65];
  __shared__ float Bs[16][65];
  int tid = threadIdx.x;
  int bm = blockIdx.y * 64, bn = blockIdx.x * 64;
  int tx = tid & 15, ty = tid >> 4;
  float acc[4][4] = {};
  int alm = tid >> 2;           // 0..63 : row in A tile
  int alk = (tid & 3) * 4;      // k offset

  for (int k0 = 0; k0 < K; k0 += 16){
    const float* ap = A + (long)(bm + alm) * K + k0 + alk;
    float a0 = ap[0], a1 = ap[1], a2 = ap[2], a3 = ap[3];
    As[alk + 0][alm] = a0; As[alk + 1][alm] = a1;
    As[alk + 2][alm] = a2; As[alk + 3][alm] = a3;
    if (!BT){
      int blk = tid >> 4;             // 0..15 : k row
      int bln = (tid & 15) * 4;       // 0..60 : n
      const float* bp = Bm + (long)(k0 + blk) * N + bn + bln;
      float b0 = (bn + bln + 0 < N) ? bp[0] : 0.0f;
      float b1 = (bn + bln + 1 < N) ? bp[1] : 0.0f;
      float b2 = (bn + bln + 2 < N) ? bp[2] : 0.0f;
      float b3 = (bn + bln + 3 < N) ? bp[3] : 0.0f;
      Bs[blk][bln + 0] = b0; Bs[blk][bln + 1] = b1;
      Bs[blk][bln + 2] = b2; Bs[blk][bln + 3] = b3;
    } else {
      int bln = tid >> 2;             // 0..63 : n
      int blk = (tid & 3) * 4;        // k offset
      int n = bn + bln;
      bool ok = n < N;
      const float* bp = Bm + (long)(ok ? n : 0) * K + k0 + blk;
      float b0 = ok ? bp[0] : 0.0f;
      float b1 = ok ? bp[1] : 0.0f;
      float b2 = ok ? bp[2] : 0.0f;
      float b3 = ok ? bp[3] : 0.0f;
      Bs[blk + 0][bln] = b0; Bs[blk + 1][bln] = b1;
      Bs[blk + 2][bln] = b2; Bs[blk + 3][bln] = b3;
    }
    __syncthreads();
#pragma unroll
    for (int k = 0; k < 16; k++){
      float av[4], bv[4];
#pragma unroll
      for (int ii = 0; ii < 4; ii++) av[ii] = As[k][ty * 4 + ii];
#pragma unroll
      for (int jj = 0; jj < 4; jj++) bv[jj] = Bs[k][tx * 4 + jj];
#pragma unroll
      for (int ii = 0; ii < 4; ii++)
#pragma unroll
        for (int jj = 0; jj < 4; jj++)
          acc[ii][jj] += av[ii] * bv[jj];
    }
    __syncthreads();
  }
#pragma unroll
  for (int ii = 0; ii < 4; ii++){
    long m = bm + ty * 4 + ii;
#pragma unroll
    for (int jj = 0; jj < 4; jj++){
      int n = bn + tx * 4 + jj;
      if (n < N){
        float v = acc[ii][jj];
        if (bias) v += bias[n];
        if (ACT == 1) v = geluf(v);
        long off = m * (long)ldc + ccol + n;
        if (res) v += res[off];
        C[off] = v;
      }
    }
  }
}

// ---------------- compressed-block mean pooling of K and V ----------------
__global__ __launch_bounds__(512) void k_cpool(const float* __restrict__ qkvg,
                                               float* __restrict__ ck,
                                               float* __restrict__ cv){
  int bj = blockIdx.x;
  int j = bj % NC_;
  int b = bj / NC_;
  int c = threadIdx.x;
  const float* base = qkvg + ((long)b * SEQ_ + (long)j * CST_) * QLD + c;
  float sk = 0.0f, sv = 0.0f;
  for (int t = 0; t < CBS_; t++){
    sk += base[512  + (long)t * QLD];
    sv += base[1024 + (long)t * QLD];
  }
  ck[bj * DIMC + c] = sk * (1.0f / CBS_);
  cv[bj * DIMC + c] = sv * (1.0f / CBS_);
}

// ---------------- fused NSA attention v2: Q-tiled, shared K/V through LDS ----------------
// grid = (28 q-tiles, B*H). Block = 256 (4 waves); wave w owns queries w*7..w*7+6 of the tile.
// Phase A: Q tile -> LDS. Phase B: compressed branch + gates + top-1 sel (sel = s2>s0).
// Phase C: scores for all 784 cols via 14 K-chunks in LDS; bf16 rows in LDS.
// Phase D: PV for window+selection branches via 14 V-chunks; softmax without max-subtract
//          (|s|<~2 so sum(e^s) is safe; normalization is exact).
__global__ __launch_bounds__(256) void k_attn(const float* __restrict__ qkvg,
                                              const float* __restrict__ ck,
                                              const float* __restrict__ cv,
                                              float* __restrict__ oattn){
  int tid = threadIdx.x;
  int wave = tid >> 6, lane = tid & 63;
  int i0 = blockIdx.x * TQ_;
  int bh = blockIdx.y;
  int h = bh & 7, b = bh >> 3;

  __shared__ float Qs[TQ_][64];                 // 7 KB
  __shared__ float KVs[CH_][65];                // 14.6 KB (K then V chunks)
  __shared__ __hip_bfloat16 sbuf[TQ_][SEQ_];    // 43.9 KB score rows

  const float scale = 0.125f;   // 64^-0.5
  const long headBase = (long)b * SEQ_ * QLD + h * 64;   // + {0,512,1024} for q/k/v

  // ---- Phase A: load Q tile ----
#pragma unroll
  for (int p = 0; p < 7; p++){
    int idx = tid + p * 256;
    int r = idx >> 6, d = idx & 63;
    Qs[r][d] = qkvg[headBase + (long)(i0 + r) * QLD + d];
  }
  __syncthreads();

  // ---- Phase B: compressed branch + gates + selection ----
  float outc[7], g0r[7], g1r[7], g2r[7];
  int selr[7];
  {
    const float* CKp = ck + (long)b * NC_ * DIMC + h * 64 + lane;
    const float* CVp = cv + (long)b * NC_ * DIMC + h * 64 + lane;
    float k0 = CKp[0], k1 = CKp[512], k2 = CKp[1024];
    float v0 = CVp[0], v1 = CVp[512], v2 = CVp[1024];
#pragma unroll
    for (int q = 0; q < 7; q++){
      int qg = wave * 7 + q;
      float qd = Qs[qg][lane];
      float s0 = wsum(qd * k0) * scale;
      float s1 = wsum(qd * k1) * scale;
      float s2 = wsum(qd * k2) * scale;
      float m3 = fmaxf(s0, fmaxf(s1, s2));
      float e0 = __expf(s0 - m3), e1 = __expf(s1 - m3), e2 = __expf(s2 - m3);
      float inv = 1.0f / (e0 + e1 + e2);
      outc[q] = (e0 * v0 + e1 * v1 + e2 * v2) * inv;
      // imp1 - imp0 = p2 - p0 ; softmax monotone => compare s2 vs s0
      selr[q] = (s2 > s0) ? 1 : 0;
      const float* grow = qkvg + (long)(b * SEQ_ + i0 + qg) * QLD + 1536 + h * 3;
      g0r[q] = sigmoidf_(grow[0]);
      g1r[q] = sigmoidf_(grow[1]);
      g2r[q] = sigmoidf_(grow[2]);
    }
  }

  // ---- Phase C: full score rows (bf16) via K chunks ----
  for (int ch = 0; ch < NCH_; ch++){
    int c0 = ch * CH_;
#pragma unroll
    for (int p = 0; p < 14; p++){
      int idx = tid + p * 256;
      int r = idx >> 6, d = idx & 63;
      KVs[r][d] = qkvg[headBase + 512 + (long)(c0 + r) * QLD + d];
    }
    __syncthreads();
    if (lane < CH_){
      float acc[7] = {0.f,0.f,0.f,0.f,0.f,0.f,0.f};
#pragma unroll 8
      for (int d = 0; d < 64; d++){
        float kd = KVs[lane][d];
#pragma unroll
        for (int q = 0; q < 7; q++) acc[q] += Qs[wave * 7 + q][d] * kd;
      }
#pragma unroll
      for (int q = 0; q < 7; q++)
        sbuf[wave * 7 + q][c0 + lane] = __float2bfloat16(acc[q] * scale);
    }
    __syncthreads();
  }

  // ---- Phase D: window + selection PV via V chunks ----
  float accW[7] = {0.f,0.f,0.f,0.f,0.f,0.f,0.f};
  float accS[7] = {0.f,0.f,0.f,0.f,0.f,0.f,0.f};
  float lW[7]   = {0.f,0.f,0.f,0.f,0.f,0.f,0.f};
  float lS[7]   = {0.f,0.f,0.f,0.f,0.f,0.f,0.f};
  for (int ch = 0; ch < NCH_; ch++){
    int c0 = ch * CH_;
#pragma unroll
    for (int p = 0; p < 14; p++){
      int idx = tid + p * 256;
      int r = idx >> 6, d = idx & 63;
      KVs[r][d] = qkvg[headBase + 1024 + (long)(c0 + r) * QLD + d];
    }
    __syncthreads();
    int blk = ch / 7;   // selection block covered by this chunk (392 = 7*56)
#pragma unroll
    for (int q = 0; q < 7; q++){
      int qg = wave * 7 + q;
      int iq = i0 + qg;
      const __hip_bfloat16* srow = sbuf[qg];
      // window part: rows in [iq-195, iq+195] ∩ chunk
      int lo = iq - (WIN_ - 1); if (lo < c0) lo = c0;
      int hi = iq + (WIN_ - 1); if (hi > c0 + CH_ - 1) hi = c0 + CH_ - 1;
      float aW = accW[q], sWl = lW[q];
#pragma unroll 4
      for (int r = lo; r <= hi; r++){
        float e = __expf(__bfloat162float(srow[r]));
        aW += e * KVs[r - c0][lane];
        sWl += e;
      }
      accW[q] = aW; lW[q] = sWl;
      // selection part: whole chunk iff chunk inside selected block
      if (blk == selr[q]){
        float aS = accS[q], sSl = lS[q];
#pragma unroll 4
        for (int r = 0; r < CH_; r++){
          float e = __expf(__bfloat162float(srow[c0 + r]));
          aS += e * KVs[r][lane];
          sSl += e;
        }
        accS[q] = aS; lS[q] = sSl;
      }
    }
    __syncthreads();
  }

  // ---- combine + write ----
#pragma unroll
  for (int q = 0; q < 7; q++){
    int qg = wave * 7 + q;
    float o = g0r[q] * outc[q] + g1r[q] * (accS[q] / lS[q]) + g2r[q] * (accW[q] / lW[q]);
    oattn[(long)(b * SEQ_ + i0 + qg) * DIMC + h * 64 + lane] = o;
  }
}

// ---------------- host launcher ----------------
extern "C" void kernel_launch(void* const* d_in, const int* in_sizes, int n_in,
                              void* d_out, int out_size, void* d_ws, size_t ws_size,
                              hipStream_t stream){
  const float* xin  = (const float*)d_in[0];
  const float* pos  = (const float*)d_in[1];
  const float* angm = (const float*)d_in[2];
  const float* Wq   = (const float*)d_in[3];
  const float* Wk   = (const float*)d_in[4];
  const float* Wv   = (const float*)d_in[5];
  const float* Wo   = (const float*)d_in[6];
  const float* Wg   = (const float*)d_in[7];
  const float* fng  = (const float*)d_in[8];
  const float* fnb  = (const float*)d_in[9];
  const float* fw1  = (const float*)d_in[10];
  const float* fb1  = (const float*)d_in[11];
  const float* fw2  = (const float*)d_in[12];
  const float* fb2  = (const float*)d_in[13];

  float* X   = (float*)d_ws;                       // [NTOK,512]
  float* XR  = X  + (long)NTOK * DIMC;             // [NTOK,512] (xr / xn)
  float* OA  = XR + (long)NTOK * DIMC;             // [NTOK,512] attention out
  float* BUF = OA + (long)NTOK * DIMC;             // [NTOK,2048] (qkvg @1560 / h1 @2048)
  float* CK  = BUF + (long)NTOK * FF_;             // [B,3,512]
  float* CV  = CK  + (long)B_ * NC_ * DIMC;        // [B,3,512]

  k_init<<<12544, 256, 0, stream>>>(xin, pos, X);

  for (int l = 0; l < 2; l++){
    long wOff  = (long)l * DIMC * DIMC;      // 512*512
    long wgOff = (long)l * DIMC * 24;
    long fwOff = (long)l * FF_ * DIMC;       // 2048*512

    k_rms<<<NTOK, 256, 0, stream>>>(X, angm + (long)l * DIMC, XR);

    dim3 g512(512 / 64, NTOK / 64);
    dim3 g24(1, NTOK / 64);
    dim3 g2048(FF_ / 64, NTOK / 64);

    k_gemm<false, 0><<<g512, 256, 0, stream>>>(XR, Wq + wOff, BUF, nullptr, nullptr,
                                               NTOK, 512, 512, QLD, 0);
    k_gemm<false, 0><<<g512, 256, 0, stream>>>(XR, Wk + wOff, BUF, nullptr, nullptr,
                                               NTOK, 512, 512, QLD, 512);
    k_gemm<false, 0><<<g512, 256, 0, stream>>>(XR, Wv + wOff, BUF, nullptr, nullptr,
                                               NTOK, 512, 512, QLD, 1024);
    k_gemm<false, 0><<<g24, 256, 0, stream>>>(XR, Wg + wgOff, BUF, nullptr, nullptr,
                                              NTOK, 24, 512, QLD, 1536);

    k_cpool<<<B_ * NC_, 512, 0, stream>>>(BUF, CK, CV);

    dim3 ga(SEQ_ / TQ_, B_ * HEADS_);
    k_attn<<<ga, 256, 0, stream>>>(BUF, CK, CV, OA);

    k_gemm<false, 0><<<g512, 256, 0, stream>>>(OA, Wo + wOff, X, nullptr, X,
                                               NTOK, 512, 512, 512, 0);

    k_ln<<<NTOK, 256, 0, stream>>>(X, fng + (long)l * DIMC, fnb + (long)l * DIMC, XR);

    k_gemm<true, 1><<<g2048, 256, 0, stream>>>(XR, fw1 + fwOff, BUF, fb1 + (long)l * FF_,
                                               nullptr, NTOK, FF_, 512, FF_, 0);
    k_gemm<true, 0><<<g512, 256, 0, stream>>>(BUF, fw2 + fwOff, X, fb2 + (long)l * DIMC,
                                              X, NTOK, 512, FF_, 512, 0);
  }

  k_final<<<12544, 256, 0, stream>>>(X, (float*)d_out);
}

// Round 6
// 2916.419 us; speedup vs baseline: 1.5439x; 1.4082x over previous
//
#include <hip/hip_runtime.h>
#include <hip/hip_bf16.h>
#include <math.h>

// ---- static config (matches reference) ----
#define B_      8
#define DIMC    512
#define SEQ_    784
#define HEADS_  8
#define DH_     64
#define NTOK    (B_*SEQ_)      // 6272
#define QLD     1560           // q(512) | k(512) | v(512) | gates(24)
#define WIN_    196
#define CBS_    392
#define CST_    196
#define NC_     3
#define EPSF    1e-5f
#define FF_     2048
// attention tiling
#define TQ_     28             // queries per block (28*28 = 784)
#define CH_     56             // K/V rows per LDS chunk (56*14 = 784)
#define NCH_    14

typedef __attribute__((ext_vector_type(8))) short bf16x8;
typedef __attribute__((ext_vector_type(4))) float floatx4;
typedef __attribute__((ext_vector_type(4))) unsigned int uintx4;

// ---------------- helpers ----------------
__device__ __forceinline__ float wsum(float x){
#pragma unroll
  for (int o = 32; o; o >>= 1) x += __shfl_xor(x, o, 64);
  return x;
}
__device__ __forceinline__ float geluf(float x){
  return 0.5f * x * (1.0f + erff(x * 0.70710678118654752f));
}
__device__ __forceinline__ float sigmoidf_(float x){
  return 1.0f / (1.0f + __expf(-x));
}

// ---------------- init: x[b,c,h,w] (f32) -> X[b,p,c] (f32) + pos ----------------
__global__ __launch_bounds__(256) void k_init(const float* __restrict__ xin,
                                              const float* __restrict__ pos,
                                              float* __restrict__ X){
  int idx = blockIdx.x * 256 + threadIdx.x;       // over NTOK*512 (exact)
  int c = idx & 511;
  int t = idx >> 9;          // b*784 + p
  int p = t % SEQ_;
  int b = t / SEQ_;
  float v = xin[((long)(b * DIMC + c)) * SEQ_ + p];
  X[idx] = v + pos[p];
}

// ---------------- final: X[b,p,c] -> out[b,c,h,w] f32 ----------------
__global__ __launch_bounds__(256) void k_final(const float* __restrict__ X,
                                               float* __restrict__ out){
  int idx = blockIdx.x * 256 + threadIdx.x;       // over B*DIMC*SEQ (exact)
  int p = idx % SEQ_;
  int t = idx / SEQ_;        // b*512 + c
  int c = t & 511;
  int b = t >> 9;
  out[idx] = X[((long)(b * SEQ_ + p)) * DIMC + c];
}

// ---------------- RMSNorm: f32 in -> bf16 out ----------------
__global__ __launch_bounds__(256) void k_rms(const float* __restrict__ X,
                                             const float* __restrict__ g,
                                             __hip_bfloat16* __restrict__ XR){
  int tok = blockIdx.x;
  int tid = threadIdx.x;
  const float* xr = X + (long)tok * DIMC;
  float v0 = xr[tid], v1 = xr[tid + 256];
  float ss = v0 * v0 + v1 * v1;
  ss = wsum(ss);
  __shared__ float red[4];
  if ((tid & 63) == 0) red[tid >> 6] = ss;
  __syncthreads();
  float tot = red[0] + red[1] + red[2] + red[3];
  float r = rsqrtf(tot * (1.0f / DIMC) + EPSF);
  XR[(long)tok * DIMC + tid]       = __float2bfloat16(v0 * r * g[tid]);
  XR[(long)tok * DIMC + tid + 256] = __float2bfloat16(v1 * r * g[tid + 256]);
}

// ---------------- LayerNorm: f32 in -> bf16 out ----------------
__global__ __launch_bounds__(256) void k_ln(const float* __restrict__ X,
                                            const float* __restrict__ g,
                                            const float* __restrict__ bb,
                                            __hip_bfloat16* __restrict__ XN){
  int tok = blockIdx.x;
  int tid = threadIdx.x;
  const float* xr = X + (long)tok * DIMC;
  float v0 = xr[tid], v1 = xr[tid + 256];
  float s = v0 + v1;
  float q = v0 * v0 + v1 * v1;
  s = wsum(s); q = wsum(q);
  __shared__ float r1[4], r2[4];
  if ((tid & 63) == 0){ r1[tid >> 6] = s; r2[tid >> 6] = q; }
  __syncthreads();
  float ts = r1[0] + r1[1] + r1[2] + r1[3];
  float tq = r2[0] + r2[1] + r2[2] + r2[3];
  float mean = ts * (1.0f / DIMC);
  float var  = tq * (1.0f / DIMC) - mean * mean;
  float rinv = rsqrtf(var + EPSF);
  XN[(long)tok * DIMC + tid]       = __float2bfloat16((v0 - mean) * rinv * g[tid]       + bb[tid]);
  XN[(long)tok * DIMC + tid + 256] = __float2bfloat16((v1 - mean) * rinv * g[tid + 256] + bb[tid + 256]);
}

// ---------------- bf16-MFMA GEMM with direct f32 weight staging ----------------
// A [M,K] bf16 row-major.  Weights Bsrc f32:
//   BT=0: Bsrc is [K][NL] (use columns bn..; transpose-staged to k-major LDS)
//   BT=1: Bsrc is [N][K]  (k-major already)
// C[m][ccol+n] = act(sum_k A[m][k]*B(k,n) + bias[n]) + res.  64x64 tile, 4 waves,
// each wave 32x32 via 2x2 mfma_f32_16x16x32_bf16.  Bs uses XOR k-octet swizzle
// keyed on (n>>2)&3 to break transpose-staging bank conflicts.
template<int BT, int OUTBF, int ACT>
__global__ __launch_bounds__(256) void k_mgemm(const __hip_bfloat16* __restrict__ A,
                                               const float* __restrict__ Bsrc,
                                               float* Cf,
                                               __hip_bfloat16* Cb,
                                               const float* __restrict__ bias,
                                               const float* res,
                                               int M, int N, int K, int NL,
                                               int ldc, int ccol){
  __shared__ __hip_bfloat16 As[64][40];   // 32 k + 8 pad
  __shared__ __hip_bfloat16 Bs[64][40];
  int tid = threadIdx.x;
  int bm = blockIdx.y * 64, bn = blockIdx.x * 64;
  int w = tid >> 6, lane = tid & 63;
  int wm = (w & 1) * 32, wn = (w >> 1) * 32;
  int quad = lane >> 4, l16 = lane & 15;

  int arow = tid >> 2, akc = (tid & 3) * 8;
  const __hip_bfloat16* ap = A + (long)(bm + arow) * K + akc;

  floatx4 acc[2][2];
#pragma unroll
  for (int i = 0; i < 2; i++)
#pragma unroll
    for (int j = 0; j < 2; j++) acc[i][j] = (floatx4)(0.0f);

  for (int k0 = 0; k0 < K; k0 += 32){
    *(uintx4*)&As[arow][akc] = *(const uintx4*)(ap + k0);
    if (BT){
      // B [N][K]: n = tid>>2, kc = (tid&3)*8 ; two float4 loads, cvt, one 16B store
      int n = tid >> 2, kc = (tid & 3) * 8;
      bool ok = (bn + n) < N;
      const float* bp = Bsrc + (long)(ok ? bn + n : 0) * K + k0 + kc;
      float f[8];
#pragma unroll
      for (int j = 0; j < 8; j++) f[j] = ok ? bp[j] : 0.0f;
      __hip_bfloat16 tmp[8];
#pragma unroll
      for (int j = 0; j < 8; j++) tmp[j] = __float2bfloat16(f[j]);
      int kcs = kc ^ (((n >> 2) & 3) * 8);
      *(uintx4*)&Bs[n][kcs] = *(uintx4*)tmp;
    } else {
      // B [K][NL]: transpose-stage. kk = tid>>4 (16 k rows/pass, 2 passes), n4 = (tid&15)*4
      int kk = tid >> 4, n4 = (tid & 15) * 4;
#pragma unroll
      for (int pp = 0; pp < 2; pp++){
        int k = kk + pp * 16;
        const float* bp = Bsrc + (long)(k0 + k) * NL + bn + n4;
#pragma unroll
        for (int j = 0; j < 4; j++){
          int n = n4 + j;
          float v = (bn + n < N) ? bp[j] : 0.0f;
          Bs[n][k ^ (((n >> 2) & 3) * 8)] = __float2bfloat16(v);
        }
      }
    }
    __syncthreads();
    int n0 = wn + l16, n1 = wn + 16 + l16;
    bf16x8 a0 = *(bf16x8*)&As[wm + l16][quad * 8];
    bf16x8 a1 = *(bf16x8*)&As[wm + 16 + l16][quad * 8];
    bf16x8 b0 = *(bf16x8*)&Bs[n0][(quad * 8) ^ (((n0 >> 2) & 3) * 8)];
    bf16x8 b1 = *(bf16x8*)&Bs[n1][(quad * 8) ^ (((n1 >> 2) & 3) * 8)];
    acc[0][0] = __builtin_amdgcn_mfma_f32_16x16x32_bf16(a0, b0, acc[0][0], 0, 0, 0);
    acc[0][1] = __builtin_amdgcn_mfma_f32_16x16x32_bf16(a0, b1, acc[0][1], 0, 0, 0);
    acc[1][0] = __builtin_amdgcn_mfma_f32_16x16x32_bf16(a1, b0, acc[1][0], 0, 0, 0);
    acc[1][1] = __builtin_amdgcn_mfma_f32_16x16x32_bf16(a1, b1, acc[1][1], 0, 0, 0);
    __syncthreads();
  }
  // epilogue: D[row][col]: col = lane&15 (within 16-tile), row = quad*4 + reg
#pragma unroll
  for (int tm = 0; tm < 2; tm++){
#pragma unroll
    for (int tn = 0; tn < 2; tn++){
      int ncol = bn + wn + tn * 16 + l16;
      if (ncol >= N) continue;
#pragma unroll
      for (int reg = 0; reg < 4; reg++){
        long mrow = bm + wm + tm * 16 + quad * 4 + reg;
        float v = acc[tm][tn][reg];
        if (bias) v += bias[ncol];
        if (ACT == 1) v = geluf(v);
        long off = mrow * (long)ldc + ccol + ncol;
        if (res) v += res[off];
        if (OUTBF) Cb[off] = __float2bfloat16(v);
        else       Cf[off] = v;
      }
    }
  }
}

// ---------------- compressed-block mean pooling of K and V (bf16 in, f32 out) ----------
__global__ __launch_bounds__(512) void k_cpool(const __hip_bfloat16* __restrict__ qkvg,
                                               float* __restrict__ ck,
                                               float* __restrict__ cv){
  int bj = blockIdx.x;
  int j = bj % NC_;
  int b = bj / NC_;
  int c = threadIdx.x;
  const __hip_bfloat16* base = qkvg + ((long)b * SEQ_ + (long)j * CST_) * QLD + c;
  float sk = 0.0f, sv = 0.0f;
  for (int t = 0; t < CBS_; t++){
    sk += __bfloat162float(base[512  + (long)t * QLD]);
    sv += __bfloat162float(base[1024 + (long)t * QLD]);
  }
  ck[bj * DIMC + c] = sk * (1.0f / CBS_);
  cv[bj * DIMC + c] = sv * (1.0f / CBS_);
}

// ---------------- fused NSA attention: Q-tiled, exp(s) cached in LDS ----------------
__global__ __launch_bounds__(256) void k_attn(const __hip_bfloat16* __restrict__ qkvg,
                                              const float* __restrict__ ck,
                                              const float* __restrict__ cv,
                                              __hip_bfloat16* __restrict__ oattn){
  int tid = threadIdx.x;
  int wave = tid >> 6, lane = tid & 63;
  int i0 = blockIdx.x * TQ_;
  int bh = blockIdx.y;
  int h = bh & 7, b = bh >> 3;

  __shared__ float Qs[TQ_][64];                 // 7 KB
  __shared__ float KVs[CH_][65];                // 14.6 KB
  __shared__ __hip_bfloat16 sbuf[TQ_][SEQ_];    // 43.9 KB : exp(score)

  const float scale = 0.125f;   // 64^-0.5
  const long headBase = (long)b * SEQ_ * QLD + h * 64;

  // ---- Phase A: load Q tile ----
#pragma unroll
  for (int p = 0; p < 7; p++){
    int idx = tid + p * 256;
    int r = idx >> 6, d = idx & 63;
    Qs[r][d] = __bfloat162float(qkvg[headBase + (long)(i0 + r) * QLD + d]);
  }
  __syncthreads();

  // ---- Phase B: compressed branch + gates + selection ----
  float outc[7], g0r[7], g1r[7], g2r[7];
  int selr[7];
  {
    const float* CKp = ck + (long)b * NC_ * DIMC + h * 64 + lane;
    const float* CVp = cv + (long)b * NC_ * DIMC + h * 64 + lane;
    float k0 = CKp[0], k1 = CKp[512], k2 = CKp[1024];
    float v0 = CVp[0], v1 = CVp[512], v2 = CVp[1024];
#pragma unroll
    for (int q = 0; q < 7; q++){
      int qg = wave * 7 + q;
      float qd = Qs[qg][lane];
      float s0 = wsum(qd * k0) * scale;
      float s1 = wsum(qd * k1) * scale;
      float s2 = wsum(qd * k2) * scale;
      float m3 = fmaxf(s0, fmaxf(s1, s2));
      float e0 = __expf(s0 - m3), e1 = __expf(s1 - m3), e2 = __expf(s2 - m3);
      float inv = 1.0f / (e0 + e1 + e2);
      outc[q] = (e0 * v0 + e1 * v1 + e2 * v2) * inv;
      selr[q] = (s2 > s0) ? 1 : 0;      // top-1: imp1>imp0 <=> p2>p0 <=> s2>s0
      const __hip_bfloat16* grow = qkvg + (long)(b * SEQ_ + i0 + qg) * QLD + 1536 + h * 3;
      g0r[q] = sigmoidf_(__bfloat162float(grow[0]));
      g1r[q] = sigmoidf_(__bfloat162float(grow[1]));
      g2r[q] = sigmoidf_(__bfloat162float(grow[2]));
    }
  }

  // ---- Phase C: exp(score) rows via K chunks ----
  for (int ch = 0; ch < NCH_; ch++){
    int c0 = ch * CH_;
#pragma unroll
    for (int p = 0; p < 14; p++){
      int idx = tid + p * 256;
      int r = idx >> 6, d = idx & 63;
      KVs[r][d] = __bfloat162float(qkvg[headBase + 512 + (long)(c0 + r) * QLD + d]);
    }
    __syncthreads();
    if (lane < CH_){
      float acc[7] = {0.f,0.f,0.f,0.f,0.f,0.f,0.f};
#pragma unroll 8
      for (int d = 0; d < 64; d++){
        float kd = KVs[lane][d];
#pragma unroll
        for (int q = 0; q < 7; q++) acc[q] += Qs[wave * 7 + q][d] * kd;
      }
#pragma unroll
      for (int q = 0; q < 7; q++)
        sbuf[wave * 7 + q][c0 + lane] = __float2bfloat16(__expf(acc[q] * scale));
    }
    __syncthreads();
  }

  // ---- Phase D: window + selection PV via V chunks (no exp — pure FMA) ----
  float accW[7] = {0.f,0.f,0.f,0.f,0.f,0.f,0.f};
  float accS[7] = {0.f,0.f,0.f,0.f,0.f,0.f,0.f};
  float lW[7]   = {0.f,0.f,0.f,0.f,0.f,0.f,0.f};
  float lS[7]   = {0.f,0.f,0.f,0.f,0.f,0.f,0.f};
  for (int ch = 0; ch < NCH_; ch++){
    int c0 = ch * CH_;
#pragma unroll
    for (int p = 0; p < 14; p++){
      int idx = tid + p * 256;
      int r = idx >> 6, d = idx & 63;
      KVs[r][d] = __bfloat162float(qkvg[headBase + 1024 + (long)(c0 + r) * QLD + d]);
    }
    __syncthreads();
    int blk = ch / 7;   // selection block covered by this chunk (392 = 7*56)
#pragma unroll
    for (int q = 0; q < 7; q++){
      int qg = wave * 7 + q;
      int iq = i0 + qg;
      const __hip_bfloat16* srow = sbuf[qg];
      int lo = iq - (WIN_ - 1); if (lo < c0) lo = c0;
      int hi = iq + (WIN_ - 1); if (hi > c0 + CH_ - 1) hi = c0 + CH_ - 1;
      float aW = accW[q], sWl = lW[q];
#pragma unroll 4
      for (int r = lo; r <= hi; r++){
        float p = __bfloat162float(srow[r]);
        aW += p * KVs[r - c0][lane];
        sWl += p;
      }
      accW[q] = aW; lW[q] = sWl;
      if (blk == selr[q]){
        float aS = accS[q], sSl = lS[q];
#pragma unroll 4
        for (int r = 0; r < CH_; r++){
          float p = __bfloat162float(srow[c0 + r]);
          aS += p * KVs[r][lane];
          sSl += p;
        }
        accS[q] = aS; lS[q] = sSl;
      }
    }
    __syncthreads();
  }

  // ---- combine + write (bf16) ----
#pragma unroll
  for (int q = 0; q < 7; q++){
    int qg = wave * 7 + q;
    float o = g0r[q] * outc[q] + g1r[q] * (accS[q] / lS[q]) + g2r[q] * (accW[q] / lW[q]);
    oattn[(long)(b * SEQ_ + i0 + qg) * DIMC + h * 64 + lane] = __float2bfloat16(o);
  }
}

// ---------------- host launcher ----------------
extern "C" void kernel_launch(void* const* d_in, const int* in_sizes, int n_in,
                              void* d_out, int out_size, void* d_ws, size_t ws_size,
                              hipStream_t stream){
  const float* xin  = (const float*)d_in[0];
  const float* pos  = (const float*)d_in[1];
  const float* angm = (const float*)d_in[2];
  const float* Wq   = (const float*)d_in[3];
  const float* Wk   = (const float*)d_in[4];
  const float* Wv   = (const float*)d_in[5];
  const float* Wo   = (const float*)d_in[6];
  const float* Wg   = (const float*)d_in[7];
  const float* fng  = (const float*)d_in[8];
  const float* fnb  = (const float*)d_in[9];
  const float* fw1  = (const float*)d_in[10];
  const float* fb1  = (const float*)d_in[11];
  const float* fw2  = (const float*)d_in[12];
  const float* fb2  = (const float*)d_in[13];

  char* cw = (char*)d_ws;
  float* X = (float*)cw;                      cw += (long)NTOK * 512 * 4;
  __hip_bfloat16* XRb = (__hip_bfloat16*)cw;  cw += (long)NTOK * 512 * 2;
  __hip_bfloat16* OAb = (__hip_bfloat16*)cw;  cw += (long)NTOK * 512 * 2;
  __hip_bfloat16* BUFb = (__hip_bfloat16*)cw; cw += (long)NTOK * QLD * 2;
  __hip_bfloat16* H1b = (__hip_bfloat16*)cw;  cw += (long)NTOK * FF_ * 2;
  float* CK = (float*)cw;                     cw += (long)B_ * NC_ * DIMC * 4;
  float* CV = (float*)cw;                     cw += (long)B_ * NC_ * DIMC * 4;

  k_init<<<12544, 256, 0, stream>>>(xin, pos, X);

  for (int l = 0; l < 2; l++){
    long wOff  = (long)l * 512 * 512;
    long wgOff = (long)l * 512 * 24;
    long f1Off = (long)l * FF_ * 512;

    k_rms<<<NTOK, 256, 0, stream>>>(X, angm + (long)l * DIMC, XRb);

    dim3 g512(8, 98), g24(1, 98), g2048(32, 98);

    // Q, K, V, G GEMMs (weights [K,N] f32, BT=0), bf16 out into packed BUFb
    k_mgemm<0, 1, 0><<<g512, 256, 0, stream>>>(XRb, Wq + wOff, nullptr, BUFb, nullptr,
                                               nullptr, NTOK, 512, 512, 512, QLD, 0);
    k_mgemm<0, 1, 0><<<g512, 256, 0, stream>>>(XRb, Wk + wOff, nullptr, BUFb, nullptr,
                                               nullptr, NTOK, 512, 512, 512, QLD, 512);
    k_mgemm<0, 1, 0><<<g512, 256, 0, stream>>>(XRb, Wv + wOff, nullptr, BUFb, nullptr,
                                               nullptr, NTOK, 512, 512, 512, QLD, 1024);
    k_mgemm<0, 1, 0><<<g24, 256, 0, stream>>>(XRb, Wg + wgOff, nullptr, BUFb, nullptr,
                                              nullptr, NTOK, 24, 512, 24, QLD, 1536);

    k_cpool<<<B_ * NC_, 512, 0, stream>>>(BUFb, CK, CV);

    dim3 ga(SEQ_ / TQ_, B_ * HEADS_);
    k_attn<<<ga, 256, 0, stream>>>(BUFb, CK, CV, OAb);

    // Wo GEMM (f32 out + residual into X)
    k_mgemm<0, 0, 0><<<g512, 256, 0, stream>>>(OAb, Wo + wOff, X, nullptr, nullptr,
                                               X, NTOK, 512, 512, 512, 512, 0);

    k_ln<<<NTOK, 256, 0, stream>>>(X, fng + (long)l * DIMC, fnb + (long)l * DIMC, XRb);

    // FF1 (weights [N,K] f32, BT=1) + GELU, bf16 out
    k_mgemm<1, 1, 1><<<g2048, 256, 0, stream>>>(XRb, fw1 + f1Off, nullptr, H1b,
                                                fb1 + (long)l * FF_, nullptr,
                                                NTOK, FF_, 512, 512, FF_, 0);
    // FF2 (weights [N,K] f32, BT=1), f32 out + residual into X
    k_mgemm<1, 0, 0><<<g512, 256, 0, stream>>>(H1b, fw2 + f1Off, X, nullptr,
                                               fb2 + (long)l * DIMC, X,
                                               NTOK, 512, FF_, FF_, 512, 0);
  }

  k_final<<<12544, 256, 0, stream>>>(X, (float*)d_out);
}

// Round 7
// 1799.067 us; speedup vs baseline: 2.5028x; 1.6211x over previous
//
#include <hip/hip_runtime.h>
#include <hip/hip_bf16.h>
#include <math.h>

// ---- static config (matches reference) ----
#define B_      8
#define DIMC    512
#define SEQ_    784
#define HEADS_  8
#define DH_     64
#define NTOK    (B_*SEQ_)      // 6272
#define QLD     1560           // q(512) | k(512) | v(512) | gates(24)
#define WIN_    196
#define CBS_    392
#define CST_    196
#define NC_     3
#define EPSF    1e-5f
#define FF_     2048
#define TQ_     28             // queries per block (28*28 = 784)

typedef __hip_bfloat16 bf16_t;
typedef __attribute__((ext_vector_type(8))) short bf16x8;
typedef __attribute__((ext_vector_type(4))) float floatx4;
typedef __attribute__((ext_vector_type(4))) unsigned int uintx4;

// ---------------- helpers ----------------
__device__ __forceinline__ float wsum(float x){
#pragma unroll
  for (int o = 32; o; o >>= 1) x += __shfl_xor(x, o, 64);
  return x;
}
__device__ __forceinline__ float geluf(float x){
  return 0.5f * x * (1.0f + erff(x * 0.70710678118654752f));
}
__device__ __forceinline__ float sigmoidf_(float x){
  return 1.0f / (1.0f + __expf(-x));
}

// ---------------- init: x[b,c,h,w] (f32) -> X[b,p,c] (f32) + pos ----------------
__global__ __launch_bounds__(256) void k_init(const float* __restrict__ xin,
                                              const float* __restrict__ pos,
                                              float* __restrict__ X){
  int idx = blockIdx.x * 256 + threadIdx.x;       // over NTOK*512 (exact)
  int c = idx & 511;
  int t = idx >> 9;          // b*784 + p
  int p = t % SEQ_;
  int b = t / SEQ_;
  float v = xin[((long)(b * DIMC + c)) * SEQ_ + p];
  X[idx] = v + pos[p];
}

// ---------------- final: X[b,p,c] -> out[b,c,h,w] f32 ----------------
__global__ __launch_bounds__(256) void k_final(const float* __restrict__ X,
                                               float* __restrict__ out){
  int idx = blockIdx.x * 256 + threadIdx.x;       // over B*DIMC*SEQ (exact)
  int p = idx % SEQ_;
  int t = idx / SEQ_;        // b*512 + c
  int c = t & 511;
  int b = t >> 9;
  out[idx] = X[((long)(b * SEQ_ + p)) * DIMC + c];
}

// ---------------- RMSNorm: f32 in -> bf16 out ----------------
__global__ __launch_bounds__(256) void k_rms(const float* __restrict__ X,
                                             const float* __restrict__ g,
                                             bf16_t* __restrict__ XR){
  int tok = blockIdx.x;
  int tid = threadIdx.x;
  const float* xr = X + (long)tok * DIMC;
  float v0 = xr[tid], v1 = xr[tid + 256];
  float ss = v0 * v0 + v1 * v1;
  ss = wsum(ss);
  __shared__ float red[4];
  if ((tid & 63) == 0) red[tid >> 6] = ss;
  __syncthreads();
  float tot = red[0] + red[1] + red[2] + red[3];
  float r = rsqrtf(tot * (1.0f / DIMC) + EPSF);
  XR[(long)tok * DIMC + tid]       = __float2bfloat16(v0 * r * g[tid]);
  XR[(long)tok * DIMC + tid + 256] = __float2bfloat16(v1 * r * g[tid + 256]);
}

// ---------------- LayerNorm: f32 in -> bf16 out ----------------
__global__ __launch_bounds__(256) void k_ln(const float* __restrict__ X,
                                            const float* __restrict__ g,
                                            const float* __restrict__ bb,
                                            bf16_t* __restrict__ XN){
  int tok = blockIdx.x;
  int tid = threadIdx.x;
  const float* xr = X + (long)tok * DIMC;
  float v0 = xr[tid], v1 = xr[tid + 256];
  float s = v0 + v1;
  float q = v0 * v0 + v1 * v1;
  s = wsum(s); q = wsum(q);
  __shared__ float r1[4], r2[4];
  if ((tid & 63) == 0){ r1[tid >> 6] = s; r2[tid >> 6] = q; }
  __syncthreads();
  float ts = r1[0] + r1[1] + r1[2] + r1[3];
  float tq = r2[0] + r2[1] + r2[2] + r2[3];
  float mean = ts * (1.0f / DIMC);
  float var  = tq * (1.0f / DIMC) - mean * mean;
  float rinv = rsqrtf(var + EPSF);
  XN[(long)tok * DIMC + tid]       = __float2bfloat16((v0 - mean) * rinv * g[tid]       + bb[tid]);
  XN[(long)tok * DIMC + tid + 256] = __float2bfloat16((v1 - mean) * rinv * g[tid + 256] + bb[tid + 256]);
}

// ---------------- bf16-MFMA GEMM with direct f32 weight staging ----------------
template<int BT, int OUTBF, int ACT>
__global__ __launch_bounds__(256) void k_mgemm(const bf16_t* __restrict__ A,
                                               const float* __restrict__ Bsrc,
                                               float* Cf,
                                               bf16_t* Cb,
                                               const float* __restrict__ bias,
                                               const float* res,
                                               int M, int N, int K, int NL,
                                               int ldc, int ccol){
  __shared__ bf16_t As[64][40];   // 32 k + 8 pad
  __shared__ bf16_t Bs[64][40];
  int tid = threadIdx.x;
  int bm = blockIdx.y * 64, bn = blockIdx.x * 64;
  int w = tid >> 6, lane = tid & 63;
  int wm = (w & 1) * 32, wn = (w >> 1) * 32;
  int quad = lane >> 4, l16 = lane & 15;

  int arow = tid >> 2, akc = (tid & 3) * 8;
  const bf16_t* ap = A + (long)(bm + arow) * K + akc;

  floatx4 acc[2][2];
#pragma unroll
  for (int i = 0; i < 2; i++)
#pragma unroll
    for (int j = 0; j < 2; j++) acc[i][j] = (floatx4)(0.0f);

  for (int k0 = 0; k0 < K; k0 += 32){
    *(uintx4*)&As[arow][akc] = *(const uintx4*)(ap + k0);
    if (BT){
      int n = tid >> 2, kc = (tid & 3) * 8;
      bool ok = (bn + n) < N;
      const float* bp = Bsrc + (long)(ok ? bn + n : 0) * K + k0 + kc;
      float f[8];
#pragma unroll
      for (int j = 0; j < 8; j++) f[j] = ok ? bp[j] : 0.0f;
      bf16_t tmp[8];
#pragma unroll
      for (int j = 0; j < 8; j++) tmp[j] = __float2bfloat16(f[j]);
      int kcs = kc ^ (((n >> 2) & 3) * 8);
      *(uintx4*)&Bs[n][kcs] = *(uintx4*)tmp;
    } else {
      int kk = tid >> 4, n4 = (tid & 15) * 4;
#pragma unroll
      for (int pp = 0; pp < 2; pp++){
        int k = kk + pp * 16;
        const float* bp = Bsrc + (long)(k0 + k) * NL + bn + n4;
#pragma unroll
        for (int j = 0; j < 4; j++){
          int n = n4 + j;
          float v = (bn + n < N) ? bp[j] : 0.0f;
          Bs[n][k ^ (((n >> 2) & 3) * 8)] = __float2bfloat16(v);
        }
      }
    }
    __syncthreads();
    int n0 = wn + l16, n1 = wn + 16 + l16;
    bf16x8 a0 = *(bf16x8*)&As[wm + l16][quad * 8];
    bf16x8 a1 = *(bf16x8*)&As[wm + 16 + l16][quad * 8];
    bf16x8 b0 = *(bf16x8*)&Bs[n0][(quad * 8) ^ (((n0 >> 2) & 3) * 8)];
    bf16x8 b1 = *(bf16x8*)&Bs[n1][(quad * 8) ^ (((n1 >> 2) & 3) * 8)];
    acc[0][0] = __builtin_amdgcn_mfma_f32_16x16x32_bf16(a0, b0, acc[0][0], 0, 0, 0);
    acc[0][1] = __builtin_amdgcn_mfma_f32_16x16x32_bf16(a0, b1, acc[0][1], 0, 0, 0);
    acc[1][0] = __builtin_amdgcn_mfma_f32_16x16x32_bf16(a1, b0, acc[1][0], 0, 0, 0);
    acc[1][1] = __builtin_amdgcn_mfma_f32_16x16x32_bf16(a1, b1, acc[1][1], 0, 0, 0);
    __syncthreads();
  }
#pragma unroll
  for (int tm = 0; tm < 2; tm++){
#pragma unroll
    for (int tn = 0; tn < 2; tn++){
      int ncol = bn + wn + tn * 16 + l16;
      if (ncol >= N) continue;
#pragma unroll
      for (int reg = 0; reg < 4; reg++){
        long mrow = bm + wm + tm * 16 + quad * 4 + reg;
        float v = acc[tm][tn][reg];
        if (bias) v += bias[ncol];
        if (ACT == 1) v = geluf(v);
        long off = mrow * (long)ldc + ccol + ncol;
        if (res) v += res[off];
        if (OUTBF) Cb[off] = __float2bfloat16(v);
        else       Cf[off] = v;
      }
    }
  }
}

// ---------------- compressed-block mean pooling of K and V (bf16 in, f32 out) ----------
__global__ __launch_bounds__(512) void k_cpool(const bf16_t* __restrict__ qkvg,
                                               float* __restrict__ ck,
                                               float* __restrict__ cv){
  int bj = blockIdx.x;
  int j = bj % NC_;
  int b = bj / NC_;
  int c = threadIdx.x;
  const bf16_t* base = qkvg + ((long)b * SEQ_ + (long)j * CST_) * QLD + c;
  float sk = 0.0f, sv = 0.0f;
  for (int t = 0; t < CBS_; t++){
    sk += __bfloat162float(base[512  + (long)t * QLD]);
    sv += __bfloat162float(base[1024 + (long)t * QLD]);
  }
  ck[bj * DIMC + c] = sk * (1.0f / CBS_);
  cv[bj * DIMC + c] = sv * (1.0f / CBS_);
}

// ---------------- fused NSA attention v3: MFMA QK^T + combined-weight MFMA PV --------
// One block per (28-query tile, b, h). 256 threads = 4 waves.
// sbuf rows padded to 808 bf16 (1616 B stride: 16B-aligned, 404 dw -> mod32=20 stagger).
// W(q,t) = exp(s)*(inWin*g2/lW + inSel*g1/lS); out = W·V + g0*outc (compressed).
__global__ __launch_bounds__(256) void k_attn(const bf16_t* __restrict__ qkvg,
                                              const float* __restrict__ ck,
                                              const float* __restrict__ cv,
                                              bf16_t* __restrict__ oattn){
  int tid = threadIdx.x;
  int w = tid >> 6, lane = tid & 63;
  int quad = lane >> 4, l16 = lane & 15;
  int i0 = blockIdx.x * TQ_;
  int bh = blockIdx.y;
  int h = bh & 7, b = bh >> 3;
  const float scale = 0.125f;

  __shared__ __align__(16) char smem[78864];
  bf16_t (*Qs)[72]    = (bf16_t(*)[72])(smem);            // 4608 B  (rows 28-31 zero)
  bf16_t (*Ks)[72]    = (bf16_t(*)[72])(smem + 4608);     // 9216 B  (phase C)
  bf16_t (*Vt)[168]   = (bf16_t(*)[168])(smem + 4608);    // 21504 B (phase D, same buf)
  bf16_t (*sbuf)[808] = (bf16_t(*)[808])(smem + 26112);   // 45248 B
  float  (*outc_s)[64] = (float(*)[64])(smem + 71360);    // 7168 B
  int*   sel_s = (int*)(smem + 78528);
  float* cw_s  = (float*)(smem + 78640);
  float* cs_s  = (float*)(smem + 78752);

  const long rowBase = (long)b * SEQ_ * QLD + h * 64;     // + token*QLD + {0,512,1024}

  // ---- Phase A: stage Q tile (28 rows) + zero rows 28-31 ----
  if (tid < 224){
    int q = tid >> 3, seg = tid & 7;
    uintx4 qv = *(const uintx4*)(qkvg + rowBase + (long)(i0 + q) * QLD + seg * 8);
    *(uintx4*)&Qs[q][seg * 8] = qv;
  } else {
    int u = tid - 224;
    int r = 28 + (u >> 3), seg = u & 7;
    *(uintx4*)&Qs[r][seg * 8] = (uintx4){0u, 0u, 0u, 0u};
  }
  __syncthreads();

  // ---- Phase B: compressed branch + gates + top-1 selection (wave w owns q = w*7..w*7+6)
  float g1r[7], g2r[7];
  int selr[7];
  {
    const float* CKp = ck + (long)b * NC_ * DIMC + h * 64 + lane;
    const float* CVp = cv + (long)b * NC_ * DIMC + h * 64 + lane;
    float k0 = CKp[0], k1 = CKp[512], k2 = CKp[1024];
    float v0 = CVp[0], v1 = CVp[512], v2 = CVp[1024];
#pragma unroll
    for (int qp = 0; qp < 7; qp++){
      int qg = w * 7 + qp;
      float qd = __bfloat162float(Qs[qg][lane]);
      float s0 = wsum(qd * k0) * scale;
      float s1 = wsum(qd * k1) * scale;
      float s2 = wsum(qd * k2) * scale;
      float m3 = fmaxf(s0, fmaxf(s1, s2));
      float e0 = __expf(s0 - m3), e1 = __expf(s1 - m3), e2 = __expf(s2 - m3);
      float inv = 1.0f / (e0 + e1 + e2);
      const bf16_t* grow = qkvg + (long)(b * SEQ_ + i0 + qg) * QLD + 1536 + h * 3;
      float g0 = sigmoidf_(__bfloat162float(grow[0]));
      g1r[qp] = sigmoidf_(__bfloat162float(grow[1]));
      g2r[qp] = sigmoidf_(__bfloat162float(grow[2]));
      outc_s[qg][lane] = g0 * (e0 * v0 + e1 * v1 + e2 * v2) * inv;
      selr[qp] = (s2 > s0) ? 1 : 0;   // imp1>imp0 <=> p2>p0 <=> s2>s0
      if (lane == 0) sel_s[qg] = selr[qp];
    }
  }

  // hoist Q A-fragments (chunk-invariant)
  bf16x8 a00 = *(bf16x8*)&Qs[l16][quad * 8];
  bf16x8 a01 = *(bf16x8*)&Qs[l16][32 + quad * 8];
  bf16x8 a10 = *(bf16x8*)&Qs[16 + l16][quad * 8];
  bf16x8 a11 = *(bf16x8*)&Qs[16 + l16][32 + quad * 8];

  // ---- Phase C: QK^T via MFMA, exp -> sbuf (14 chunks of 56 keys) ----
  for (int ch = 0; ch < 14; ch++){
    int c0 = ch * 56;
#pragma unroll
    for (int p = 0; p < 2; p++){
      int uu = tid + p * 256;
      int r = uu >> 3, seg = uu & 7;
      int tok = c0 + r; tok = tok > 783 ? 783 : tok;   // rows 56-63 duplicated, discarded
      uintx4 kv = *(const uintx4*)(qkvg + rowBase + (long)tok * QLD + 512 + seg * 8);
      *(uintx4*)&Ks[r][seg * 8] = kv;
    }
    __syncthreads();
    bf16x8 b0 = *(bf16x8*)&Ks[w * 16 + l16][quad * 8];
    bf16x8 b1 = *(bf16x8*)&Ks[w * 16 + l16][32 + quad * 8];
    floatx4 d0 = (floatx4)(0.0f), d1 = (floatx4)(0.0f);
    d0 = __builtin_amdgcn_mfma_f32_16x16x32_bf16(a00, b0, d0, 0, 0, 0);
    d0 = __builtin_amdgcn_mfma_f32_16x16x32_bf16(a01, b1, d0, 0, 0, 0);
    d1 = __builtin_amdgcn_mfma_f32_16x16x32_bf16(a10, b0, d1, 0, 0, 0);
    d1 = __builtin_amdgcn_mfma_f32_16x16x32_bf16(a11, b1, d1, 0, 0, 0);
    int tc = w * 16 + l16;
    if (tc < 56){
      int t = c0 + tc;
#pragma unroll
      for (int reg = 0; reg < 4; reg++){
        sbuf[quad * 4 + reg][t] = __float2bfloat16(__expf(d0[reg] * scale));
        int q2 = 16 + quad * 4 + reg;
        if (q2 < 28) sbuf[q2][t] = __float2bfloat16(__expf(d1[reg] * scale));
      }
    }
    __syncthreads();
  }

  // ---- row sums -> per-row coefficients ----
#pragma unroll
  for (int qp = 0; qp < 7; qp++){
    int q = w * 7 + qp;
    int iq = i0 + q;
    int lo = iq - 195; if (lo < 0) lo = 0;
    int hi = iq + 195; if (hi > 783) hi = 783;
    float sw = 0.0f;
    for (int t = lo + lane; t <= hi; t += 64) sw += __bfloat162float(sbuf[q][t]);
    sw = wsum(sw);
    int slo = selr[qp] * 392;
    float ss = 0.0f;
    for (int t = slo + lane; t < slo + 392; t += 64) ss += __bfloat162float(sbuf[q][t]);
    ss = wsum(ss);
    if (lane == 0){
      cw_s[q] = g2r[qp] / sw;
      cs_s[q] = g1r[qp] / ss;
    }
  }
  __syncthreads();

  // ---- build combined weight matrix W in place (zero cols 784..807) ----
  for (int q = 0; q < 28; q++){
    int iq = i0 + q;
    float cw = cw_s[q], cs = cs_s[q];
    int sl = sel_s[q];
    for (int c = tid; c < 808; c += 256){
      float wv = 0.0f;
      if (c < 784){
        float e = __bfloat162float(sbuf[q][c]);
        float coef = 0.0f;
        if (c >= iq - 195 && c <= iq + 195) coef += cw;
        if ((c >= 392 ? 1 : 0) == sl)       coef += cs;
        wv = e * coef;
      }
      sbuf[q][c] = __float2bfloat16(wv);
    }
  }
  __syncthreads();

  // ---- Phase D: out = W · V via MFMA (5 chunks of 160 tokens, V transposed-staged) ----
  floatx4 o0 = (floatx4)(0.0f), o1 = (floatx4)(0.0f);
  for (int ch = 0; ch < 5; ch++){
    int c0 = ch * 160;
#pragma unroll
    for (int p = 0; p < 5; p++){
      int u = tid + p * 256;           // 1280 units exactly
      int seg = u / 160;
      int t = u - seg * 160;
      int tok = c0 + t; tok = tok > 783 ? 783 : tok;   // W cols >=784 are zero
      uintx4 vv = *(const uintx4*)(qkvg + rowBase + (long)tok * QLD + 1024 + seg * 8);
      bf16_t tmp[8]; *(uintx4*)tmp = vv;
#pragma unroll
      for (int j = 0; j < 8; j++) Vt[seg * 8 + j][t] = tmp[j];
    }
    __syncthreads();
#pragma unroll
    for (int ks = 0; ks < 5; ks++){
      int kc = c0 + ks * 32;
      bf16x8 av0 = *(bf16x8*)&sbuf[l16][kc + quad * 8];
      bf16x8 av1 = *(bf16x8*)&sbuf[16 + l16][kc + quad * 8];  // rows 28-31 OOB-read: finite, discarded
      bf16x8 bv  = *(bf16x8*)&Vt[w * 16 + l16][ks * 32 + quad * 8];
      o0 = __builtin_amdgcn_mfma_f32_16x16x32_bf16(av0, bv, o0, 0, 0, 0);
      o1 = __builtin_amdgcn_mfma_f32_16x16x32_bf16(av1, bv, o1, 0, 0, 0);
    }
    __syncthreads();
  }

  // ---- epilogue: add compressed branch, write bf16 ----
  int d = w * 16 + l16;
#pragma unroll
  for (int reg = 0; reg < 4; reg++){
    int q = quad * 4 + reg;
    float o = o0[reg] + outc_s[q][d];
    oattn[((long)(b * SEQ_ + i0 + q)) * DIMC + h * 64 + d] = __float2bfloat16(o);
    int q2 = q + 16;
    if (q2 < 28){
      float o2 = o1[reg] + outc_s[q2][d];
      oattn[((long)(b * SEQ_ + i0 + q2)) * DIMC + h * 64 + d] = __float2bfloat16(o2);
    }
  }
}

// ---------------- host launcher ----------------
extern "C" void kernel_launch(void* const* d_in, const int* in_sizes, int n_in,
                              void* d_out, int out_size, void* d_ws, size_t ws_size,
                              hipStream_t stream){
  const float* xin  = (const float*)d_in[0];
  const float* pos  = (const float*)d_in[1];
  const float* angm = (const float*)d_in[2];
  const float* Wq   = (const float*)d_in[3];
  const float* Wk   = (const float*)d_in[4];
  const float* Wv   = (const float*)d_in[5];
  const float* Wo   = (const float*)d_in[6];
  const float* Wg   = (const float*)d_in[7];
  const float* fng  = (const float*)d_in[8];
  const float* fnb  = (const float*)d_in[9];
  const float* fw1  = (const float*)d_in[10];
  const float* fb1  = (const float*)d_in[11];
  const float* fw2  = (const float*)d_in[12];
  const float* fb2  = (const float*)d_in[13];

  char* cw = (char*)d_ws;
  float* X = (float*)cw;             cw += (long)NTOK * 512 * 4;
  bf16_t* XRb = (bf16_t*)cw;         cw += (long)NTOK * 512 * 2;
  bf16_t* OAb = (bf16_t*)cw;         cw += (long)NTOK * 512 * 2;
  bf16_t* BUFb = (bf16_t*)cw;        cw += (long)NTOK * QLD * 2;
  bf16_t* H1b = (bf16_t*)cw;         cw += (long)NTOK * FF_ * 2;
  float* CK = (float*)cw;            cw += (long)B_ * NC_ * DIMC * 4;
  float* CV = (float*)cw;            cw += (long)B_ * NC_ * DIMC * 4;

  k_init<<<12544, 256, 0, stream>>>(xin, pos, X);

  for (int l = 0; l < 2; l++){
    long wOff  = (long)l * 512 * 512;
    long wgOff = (long)l * 512 * 24;
    long f1Off = (long)l * FF_ * 512;

    k_rms<<<NTOK, 256, 0, stream>>>(X, angm + (long)l * DIMC, XRb);

    dim3 g512(8, 98), g24(1, 98), g2048(32, 98);

    k_mgemm<0, 1, 0><<<g512, 256, 0, stream>>>(XRb, Wq + wOff, nullptr, BUFb, nullptr,
                                               nullptr, NTOK, 512, 512, 512, QLD, 0);
    k_mgemm<0, 1, 0><<<g512, 256, 0, stream>>>(XRb, Wk + wOff, nullptr, BUFb, nullptr,
                                               nullptr, NTOK, 512, 512, 512, QLD, 512);
    k_mgemm<0, 1, 0><<<g512, 256, 0, stream>>>(XRb, Wv + wOff, nullptr, BUFb, nullptr,
                                               nullptr, NTOK, 512, 512, 512, QLD, 1024);
    k_mgemm<0, 1, 0><<<g24, 256, 0, stream>>>(XRb, Wg + wgOff, nullptr, BUFb, nullptr,
                                              nullptr, NTOK, 24, 512, 24, QLD, 1536);

    k_cpool<<<B_ * NC_, 512, 0, stream>>>(BUFb, CK, CV);

    dim3 ga(SEQ_ / TQ_, B_ * HEADS_);
    k_attn<<<ga, 256, 0, stream>>>(BUFb, CK, CV, OAb);

    k_mgemm<0, 0, 0><<<g512, 256, 0, stream>>>(OAb, Wo + wOff, X, nullptr, nullptr,
                                               X, NTOK, 512, 512, 512, 512, 0);

    k_ln<<<NTOK, 256, 0, stream>>>(X, fng + (long)l * DIMC, fnb + (long)l * DIMC, XRb);

    k_mgemm<1, 1, 1><<<g2048, 256, 0, stream>>>(XRb, fw1 + f1Off, nullptr, H1b,
                                                fb1 + (long)l * FF_, nullptr,
                                                NTOK, FF_, 512, 512, FF_, 0);
    k_mgemm<1, 0, 0><<<g512, 256, 0, stream>>>(H1b, fw2 + f1Off, X, nullptr,
                                               fb2 + (long)l * DIMC, X,
                                               NTOK, 512, FF_, FF_, 512, 0);
  }

  k_final<<<12544, 256, 0, stream>>>(X, (float*)d_out);
}

// Round 8
// 1773.490 us; speedup vs baseline: 2.5389x; 1.0144x over previous
//
#include <hip/hip_runtime.h>
#include <hip/hip_bf16.h>
#include <math.h>

// ---- static config (matches reference) ----
#define B_      8
#define DIMC    512
#define SEQ_    784
#define HEADS_  8
#define DH_     64
#define NTOK    (B_*SEQ_)      // 6272
#define QLD     1560           // q(512) | k(512) | v(512) | gates(24)
#define WIN_    196
#define CBS_    392
#define CST_    196
#define NC_     3
#define EPSF    1e-5f
#define FF_     2048
#define TQ_     28             // queries per block (28*28 = 784)
#define MT_     98             // m-tiles (6272/64)
#define MTP_    104            // m-tiles padded to 8*13 for XCD swizzle

typedef __hip_bfloat16 bf16_t;
typedef __attribute__((ext_vector_type(8))) short bf16x8;
typedef __attribute__((ext_vector_type(4))) float floatx4;
typedef __attribute__((ext_vector_type(4))) unsigned int uintx4;

// ---------------- helpers ----------------
__device__ __forceinline__ float wsum(float x){
#pragma unroll
  for (int o = 32; o; o >>= 1) x += __shfl_xor(x, o, 64);
  return x;
}
__device__ __forceinline__ float geluf(float x){
  return 0.5f * x * (1.0f + erff(x * 0.70710678118654752f));
}
__device__ __forceinline__ float sigmoidf_(float x){
  return 1.0f / (1.0f + __expf(-x));
}

// ---------------- init: x[b,c,h,w] (f32) -> X[b,p,c] (f32) + pos ----------------
__global__ __launch_bounds__(256) void k_init(const float* __restrict__ xin,
                                              const float* __restrict__ pos,
                                              float* __restrict__ X){
  int idx = blockIdx.x * 256 + threadIdx.x;       // over NTOK*512 (exact)
  int c = idx & 511;
  int t = idx >> 9;          // b*784 + p
  int p = t % SEQ_;
  int b = t / SEQ_;
  float v = xin[((long)(b * DIMC + c)) * SEQ_ + p];
  X[idx] = v + pos[p];
}

// ---------------- final: X[b,p,c] -> out[b,c,h,w] f32 ----------------
__global__ __launch_bounds__(256) void k_final(const float* __restrict__ X,
                                               float* __restrict__ out){
  int idx = blockIdx.x * 256 + threadIdx.x;       // over B*DIMC*SEQ (exact)
  int p = idx % SEQ_;
  int t = idx / SEQ_;        // b*512 + c
  int c = t & 511;
  int b = t >> 9;
  out[idx] = X[((long)(b * SEQ_ + p)) * DIMC + c];
}

// ---------------- RMSNorm: f32 in -> bf16 out ----------------
__global__ __launch_bounds__(256) void k_rms(const float* __restrict__ X,
                                             const float* __restrict__ g,
                                             bf16_t* __restrict__ XR){
  int tok = blockIdx.x;
  int tid = threadIdx.x;
  const float* xr = X + (long)tok * DIMC;
  float v0 = xr[tid], v1 = xr[tid + 256];
  float ss = v0 * v0 + v1 * v1;
  ss = wsum(ss);
  __shared__ float red[4];
  if ((tid & 63) == 0) red[tid >> 6] = ss;
  __syncthreads();
  float tot = red[0] + red[1] + red[2] + red[3];
  float r = rsqrtf(tot * (1.0f / DIMC) + EPSF);
  XR[(long)tok * DIMC + tid]       = __float2bfloat16(v0 * r * g[tid]);
  XR[(long)tok * DIMC + tid + 256] = __float2bfloat16(v1 * r * g[tid + 256]);
}

// ---------------- LayerNorm: f32 in -> bf16 out ----------------
__global__ __launch_bounds__(256) void k_ln(const float* __restrict__ X,
                                            const float* __restrict__ g,
                                            const float* __restrict__ bb,
                                            bf16_t* __restrict__ XN){
  int tok = blockIdx.x;
  int tid = threadIdx.x;
  const float* xr = X + (long)tok * DIMC;
  float v0 = xr[tid], v1 = xr[tid + 256];
  float s = v0 + v1;
  float q = v0 * v0 + v1 * v1;
  s = wsum(s); q = wsum(q);
  __shared__ float r1[4], r2[4];
  if ((tid & 63) == 0){ r1[tid >> 6] = s; r2[tid >> 6] = q; }
  __syncthreads();
  float ts = r1[0] + r1[1] + r1[2] + r1[3];
  float tq = r2[0] + r2[1] + r2[2] + r2[3];
  float mean = ts * (1.0f / DIMC);
  float var  = tq * (1.0f / DIMC) - mean * mean;
  float rinv = rsqrtf(var + EPSF);
  XN[(long)tok * DIMC + tid]       = __float2bfloat16((v0 - mean) * rinv * g[tid]       + bb[tid]);
  XN[(long)tok * DIMC + tid + 256] = __float2bfloat16((v1 - mean) * rinv * g[tid + 256] + bb[tid + 256]);
}

// ---------------- bf16-MFMA GEMM with direct f32 weight staging ----------------
// 1-D grid of nx*104 blocks, XCD-swizzled: xcd=id&7 owns a disjoint band of 13
// m-tiles across ALL n-tiles -> A fetched once per band, B once per XCD L2.
template<int BT, int OUTBF, int ACT>
__global__ __launch_bounds__(256) void k_mgemm(const bf16_t* __restrict__ A,
                                               const float* __restrict__ Bsrc,
                                               float* Cf,
                                               bf16_t* Cb,
                                               const float* __restrict__ bias,
                                               const float* res,
                                               int M, int N, int K, int NL,
                                               int ldc, int ccol){
  int id = blockIdx.x;
  int xcd = id & 7;
  int j = id >> 3;
  int nt = j / 13;
  int mt = xcd * 13 + (j - nt * 13);
  if (mt >= MT_) return;
  int bm = mt * 64, bn = nt * 64;

  __shared__ bf16_t As[64][40];   // 32 k + 8 pad
  __shared__ bf16_t Bs[64][40];
  int tid = threadIdx.x;
  int w = tid >> 6, lane = tid & 63;
  int wm = (w & 1) * 32, wn = (w >> 1) * 32;
  int quad = lane >> 4, l16 = lane & 15;

  int arow = tid >> 2, akc = (tid & 3) * 8;
  const bf16_t* ap = A + (long)(bm + arow) * K + akc;

  floatx4 acc[2][2];
#pragma unroll
  for (int i = 0; i < 2; i++)
#pragma unroll
    for (int jj = 0; jj < 2; jj++) acc[i][jj] = (floatx4)(0.0f);

  for (int k0 = 0; k0 < K; k0 += 32){
    *(uintx4*)&As[arow][akc] = *(const uintx4*)(ap + k0);
    if (BT){
      int n = tid >> 2, kc = (tid & 3) * 8;
      bool ok = (bn + n) < N;
      const float* bp = Bsrc + (long)(ok ? bn + n : 0) * K + k0 + kc;
      float f[8];
#pragma unroll
      for (int jj = 0; jj < 8; jj++) f[jj] = ok ? bp[jj] : 0.0f;
      bf16_t tmp[8];
#pragma unroll
      for (int jj = 0; jj < 8; jj++) tmp[jj] = __float2bfloat16(f[jj]);
      int kcs = kc ^ (((n >> 2) & 3) * 8);
      *(uintx4*)&Bs[n][kcs] = *(uintx4*)tmp;
    } else {
      int kk = tid >> 4, n4 = (tid & 15) * 4;
#pragma unroll
      for (int pp = 0; pp < 2; pp++){
        int k = kk + pp * 16;
        const float* bp = Bsrc + (long)(k0 + k) * NL + bn + n4;
#pragma unroll
        for (int jj = 0; jj < 4; jj++){
          int n = n4 + jj;
          float v = (bn + n < N) ? bp[jj] : 0.0f;
          Bs[n][k ^ (((n >> 2) & 3) * 8)] = __float2bfloat16(v);
        }
      }
    }
    __syncthreads();
    int n0 = wn + l16, n1 = wn + 16 + l16;
    bf16x8 a0 = *(bf16x8*)&As[wm + l16][quad * 8];
    bf16x8 a1 = *(bf16x8*)&As[wm + 16 + l16][quad * 8];
    bf16x8 b0 = *(bf16x8*)&Bs[n0][(quad * 8) ^ (((n0 >> 2) & 3) * 8)];
    bf16x8 b1 = *(bf16x8*)&Bs[n1][(quad * 8) ^ (((n1 >> 2) & 3) * 8)];
    acc[0][0] = __builtin_amdgcn_mfma_f32_16x16x32_bf16(a0, b0, acc[0][0], 0, 0, 0);
    acc[0][1] = __builtin_amdgcn_mfma_f32_16x16x32_bf16(a0, b1, acc[0][1], 0, 0, 0);
    acc[1][0] = __builtin_amdgcn_mfma_f32_16x16x32_bf16(a1, b0, acc[1][0], 0, 0, 0);
    acc[1][1] = __builtin_amdgcn_mfma_f32_16x16x32_bf16(a1, b1, acc[1][1], 0, 0, 0);
    __syncthreads();
  }
#pragma unroll
  for (int tm = 0; tm < 2; tm++){
#pragma unroll
    for (int tn = 0; tn < 2; tn++){
      int ncol = bn + wn + tn * 16 + l16;
      if (ncol >= N) continue;
#pragma unroll
      for (int reg = 0; reg < 4; reg++){
        long mrow = bm + wm + tm * 16 + quad * 4 + reg;
        float v = acc[tm][tn][reg];
        if (bias) v += bias[ncol];
        if (ACT == 1) v = geluf(v);
        long off = mrow * (long)ldc + ccol + ncol;
        if (res) v += res[off];
        if (OUTBF) Cb[off] = __float2bfloat16(v);
        else       Cf[off] = v;
      }
    }
  }
}

// ---------------- compressed-block mean pooling of K and V (bf16 in, f32 out) ----------
__global__ __launch_bounds__(512) void k_cpool(const bf16_t* __restrict__ qkvg,
                                               float* __restrict__ ck,
                                               float* __restrict__ cv){
  int bj = blockIdx.x;
  int j = bj % NC_;
  int b = bj / NC_;
  int c = threadIdx.x;
  const bf16_t* base = qkvg + ((long)b * SEQ_ + (long)j * CST_) * QLD + c;
  float sk = 0.0f, sv = 0.0f;
  for (int t = 0; t < CBS_; t++){
    sk += __bfloat162float(base[512  + (long)t * QLD]);
    sv += __bfloat162float(base[1024 + (long)t * QLD]);
  }
  ck[bj * DIMC + c] = sk * (1.0f / CBS_);
  cv[bj * DIMC + c] = sv * (1.0f / CBS_);
}

// ---------------- fused NSA attention v3: MFMA QK^T + combined-weight MFMA PV --------
__global__ __launch_bounds__(256) void k_attn(const bf16_t* __restrict__ qkvg,
                                              const float* __restrict__ ck,
                                              const float* __restrict__ cv,
                                              bf16_t* __restrict__ oattn){
  int tid = threadIdx.x;
  int w = tid >> 6, lane = tid & 63;
  int quad = lane >> 4, l16 = lane & 15;
  int i0 = blockIdx.x * TQ_;
  int bh = blockIdx.y;
  int h = bh & 7, b = bh >> 3;
  const float scale = 0.125f;

  __shared__ __align__(16) char smem[78864];
  bf16_t (*Qs)[72]    = (bf16_t(*)[72])(smem);            // 4608 B  (rows 28-31 zero)
  bf16_t (*Ks)[72]    = (bf16_t(*)[72])(smem + 4608);     // 9216 B  (phase C)
  bf16_t (*Vt)[168]   = (bf16_t(*)[168])(smem + 4608);    // 21504 B (phase D, same buf)
  bf16_t (*sbuf)[808] = (bf16_t(*)[808])(smem + 26112);   // 45248 B
  float  (*outc_s)[64] = (float(*)[64])(smem + 71360);    // 7168 B
  int*   sel_s = (int*)(smem + 78528);
  float* cw_s  = (float*)(smem + 78640);
  float* cs_s  = (float*)(smem + 78752);

  const long rowBase = (long)b * SEQ_ * QLD + h * 64;     // + token*QLD + {0,512,1024}

  // ---- Phase A: stage Q tile (28 rows) + zero rows 28-31 ----
  if (tid < 224){
    int q = tid >> 3, seg = tid & 7;
    uintx4 qv = *(const uintx4*)(qkvg + rowBase + (long)(i0 + q) * QLD + seg * 8);
    *(uintx4*)&Qs[q][seg * 8] = qv;
  } else {
    int u = tid - 224;
    int r = 28 + (u >> 3), seg = u & 7;
    *(uintx4*)&Qs[r][seg * 8] = (uintx4){0u, 0u, 0u, 0u};
  }
  __syncthreads();

  // ---- Phase B: compressed branch + gates + top-1 selection ----
  float g1r[7], g2r[7];
  int selr[7];
  {
    const float* CKp = ck + (long)b * NC_ * DIMC + h * 64 + lane;
    const float* CVp = cv + (long)b * NC_ * DIMC + h * 64 + lane;
    float k0 = CKp[0], k1 = CKp[512], k2 = CKp[1024];
    float v0 = CVp[0], v1 = CVp[512], v2 = CVp[1024];
#pragma unroll
    for (int qp = 0; qp < 7; qp++){
      int qg = w * 7 + qp;
      float qd = __bfloat162float(Qs[qg][lane]);
      float s0 = wsum(qd * k0) * scale;
      float s1 = wsum(qd * k1) * scale;
      float s2 = wsum(qd * k2) * scale;
      float m3 = fmaxf(s0, fmaxf(s1, s2));
      float e0 = __expf(s0 - m3), e1 = __expf(s1 - m3), e2 = __expf(s2 - m3);
      float inv = 1.0f / (e0 + e1 + e2);
      const bf16_t* grow = qkvg + (long)(b * SEQ_ + i0 + qg) * QLD + 1536 + h * 3;
      float g0 = sigmoidf_(__bfloat162float(grow[0]));
      g1r[qp] = sigmoidf_(__bfloat162float(grow[1]));
      g2r[qp] = sigmoidf_(__bfloat162float(grow[2]));
      outc_s[qg][lane] = g0 * (e0 * v0 + e1 * v1 + e2 * v2) * inv;
      selr[qp] = (s2 > s0) ? 1 : 0;   // imp1>imp0 <=> p2>p0 <=> s2>s0
      if (lane == 0) sel_s[qg] = selr[qp];
    }
  }

  // hoist Q A-fragments (chunk-invariant)
  bf16x8 a00 = *(bf16x8*)&Qs[l16][quad * 8];
  bf16x8 a01 = *(bf16x8*)&Qs[l16][32 + quad * 8];
  bf16x8 a10 = *(bf16x8*)&Qs[16 + l16][quad * 8];
  bf16x8 a11 = *(bf16x8*)&Qs[16 + l16][32 + quad * 8];

  // ---- Phase C: QK^T via MFMA, exp -> sbuf (14 chunks of 56 keys) ----
  for (int ch = 0; ch < 14; ch++){
    int c0 = ch * 56;
#pragma unroll
    for (int p = 0; p < 2; p++){
      int uu = tid + p * 256;
      int r = uu >> 3, seg = uu & 7;
      int tok = c0 + r; tok = tok > 783 ? 783 : tok;   // rows 56-63 duplicated, discarded
      uintx4 kv = *(const uintx4*)(qkvg + rowBase + (long)tok * QLD + 512 + seg * 8);
      *(uintx4*)&Ks[r][seg * 8] = kv;
    }
    __syncthreads();
    bf16x8 b0 = *(bf16x8*)&Ks[w * 16 + l16][quad * 8];
    bf16x8 b1 = *(bf16x8*)&Ks[w * 16 + l16][32 + quad * 8];
    floatx4 d0 = (floatx4)(0.0f), d1 = (floatx4)(0.0f);
    d0 = __builtin_amdgcn_mfma_f32_16x16x32_bf16(a00, b0, d0, 0, 0, 0);
    d0 = __builtin_amdgcn_mfma_f32_16x16x32_bf16(a01, b1, d0, 0, 0, 0);
    d1 = __builtin_amdgcn_mfma_f32_16x16x32_bf16(a10, b0, d1, 0, 0, 0);
    d1 = __builtin_amdgcn_mfma_f32_16x16x32_bf16(a11, b1, d1, 0, 0, 0);
    int tc = w * 16 + l16;
    if (tc < 56){
      int t = c0 + tc;
#pragma unroll
      for (int reg = 0; reg < 4; reg++){
        sbuf[quad * 4 + reg][t] = __float2bfloat16(__expf(d0[reg] * scale));
        int q2 = 16 + quad * 4 + reg;
        if (q2 < 28) sbuf[q2][t] = __float2bfloat16(__expf(d1[reg] * scale));
      }
    }
    __syncthreads();
  }

  // ---- row sums -> per-row coefficients ----
#pragma unroll
  for (int qp = 0; qp < 7; qp++){
    int q = w * 7 + qp;
    int iq = i0 + q;
    int lo = iq - 195; if (lo < 0) lo = 0;
    int hi = iq + 195; if (hi > 783) hi = 783;
    float sw = 0.0f;
    for (int t = lo + lane; t <= hi; t += 64) sw += __bfloat162float(sbuf[q][t]);
    sw = wsum(sw);
    int slo = selr[qp] * 392;
    float ss = 0.0f;
    for (int t = slo + lane; t < slo + 392; t += 64) ss += __bfloat162float(sbuf[q][t]);
    ss = wsum(ss);
    if (lane == 0){
      cw_s[q] = g2r[qp] / sw;
      cs_s[q] = g1r[qp] / ss;
    }
  }
  __syncthreads();

  // ---- build combined weight matrix W in place (zero cols 784..807) ----
  for (int q = 0; q < 28; q++){
    int iq = i0 + q;
    float cw = cw_s[q], cs = cs_s[q];
    int sl = sel_s[q];
    for (int c = tid; c < 808; c += 256){
      float wv = 0.0f;
      if (c < 784){
        float e = __bfloat162float(sbuf[q][c]);
        float coef = 0.0f;
        if (c >= iq - 195 && c <= iq + 195) coef += cw;
        if ((c >= 392 ? 1 : 0) == sl)       coef += cs;
        wv = e * coef;
      }
      sbuf[q][c] = __float2bfloat16(wv);
    }
  }
  __syncthreads();

  // ---- Phase D: out = W · V via MFMA (5 chunks of 160 tokens, V transposed-staged) ----
  floatx4 o0 = (floatx4)(0.0f), o1 = (floatx4)(0.0f);
  for (int ch = 0; ch < 5; ch++){
    int c0 = ch * 160;
#pragma unroll
    for (int p = 0; p < 5; p++){
      int u = tid + p * 256;           // 1280 units exactly
      int seg = u / 160;
      int t = u - seg * 160;
      int tok = c0 + t; tok = tok > 783 ? 783 : tok;   // W cols >=784 are zero
      uintx4 vv = *(const uintx4*)(qkvg + rowBase + (long)tok * QLD + 1024 + seg * 8);
      bf16_t tmp[8]; *(uintx4*)tmp = vv;
#pragma unroll
      for (int jj = 0; jj < 8; jj++) Vt[seg * 8 + jj][t] = tmp[jj];
    }
    __syncthreads();
#pragma unroll
    for (int ks = 0; ks < 5; ks++){
      int kc = c0 + ks * 32;
      bf16x8 av0 = *(bf16x8*)&sbuf[l16][kc + quad * 8];
      bf16x8 av1 = *(bf16x8*)&sbuf[16 + l16][kc + quad * 8];
      bf16x8 bv  = *(bf16x8*)&Vt[w * 16 + l16][ks * 32 + quad * 8];
      o0 = __builtin_amdgcn_mfma_f32_16x16x32_bf16(av0, bv, o0, 0, 0, 0);
      o1 = __builtin_amdgcn_mfma_f32_16x16x32_bf16(av1, bv, o1, 0, 0, 0);
    }
    __syncthreads();
  }

  // ---- epilogue: add compressed branch, write bf16 ----
  int d = w * 16 + l16;
#pragma unroll
  for (int reg = 0; reg < 4; reg++){
    int q = quad * 4 + reg;
    float o = o0[reg] + outc_s[q][d];
    oattn[((long)(b * SEQ_ + i0 + q)) * DIMC + h * 64 + d] = __float2bfloat16(o);
    int q2 = q + 16;
    if (q2 < 28){
      float o2 = o1[reg] + outc_s[q2][d];
      oattn[((long)(b * SEQ_ + i0 + q2)) * DIMC + h * 64 + d] = __float2bfloat16(o2);
    }
  }
}

// ---------------- host launcher ----------------
extern "C" void kernel_launch(void* const* d_in, const int* in_sizes, int n_in,
                              void* d_out, int out_size, void* d_ws, size_t ws_size,
                              hipStream_t stream){
  const float* xin  = (const float*)d_in[0];
  const float* pos  = (const float*)d_in[1];
  const float* angm = (const float*)d_in[2];
  const float* Wq   = (const float*)d_in[3];
  const float* Wk   = (const float*)d_in[4];
  const float* Wv   = (const float*)d_in[5];
  const float* Wo   = (const float*)d_in[6];
  const float* Wg   = (const float*)d_in[7];
  const float* fng  = (const float*)d_in[8];
  const float* fnb  = (const float*)d_in[9];
  const float* fw1  = (const float*)d_in[10];
  const float* fb1  = (const float*)d_in[11];
  const float* fw2  = (const float*)d_in[12];
  const float* fb2  = (const float*)d_in[13];

  char* cw = (char*)d_ws;
  float* X = (float*)cw;             cw += (long)NTOK * 512 * 4;
  bf16_t* XRb = (bf16_t*)cw;         cw += (long)NTOK * 512 * 2;
  bf16_t* OAb = (bf16_t*)cw;         cw += (long)NTOK * 512 * 2;
  bf16_t* BUFb = (bf16_t*)cw;        cw += (long)NTOK * QLD * 2;
  bf16_t* H1b = (bf16_t*)cw;         cw += (long)NTOK * FF_ * 2;
  float* CK = (float*)cw;            cw += (long)B_ * NC_ * DIMC * 4;
  float* CV = (float*)cw;            cw += (long)B_ * NC_ * DIMC * 4;

  k_init<<<12544, 256, 0, stream>>>(xin, pos, X);

  for (int l = 0; l < 2; l++){
    long wOff  = (long)l * 512 * 512;
    long wgOff = (long)l * 512 * 24;
    long f1Off = (long)l * FF_ * 512;

    k_rms<<<NTOK, 256, 0, stream>>>(X, angm + (long)l * DIMC, XRb);

    dim3 g512(8 * MTP_), g24(1 * MTP_), g2048(32 * MTP_);

    k_mgemm<0, 1, 0><<<g512, 256, 0, stream>>>(XRb, Wq + wOff, nullptr, BUFb, nullptr,
                                               nullptr, NTOK, 512, 512, 512, QLD, 0);
    k_mgemm<0, 1, 0><<<g512, 256, 0, stream>>>(XRb, Wk + wOff, nullptr, BUFb, nullptr,
                                               nullptr, NTOK, 512, 512, 512, QLD, 512);
    k_mgemm<0, 1, 0><<<g512, 256, 0, stream>>>(XRb, Wv + wOff, nullptr, BUFb, nullptr,
                                               nullptr, NTOK, 512, 512, 512, QLD, 1024);
    k_mgemm<0, 1, 0><<<g24, 256, 0, stream>>>(XRb, Wg + wgOff, nullptr, BUFb, nullptr,
                                              nullptr, NTOK, 24, 512, 24, QLD, 1536);

    k_cpool<<<B_ * NC_, 512, 0, stream>>>(BUFb, CK, CV);

    dim3 ga(SEQ_ / TQ_, B_ * HEADS_);
    k_attn<<<ga, 256, 0, stream>>>(BUFb, CK, CV, OAb);

    k_mgemm<0, 0, 0><<<g512, 256, 0, stream>>>(OAb, Wo + wOff, X, nullptr, nullptr,
                                               X, NTOK, 512, 512, 512, 512, 0);

    k_ln<<<NTOK, 256, 0, stream>>>(X, fng + (long)l * DIMC, fnb + (long)l * DIMC, XRb);

    k_mgemm<1, 1, 1><<<g2048, 256, 0, stream>>>(XRb, fw1 + f1Off, nullptr, H1b,
                                                fb1 + (long)l * FF_, nullptr,
                                                NTOK, FF_, 512, 512, FF_, 0);
    k_mgemm<1, 0, 0><<<g512, 256, 0, stream>>>(H1b, fw2 + f1Off, X, nullptr,
                                               fb2 + (long)l * DIMC, X,
                                               NTOK, 512, FF_, FF_, 512, 0);
  }

  k_final<<<12544, 256, 0, stream>>>(X, (float*)d_out);
}

// Round 9
// 1733.072 us; speedup vs baseline: 2.5981x; 1.0233x over previous
//
#include <hip/hip_runtime.h>
#include <hip/hip_bf16.h>
#include <math.h>

// ---- static config (matches reference) ----
#define B_      8
#define DIMC    512
#define SEQ_    784
#define HEADS_  8
#define DH_     64
#define NTOK    (B_*SEQ_)      // 6272
#define QLD     1560           // q(512) | k(512) | v(512) | gates(24)
#define WIN_    196
#define CBS_    392
#define CST_    196
#define NC_     3
#define EPSF    1e-5f
#define FF_     2048
#define TQ_     28             // queries per block (28*28 = 784)
#define MT_     98             // m-tiles (6272/64)

typedef __hip_bfloat16 bf16_t;
typedef __attribute__((ext_vector_type(8))) short bf16x8;
typedef __attribute__((ext_vector_type(4))) float floatx4;
typedef __attribute__((ext_vector_type(4))) unsigned int uintx4;

// ---------------- helpers ----------------
__device__ __forceinline__ float wsum(float x){
#pragma unroll
  for (int o = 32; o; o >>= 1) x += __shfl_xor(x, o, 64);
  return x;
}
__device__ __forceinline__ float geluf(float x){
  return 0.5f * x * (1.0f + erff(x * 0.70710678118654752f));
}
__device__ __forceinline__ float sigmoidf_(float x){
  return 1.0f / (1.0f + __expf(-x));
}

// ---------------- init: x[b,c,h,w] (f32) -> X[b,p,c] (f32) + pos ----------------
__global__ __launch_bounds__(256) void k_init(const float* __restrict__ xin,
                                              const float* __restrict__ pos,
                                              float* __restrict__ X){
  int idx = blockIdx.x * 256 + threadIdx.x;       // over NTOK*512 (exact)
  int c = idx & 511;
  int t = idx >> 9;          // b*784 + p
  int p = t % SEQ_;
  int b = t / SEQ_;
  float v = xin[((long)(b * DIMC + c)) * SEQ_ + p];
  X[idx] = v + pos[p];
}

// ---------------- final: X[b,p,c] -> out[b,c,h,w] f32 ----------------
__global__ __launch_bounds__(256) void k_final(const float* __restrict__ X,
                                               float* __restrict__ out){
  int idx = blockIdx.x * 256 + threadIdx.x;       // over B*DIMC*SEQ (exact)
  int p = idx % SEQ_;
  int t = idx / SEQ_;        // b*512 + c
  int c = t & 511;
  int b = t >> 9;
  out[idx] = X[((long)(b * SEQ_ + p)) * DIMC + c];
}

// ---------------- RMSNorm: f32 in -> bf16 out ----------------
__global__ __launch_bounds__(256) void k_rms(const float* __restrict__ X,
                                             const float* __restrict__ g,
                                             bf16_t* __restrict__ XR){
  int tok = blockIdx.x;
  int tid = threadIdx.x;
  const float* xr = X + (long)tok * DIMC;
  float v0 = xr[tid], v1 = xr[tid + 256];
  float ss = v0 * v0 + v1 * v1;
  ss = wsum(ss);
  __shared__ float red[4];
  if ((tid & 63) == 0) red[tid >> 6] = ss;
  __syncthreads();
  float tot = red[0] + red[1] + red[2] + red[3];
  float r = rsqrtf(tot * (1.0f / DIMC) + EPSF);
  XR[(long)tok * DIMC + tid]       = __float2bfloat16(v0 * r * g[tid]);
  XR[(long)tok * DIMC + tid + 256] = __float2bfloat16(v1 * r * g[tid + 256]);
}

// ---------------- LayerNorm: f32 in -> bf16 out ----------------
__global__ __launch_bounds__(256) void k_ln(const float* __restrict__ X,
                                            const float* __restrict__ g,
                                            const float* __restrict__ bb,
                                            bf16_t* __restrict__ XN){
  int tok = blockIdx.x;
  int tid = threadIdx.x;
  const float* xr = X + (long)tok * DIMC;
  float v0 = xr[tid], v1 = xr[tid + 256];
  float s = v0 + v1;
  float q = v0 * v0 + v1 * v1;
  s = wsum(s); q = wsum(q);
  __shared__ float r1[4], r2[4];
  if ((tid & 63) == 0){ r1[tid >> 6] = s; r2[tid >> 6] = q; }
  __syncthreads();
  float ts = r1[0] + r1[1] + r1[2] + r1[3];
  float tq = r2[0] + r2[1] + r2[2] + r2[3];
  float mean = ts * (1.0f / DIMC);
  float var  = tq * (1.0f / DIMC) - mean * mean;
  float rinv = rsqrtf(var + EPSF);
  XN[(long)tok * DIMC + tid]       = __float2bfloat16((v0 - mean) * rinv * g[tid]       + bb[tid]);
  XN[(long)tok * DIMC + tid + 256] = __float2bfloat16((v1 - mean) * rinv * g[tid + 256] + bb[tid + 256]);
}

// ---------------- bf16-MFMA GEMM, f32 weights, BK=64, vectorized LDS staging -------
// MODE 0: B = B0 f32 [K][NL], columns bn..   (column-gather staging)
// MODE 1: B = B0 f32 [N][K]  (k-major row staging)
// MODE 2: fused QKVG: tile-uniform select among B0..B3 ([512,512]x3 + [512,24])
// 1-D grid nx*104, XCD-swizzled m-bands. 64x64 tile, 4 waves, 2x2 mfma 16x16x32.
template<int MODE, int OUTBF, int ACT>
__global__ __launch_bounds__(256) void k_mgemm(const bf16_t* __restrict__ A,
                                               const float* __restrict__ B0,
                                               const float* __restrict__ B1,
                                               const float* __restrict__ B2,
                                               const float* __restrict__ B3,
                                               float* Cf,
                                               bf16_t* Cb,
                                               const float* __restrict__ bias,
                                               const float* res,
                                               int M, int N, int K, int NL,
                                               int ldc, int ccol){
  int id = blockIdx.x;
  int xcd = id & 7;
  int j = id >> 3;
  int nt = j / 13;
  int mt = xcd * 13 + (j - nt * 13);
  if (mt >= MT_) return;
  int bm = mt * 64, bn = nt * 64;

  __shared__ bf16_t As[64][72];   // 64 k + 8 pad
  __shared__ bf16_t Bs[64][72];
  int tid = threadIdx.x;
  int w = tid >> 6, lane = tid & 63;
  int wm = (w & 1) * 32, wn = (w >> 1) * 32;
  int quad = lane >> 4, l16 = lane & 15;

  int arow = tid >> 2, akc = (tid & 3) * 8;
  const bf16_t* ap = A + (long)(bm + arow) * K + akc;

  // B source resolution (block-uniform for MODE 2)
  const float* src = B0;
  int nl = NL, coff = 0;
  if (MODE == 2){
    if (bn < 512)       { src = B0; nl = 512; coff = 0;    }
    else if (bn < 1024) { src = B1; nl = 512; coff = 512;  }
    else if (bn < 1536) { src = B2; nl = 512; coff = 1024; }
    else                { src = B3; nl = 24;  coff = 1536; }
  }
  int bcol = bn + arow - coff;          // column within src (MODE 0/2)
  bool bok = (MODE == 1) ? ((bn + arow) < N) : (bcol < nl);
  int bcolc = bok ? bcol : 0;
  int sw = ((arow >> 2) & 3) * 8;       // XOR swizzle for row arow

  floatx4 acc[2][2];
#pragma unroll
  for (int i = 0; i < 2; i++)
#pragma unroll
    for (int jj = 0; jj < 2; jj++) acc[i][jj] = (floatx4)(0.0f);

  int swr0 = ((l16 >> 2) & 3) * 8;      // read swizzle (rows wn+l16 / wn+16+l16 share it)

  for (int k0 = 0; k0 < K; k0 += 64){
    *(uintx4*)&As[arow][akc]      = *(const uintx4*)(ap + k0);
    *(uintx4*)&As[arow][akc + 32] = *(const uintx4*)(ap + k0 + 32);
    float f0[8], f1[8];
    if (MODE == 1){
      const float* bp = src + (long)((MODE == 1 && bok) ? bn + arow : 0) * K + k0 + akc;
#pragma unroll
      for (int jj = 0; jj < 8; jj++){
        f0[jj] = bok ? bp[jj] : 0.0f;
        f1[jj] = bok ? bp[32 + jj] : 0.0f;
      }
    } else {
      const float* bp = src + (long)(k0 + akc) * nl + bcolc;
#pragma unroll
      for (int jj = 0; jj < 8; jj++){
        f0[jj] = bok ? bp[(long)jj * nl] : 0.0f;
        f1[jj] = bok ? bp[(long)(32 + jj) * nl] : 0.0f;
      }
    }
    bf16_t t0[8], t1[8];
#pragma unroll
    for (int jj = 0; jj < 8; jj++){ t0[jj] = __float2bfloat16(f0[jj]); t1[jj] = __float2bfloat16(f1[jj]); }
    *(uintx4*)&Bs[arow][(akc ^ sw)]      = *(uintx4*)t0;
    *(uintx4*)&Bs[arow][(akc ^ sw) + 32] = *(uintx4*)t1;
    __syncthreads();
#pragma unroll
    for (int ks = 0; ks < 2; ks++){
      bf16x8 a0 = *(bf16x8*)&As[wm + l16][ks * 32 + quad * 8];
      bf16x8 a1 = *(bf16x8*)&As[wm + 16 + l16][ks * 32 + quad * 8];
      bf16x8 b0 = *(bf16x8*)&Bs[wn + l16][ks * 32 + ((quad * 8) ^ swr0)];
      bf16x8 b1 = *(bf16x8*)&Bs[wn + 16 + l16][ks * 32 + ((quad * 8) ^ swr0)];
      acc[0][0] = __builtin_amdgcn_mfma_f32_16x16x32_bf16(a0, b0, acc[0][0], 0, 0, 0);
      acc[0][1] = __builtin_amdgcn_mfma_f32_16x16x32_bf16(a0, b1, acc[0][1], 0, 0, 0);
      acc[1][0] = __builtin_amdgcn_mfma_f32_16x16x32_bf16(a1, b0, acc[1][0], 0, 0, 0);
      acc[1][1] = __builtin_amdgcn_mfma_f32_16x16x32_bf16(a1, b1, acc[1][1], 0, 0, 0);
    }
    __syncthreads();
  }
#pragma unroll
  for (int tm = 0; tm < 2; tm++){
#pragma unroll
    for (int tn = 0; tn < 2; tn++){
      int ncol = bn + wn + tn * 16 + l16;
      if (ncol >= N) continue;
#pragma unroll
      for (int reg = 0; reg < 4; reg++){
        long mrow = bm + wm + tm * 16 + quad * 4 + reg;
        float v = acc[tm][tn][reg];
        if (bias) v += bias[ncol];
        if (ACT == 1) v = geluf(v);
        long off = mrow * (long)ldc + ccol + ncol;
        if (res) v += res[off];
        if (OUTBF) Cb[off] = __float2bfloat16(v);
        else       Cf[off] = v;
      }
    }
  }
}

// ---------------- compressed-block mean pooling of K and V (bf16 in, f32 out) ----------
__global__ __launch_bounds__(512) void k_cpool(const bf16_t* __restrict__ qkvg,
                                               float* __restrict__ ck,
                                               float* __restrict__ cv){
  int bj = blockIdx.x;
  int j = bj % NC_;
  int b = bj / NC_;
  int c = threadIdx.x;
  const bf16_t* base = qkvg + ((long)b * SEQ_ + (long)j * CST_) * QLD + c;
  float sk = 0.0f, sv = 0.0f;
  for (int t = 0; t < CBS_; t++){
    sk += __bfloat162float(base[512  + (long)t * QLD]);
    sv += __bfloat162float(base[1024 + (long)t * QLD]);
  }
  ck[bj * DIMC + c] = sk * (1.0f / CBS_);
  cv[bj * DIMC + c] = sv * (1.0f / CBS_);
}

// ---------------- fused NSA attention v3: MFMA QK^T + combined-weight MFMA PV --------
__global__ __launch_bounds__(256) void k_attn(const bf16_t* __restrict__ qkvg,
                                              const float* __restrict__ ck,
                                              const float* __restrict__ cv,
                                              bf16_t* __restrict__ oattn){
  int tid = threadIdx.x;
  int w = tid >> 6, lane = tid & 63;
  int quad = lane >> 4, l16 = lane & 15;
  int i0 = blockIdx.x * TQ_;
  int bh = blockIdx.y;
  int h = bh & 7, b = bh >> 3;
  const float scale = 0.125f;

  __shared__ __align__(16) char smem[78864];
  bf16_t (*Qs)[72]    = (bf16_t(*)[72])(smem);            // 4608 B  (rows 28-31 zero)
  bf16_t (*Ks)[72]    = (bf16_t(*)[72])(smem + 4608);     // 9216 B  (phase C)
  bf16_t (*Vt)[168]   = (bf16_t(*)[168])(smem + 4608);    // 21504 B (phase D, same buf)
  bf16_t (*sbuf)[808] = (bf16_t(*)[808])(smem + 26112);   // 45248 B
  float  (*outc_s)[64] = (float(*)[64])(smem + 71360);    // 7168 B
  int*   sel_s = (int*)(smem + 78528);
  float* cw_s  = (float*)(smem + 78640);
  float* cs_s  = (float*)(smem + 78752);

  const long rowBase = (long)b * SEQ_ * QLD + h * 64;     // + token*QLD + {0,512,1024}

  // ---- Phase A: stage Q tile (28 rows) + zero rows 28-31 ----
  if (tid < 224){
    int q = tid >> 3, seg = tid & 7;
    uintx4 qv = *(const uintx4*)(qkvg + rowBase + (long)(i0 + q) * QLD + seg * 8);
    *(uintx4*)&Qs[q][seg * 8] = qv;
  } else {
    int u = tid - 224;
    int r = 28 + (u >> 3), seg = u & 7;
    *(uintx4*)&Qs[r][seg * 8] = (uintx4){0u, 0u, 0u, 0u};
  }
  __syncthreads();

  // ---- Phase B: compressed branch + gates + top-1 selection ----
  float g1r[7], g2r[7];
  int selr[7];
  {
    const float* CKp = ck + (long)b * NC_ * DIMC + h * 64 + lane;
    const float* CVp = cv + (long)b * NC_ * DIMC + h * 64 + lane;
    float k0 = CKp[0], k1 = CKp[512], k2 = CKp[1024];
    float v0 = CVp[0], v1 = CVp[512], v2 = CVp[1024];
#pragma unroll
    for (int qp = 0; qp < 7; qp++){
      int qg = w * 7 + qp;
      float qd = __bfloat162float(Qs[qg][lane]);
      float s0 = wsum(qd * k0) * scale;
      float s1 = wsum(qd * k1) * scale;
      float s2 = wsum(qd * k2) * scale;
      float m3 = fmaxf(s0, fmaxf(s1, s2));
      float e0 = __expf(s0 - m3), e1 = __expf(s1 - m3), e2 = __expf(s2 - m3);
      float inv = 1.0f / (e0 + e1 + e2);
      const bf16_t* grow = qkvg + (long)(b * SEQ_ + i0 + qg) * QLD + 1536 + h * 3;
      float g0 = sigmoidf_(__bfloat162float(grow[0]));
      g1r[qp] = sigmoidf_(__bfloat162float(grow[1]));
      g2r[qp] = sigmoidf_(__bfloat162float(grow[2]));
      outc_s[qg][lane] = g0 * (e0 * v0 + e1 * v1 + e2 * v2) * inv;
      selr[qp] = (s2 > s0) ? 1 : 0;   // imp1>imp0 <=> p2>p0 <=> s2>s0
      if (lane == 0) sel_s[qg] = selr[qp];
    }
  }

  // hoist Q A-fragments (chunk-invariant)
  bf16x8 a00 = *(bf16x8*)&Qs[l16][quad * 8];
  bf16x8 a01 = *(bf16x8*)&Qs[l16][32 + quad * 8];
  bf16x8 a10 = *(bf16x8*)&Qs[16 + l16][quad * 8];
  bf16x8 a11 = *(bf16x8*)&Qs[16 + l16][32 + quad * 8];

  // ---- Phase C: QK^T via MFMA, exp -> sbuf (14 chunks of 56 keys) ----
  for (int ch = 0; ch < 14; ch++){
    int c0 = ch * 56;
#pragma unroll
    for (int p = 0; p < 2; p++){
      int uu = tid + p * 256;
      int r = uu >> 3, seg = uu & 7;
      int tok = c0 + r; tok = tok > 783 ? 783 : tok;   // rows 56-63 duplicated, discarded
      uintx4 kv = *(const uintx4*)(qkvg + rowBase + (long)tok * QLD + 512 + seg * 8);
      *(uintx4*)&Ks[r][seg * 8] = kv;
    }
    __syncthreads();
    bf16x8 b0 = *(bf16x8*)&Ks[w * 16 + l16][quad * 8];
    bf16x8 b1 = *(bf16x8*)&Ks[w * 16 + l16][32 + quad * 8];
    floatx4 d0 = (floatx4)(0.0f), d1 = (floatx4)(0.0f);
    d0 = __builtin_amdgcn_mfma_f32_16x16x32_bf16(a00, b0, d0, 0, 0, 0);
    d0 = __builtin_amdgcn_mfma_f32_16x16x32_bf16(a01, b1, d0, 0, 0, 0);
    d1 = __builtin_amdgcn_mfma_f32_16x16x32_bf16(a10, b0, d1, 0, 0, 0);
    d1 = __builtin_amdgcn_mfma_f32_16x16x32_bf16(a11, b1, d1, 0, 0, 0);
    int tc = w * 16 + l16;
    if (tc < 56){
      int t = c0 + tc;
#pragma unroll
      for (int reg = 0; reg < 4; reg++){
        sbuf[quad * 4 + reg][t] = __float2bfloat16(__expf(d0[reg] * scale));
        int q2 = 16 + quad * 4 + reg;
        if (q2 < 28) sbuf[q2][t] = __float2bfloat16(__expf(d1[reg] * scale));
      }
    }
    __syncthreads();
  }

  // ---- row sums -> per-row coefficients ----
#pragma unroll
  for (int qp = 0; qp < 7; qp++){
    int q = w * 7 + qp;
    int iq = i0 + q;
    int lo = iq - 195; if (lo < 0) lo = 0;
    int hi = iq + 195; if (hi > 783) hi = 783;
    float sw = 0.0f;
    for (int t = lo + lane; t <= hi; t += 64) sw += __bfloat162float(sbuf[q][t]);
    sw = wsum(sw);
    int slo = selr[qp] * 392;
    float ss = 0.0f;
    for (int t = slo + lane; t < slo + 392; t += 64) ss += __bfloat162float(sbuf[q][t]);
    ss = wsum(ss);
    if (lane == 0){
      cw_s[q] = g2r[qp] / sw;
      cs_s[q] = g1r[qp] / ss;
    }
  }
  __syncthreads();

  // ---- build combined weight matrix W in place (zero cols 784..807) ----
  for (int q = 0; q < 28; q++){
    int iq = i0 + q;
    float cwv = cw_s[q], csv = cs_s[q];
    int sl = sel_s[q];
    for (int c = tid; c < 808; c += 256){
      float wv = 0.0f;
      if (c < 784){
        float e = __bfloat162float(sbuf[q][c]);
        float coef = 0.0f;
        if (c >= iq - 195 && c <= iq + 195) coef += cwv;
        if ((c >= 392 ? 1 : 0) == sl)       coef += csv;
        wv = e * coef;
      }
      sbuf[q][c] = __float2bfloat16(wv);
    }
  }
  __syncthreads();

  // ---- Phase D: out = W · V via MFMA (5 chunks of 160 tokens, V transposed-staged) ----
  floatx4 o0 = (floatx4)(0.0f), o1 = (floatx4)(0.0f);
  for (int ch = 0; ch < 5; ch++){
    int c0 = ch * 160;
#pragma unroll
    for (int p = 0; p < 5; p++){
      int u = tid + p * 256;           // 1280 units exactly
      int seg = u / 160;
      int t = u - seg * 160;
      int tok = c0 + t; tok = tok > 783 ? 783 : tok;   // W cols >=784 are zero
      uintx4 vv = *(const uintx4*)(qkvg + rowBase + (long)tok * QLD + 1024 + seg * 8);
      bf16_t tmp[8]; *(uintx4*)tmp = vv;
#pragma unroll
      for (int jj = 0; jj < 8; jj++) Vt[seg * 8 + jj][t] = tmp[jj];
    }
    __syncthreads();
#pragma unroll
    for (int ks = 0; ks < 5; ks++){
      int kc = c0 + ks * 32;
      bf16x8 av0 = *(bf16x8*)&sbuf[l16][kc + quad * 8];
      bf16x8 av1 = *(bf16x8*)&sbuf[16 + l16][kc + quad * 8];
      bf16x8 bv  = *(bf16x8*)&Vt[w * 16 + l16][ks * 32 + quad * 8];
      o0 = __builtin_amdgcn_mfma_f32_16x16x32_bf16(av0, bv, o0, 0, 0, 0);
      o1 = __builtin_amdgcn_mfma_f32_16x16x32_bf16(av1, bv, o1, 0, 0, 0);
    }
    __syncthreads();
  }

  // ---- epilogue: add compressed branch, write bf16 ----
  int d = w * 16 + l16;
#pragma unroll
  for (int reg = 0; reg < 4; reg++){
    int q = quad * 4 + reg;
    float o = o0[reg] + outc_s[q][d];
    oattn[((long)(b * SEQ_ + i0 + q)) * DIMC + h * 64 + d] = __float2bfloat16(o);
    int q2 = q + 16;
    if (q2 < 28){
      float o2 = o1[reg] + outc_s[q2][d];
      oattn[((long)(b * SEQ_ + i0 + q2)) * DIMC + h * 64 + d] = __float2bfloat16(o2);
    }
  }
}

// ---------------- host launcher ----------------
extern "C" void kernel_launch(void* const* d_in, const int* in_sizes, int n_in,
                              void* d_out, int out_size, void* d_ws, size_t ws_size,
                              hipStream_t stream){
  const float* xin  = (const float*)d_in[0];
  const float* pos  = (const float*)d_in[1];
  const float* angm = (const float*)d_in[2];
  const float* Wq   = (const float*)d_in[3];
  const float* Wk   = (const float*)d_in[4];
  const float* Wv   = (const float*)d_in[5];
  const float* Wo   = (const float*)d_in[6];
  const float* Wg   = (const float*)d_in[7];
  const float* fng  = (const float*)d_in[8];
  const float* fnb  = (const float*)d_in[9];
  const float* fw1  = (const float*)d_in[10];
  const float* fb1  = (const float*)d_in[11];
  const float* fw2  = (const float*)d_in[12];
  const float* fb2  = (const float*)d_in[13];

  char* cw = (char*)d_ws;
  float* X = (float*)cw;             cw += (long)NTOK * 512 * 4;
  bf16_t* XRb = (bf16_t*)cw;         cw += (long)NTOK * 512 * 2;
  bf16_t* OAb = (bf16_t*)cw;         cw += (long)NTOK * 512 * 2;
  bf16_t* BUFb = (bf16_t*)cw;        cw += (long)NTOK * QLD * 2;
  bf16_t* H1b = (bf16_t*)cw;         cw += (long)NTOK * FF_ * 2;
  float* CK = (float*)cw;            cw += (long)B_ * NC_ * DIMC * 4;
  float* CV = (float*)cw;            cw += (long)B_ * NC_ * DIMC * 4;

  k_init<<<12544, 256, 0, stream>>>(xin, pos, X);

  for (int l = 0; l < 2; l++){
    long wOff  = (long)l * 512 * 512;
    long wgOff = (long)l * 512 * 24;
    long f1Off = (long)l * FF_ * 512;

    k_rms<<<NTOK, 256, 0, stream>>>(X, angm + (long)l * DIMC, XRb);

    // fused QKV+G GEMM: N=1560 (tile-uniform weight select), bf16 out into BUFb
    k_mgemm<2, 1, 0><<<25 * 104, 256, 0, stream>>>(
        XRb, Wq + wOff, Wk + wOff, Wv + wOff, Wg + wgOff,
        nullptr, BUFb, nullptr, nullptr, NTOK, QLD, 512, 0, QLD, 0);

    k_cpool<<<B_ * NC_, 512, 0, stream>>>(BUFb, CK, CV);

    dim3 ga(SEQ_ / TQ_, B_ * HEADS_);
    k_attn<<<ga, 256, 0, stream>>>(BUFb, CK, CV, OAb);

    // Wo GEMM: weights [K,N] f32 column-gather, f32 out + residual into X
    k_mgemm<0, 0, 0><<<8 * 104, 256, 0, stream>>>(
        OAb, Wo + wOff, nullptr, nullptr, nullptr,
        X, nullptr, nullptr, X, NTOK, 512, 512, 512, 512, 0);

    k_ln<<<NTOK, 256, 0, stream>>>(X, fng + (long)l * DIMC, fnb + (long)l * DIMC, XRb);

    // FF1: weights [N,K] f32, GELU, bf16 out
    k_mgemm<1, 1, 1><<<32 * 104, 256, 0, stream>>>(
        XRb, fw1 + f1Off, nullptr, nullptr, nullptr,
        nullptr, H1b, fb1 + (long)l * FF_, nullptr, NTOK, FF_, 512, 0, FF_, 0);
    // FF2: weights [N,K] f32, f32 out + residual into X
    k_mgemm<1, 0, 0><<<8 * 104, 256, 0, stream>>>(
        H1b, fw2 + f1Off, nullptr, nullptr, nullptr,
        X, nullptr, fb2 + (long)l * DIMC, X, NTOK, 512, FF_, 0, 512, 0);
  }

  k_final<<<12544, 256, 0, stream>>>(X, (float*)d_out);
}

// Round 10
// 821.528 us; speedup vs baseline: 5.4809x; 2.1096x over previous
//
#include <hip/hip_runtime.h>
#include <hip/hip_bf16.h>
#include <math.h>

// ---- static config (matches reference) ----
#define B_      8
#define DIMC    512
#define SEQ_    784
#define HEADS_  8
#define DH_     64
#define NTOK    (B_*SEQ_)      // 6272
#define QLD     1560           // q(512) | k(512) | v(512) | gates(24)
#define WIN_    196
#define CBS_    392
#define CST_    196
#define NC_     3
#define EPSF    1e-5f
#define FF_     2048
#define TQ_     28             // queries per block (28*28 = 784)
#define MT_     98             // m-tiles (6272/64)

typedef __hip_bfloat16 bf16_t;
typedef __attribute__((ext_vector_type(8))) short bf16x8;
typedef __attribute__((ext_vector_type(4))) float floatx4;
typedef __attribute__((ext_vector_type(4))) unsigned int uintx4;

// ---------------- helpers ----------------
__device__ __forceinline__ float wsum(float x){
#pragma unroll
  for (int o = 32; o; o >>= 1) x += __shfl_xor(x, o, 64);
  return x;
}
__device__ __forceinline__ float geluf(float x){
  return 0.5f * x * (1.0f + erff(x * 0.70710678118654752f));
}
__device__ __forceinline__ float sigmoidf_(float x){
  return 1.0f / (1.0f + __expf(-x));
}

// ---------------- init: x[b,c,h,w] (f32) -> X[b,p,c] (f32) + pos ----------------
__global__ __launch_bounds__(256) void k_init(const float* __restrict__ xin,
                                              const float* __restrict__ pos,
                                              float* __restrict__ X){
  int idx = blockIdx.x * 256 + threadIdx.x;       // over NTOK*512 (exact)
  int c = idx & 511;
  int t = idx >> 9;          // b*784 + p
  int p = t % SEQ_;
  int b = t / SEQ_;
  float v = xin[((long)(b * DIMC + c)) * SEQ_ + p];
  X[idx] = v + pos[p];
}

// ---------------- final: X[b,p,c] -> out[b,c,h,w] f32 ----------------
__global__ __launch_bounds__(256) void k_final(const float* __restrict__ X,
                                               float* __restrict__ out){
  int idx = blockIdx.x * 256 + threadIdx.x;       // over B*DIMC*SEQ (exact)
  int p = idx % SEQ_;
  int t = idx / SEQ_;        // b*512 + c
  int c = t & 511;
  int b = t >> 9;
  out[idx] = X[((long)(b * SEQ_ + p)) * DIMC + c];
}

// ---------------- weight conversion: WQKVG [l][n 0..1559][k 0..511] bf16 (transposed) ----
__global__ __launch_bounds__(256) void k_wconv1(const float* __restrict__ Wq,
                                                const float* __restrict__ Wk,
                                                const float* __restrict__ Wv,
                                                const float* __restrict__ Wg,
                                                bf16_t* __restrict__ Wb){
  int idx = blockIdx.x * 256 + threadIdx.x;   // over 2*1560*512 (6240 blocks, exact)
  int k = idx & 511;
  int t = idx >> 9;
  int n = t % QLD;
  int l = t / QLD;
  float v;
  if (n < 1536){
    int which = n >> 9;
    int nn = n & 511;
    const float* W = (which == 0) ? Wq : ((which == 1) ? Wk : Wv);
    v = W[((long)(l * 512 + k)) * 512 + nn];
  } else {
    v = Wg[((long)(l * 512 + k)) * 24 + (n - 1536)];
  }
  Wb[idx] = __float2bfloat16(v);
}

// ---------------- WO transpose: Wb[l][n][k] = Wo[l][k][n] ----------------
__global__ __launch_bounds__(256) void k_wconv2(const float* __restrict__ Wo,
                                                bf16_t* __restrict__ Wb){
  int idx = blockIdx.x * 256 + threadIdx.x;   // over 2*512*512 (2048 blocks)
  int k = idx & 511;
  int t = idx >> 9;
  int n = t & 511;
  int l = t >> 9;
  Wb[idx] = __float2bfloat16(Wo[((long)(l * 512 + k)) * 512 + n]);
}

// ---------------- plain f32 -> bf16 cast ----------------
__global__ __launch_bounds__(256) void k_cast(const float* __restrict__ src,
                                              bf16_t* __restrict__ dst){
  int idx = blockIdx.x * 256 + threadIdx.x;
  dst[idx] = __float2bfloat16(src[idx]);
}

// ---------------- RMSNorm: f32 in -> bf16 out ----------------
__global__ __launch_bounds__(256) void k_rms(const float* __restrict__ X,
                                             const float* __restrict__ g,
                                             bf16_t* __restrict__ XR){
  int tok = blockIdx.x;
  int tid = threadIdx.x;
  const float* xr = X + (long)tok * DIMC;
  float v0 = xr[tid], v1 = xr[tid + 256];
  float ss = v0 * v0 + v1 * v1;
  ss = wsum(ss);
  __shared__ float red[4];
  if ((tid & 63) == 0) red[tid >> 6] = ss;
  __syncthreads();
  float tot = red[0] + red[1] + red[2] + red[3];
  float r = rsqrtf(tot * (1.0f / DIMC) + EPSF);
  XR[(long)tok * DIMC + tid]       = __float2bfloat16(v0 * r * g[tid]);
  XR[(long)tok * DIMC + tid + 256] = __float2bfloat16(v1 * r * g[tid + 256]);
}

// ---------------- LayerNorm: f32 in -> bf16 out ----------------
__global__ __launch_bounds__(256) void k_ln(const float* __restrict__ X,
                                            const float* __restrict__ g,
                                            const float* __restrict__ bb,
                                            bf16_t* __restrict__ XN){
  int tok = blockIdx.x;
  int tid = threadIdx.x;
  const float* xr = X + (long)tok * DIMC;
  float v0 = xr[tid], v1 = xr[tid + 256];
  float s = v0 + v1;
  float q = v0 * v0 + v1 * v1;
  s = wsum(s); q = wsum(q);
  __shared__ float r1[4], r2[4];
  if ((tid & 63) == 0){ r1[tid >> 6] = s; r2[tid >> 6] = q; }
  __syncthreads();
  float ts = r1[0] + r1[1] + r1[2] + r1[3];
  float tq = r2[0] + r2[1] + r2[2] + r2[3];
  float mean = ts * (1.0f / DIMC);
  float var  = tq * (1.0f / DIMC) - mean * mean;
  float rinv = rsqrtf(var + EPSF);
  XN[(long)tok * DIMC + tid]       = __float2bfloat16((v0 - mean) * rinv * g[tid]       + bb[tid]);
  XN[(long)tok * DIMC + tid + 256] = __float2bfloat16((v1 - mean) * rinv * g[tid + 256] + bb[tid + 256]);
}

// ---------------- bf16 MFMA GEMM (round-5 proven core + XCD-swizzled 1-D grid) ------
// A [M,K] bf16 row-major; B [N,K] bf16 row-major (k-major).
// C[m][ccol+n] = act(sum_k A[m][k]*B[n][k] + bias[n]) + res. 64x64 tile, 4 waves,
// each wave 32x32 via 2x2 mfma_f32_16x16x32_bf16.
template<int OUTBF, int ACT>
__global__ __launch_bounds__(256) void k_mgemm(const bf16_t* __restrict__ A,
                                               const bf16_t* __restrict__ Bm,
                                               float* Cf,
                                               bf16_t* Cb,
                                               const float* __restrict__ bias,
                                               const float* res,
                                               int M, int N, int K, int ldc, int ccol){
  int id = blockIdx.x;
  int xcd = id & 7;
  int j = id >> 3;
  int nt = j / 13;
  int mt = xcd * 13 + (j - nt * 13);
  if (mt >= MT_) return;
  int bm = mt * 64, bn = nt * 64;

  __shared__ bf16_t As[64][40];   // 32 k + 8 pad
  __shared__ bf16_t Bs[64][40];
  int tid = threadIdx.x;
  int w = tid >> 6, lane = tid & 63;
  int wm = (w & 1) * 32, wn = (w >> 1) * 32;
  int quad = lane >> 4, l16 = lane & 15;

  int lrow = tid >> 2, lkc = (tid & 3) * 8;
  bool bok = (bn + lrow) < N;
  const bf16_t* ap = A + (long)(bm + lrow) * K + lkc;
  const bf16_t* bp = Bm + (long)(bok ? bn + lrow : 0) * K + lkc;

  floatx4 acc[2][2];
#pragma unroll
  for (int i = 0; i < 2; i++)
#pragma unroll
    for (int jj = 0; jj < 2; jj++) acc[i][jj] = (floatx4)(0.0f);

  for (int k0 = 0; k0 < K; k0 += 32){
    *(uintx4*)&As[lrow][lkc] = *(const uintx4*)(ap + k0);
    uintx4 bv = *(const uintx4*)(bp + k0);
    if (!bok) bv = (uintx4){0u,0u,0u,0u};
    *(uintx4*)&Bs[lrow][lkc] = bv;
    __syncthreads();
    bf16x8 a0 = *(bf16x8*)&As[wm + l16][quad * 8];
    bf16x8 a1 = *(bf16x8*)&As[wm + 16 + l16][quad * 8];
    bf16x8 b0 = *(bf16x8*)&Bs[wn + l16][quad * 8];
    bf16x8 b1 = *(bf16x8*)&Bs[wn + 16 + l16][quad * 8];
    acc[0][0] = __builtin_amdgcn_mfma_f32_16x16x32_bf16(a0, b0, acc[0][0], 0, 0, 0);
    acc[0][1] = __builtin_amdgcn_mfma_f32_16x16x32_bf16(a0, b1, acc[0][1], 0, 0, 0);
    acc[1][0] = __builtin_amdgcn_mfma_f32_16x16x32_bf16(a1, b0, acc[1][0], 0, 0, 0);
    acc[1][1] = __builtin_amdgcn_mfma_f32_16x16x32_bf16(a1, b1, acc[1][1], 0, 0, 0);
    __syncthreads();
  }
#pragma unroll
  for (int tm = 0; tm < 2; tm++){
#pragma unroll
    for (int tn = 0; tn < 2; tn++){
      int ncol = bn + wn + tn * 16 + l16;
      if (ncol >= N) continue;
#pragma unroll
      for (int reg = 0; reg < 4; reg++){
        long mrow = bm + wm + tm * 16 + quad * 4 + reg;
        float v = acc[tm][tn][reg];
        if (bias) v += bias[ncol];
        if (ACT == 1) v = geluf(v);
        long off = mrow * (long)ldc + ccol + ncol;
        if (res) v += res[off];
        if (OUTBF) Cb[off] = __float2bfloat16(v);
        else       Cf[off] = v;
      }
    }
  }
}

// ---------------- compressed-block mean pooling of K and V (bf16 in, f32 out) ----------
__global__ __launch_bounds__(512) void k_cpool(const bf16_t* __restrict__ qkvg,
                                               float* __restrict__ ck,
                                               float* __restrict__ cv){
  int bj = blockIdx.x;
  int j = bj % NC_;
  int b = bj / NC_;
  int c = threadIdx.x;
  const bf16_t* base = qkvg + ((long)b * SEQ_ + (long)j * CST_) * QLD + c;
  float sk = 0.0f, sv = 0.0f;
  for (int t = 0; t < CBS_; t++){
    sk += __bfloat162float(base[512  + (long)t * QLD]);
    sv += __bfloat162float(base[1024 + (long)t * QLD]);
  }
  ck[bj * DIMC + c] = sk * (1.0f / CBS_);
  cv[bj * DIMC + c] = sv * (1.0f / CBS_);
}

// ---------------- fused NSA attention v3: MFMA QK^T + combined-weight MFMA PV --------
__global__ __launch_bounds__(256) void k_attn(const bf16_t* __restrict__ qkvg,
                                              const float* __restrict__ ck,
                                              const float* __restrict__ cv,
                                              bf16_t* __restrict__ oattn){
  int tid = threadIdx.x;
  int w = tid >> 6, lane = tid & 63;
  int quad = lane >> 4, l16 = lane & 15;
  int i0 = blockIdx.x * TQ_;
  int bh = blockIdx.y;
  int h = bh & 7, b = bh >> 3;
  const float scale = 0.125f;

  __shared__ __align__(16) char smem[78864];
  bf16_t (*Qs)[72]    = (bf16_t(*)[72])(smem);            // 4608 B  (rows 28-31 zero)
  bf16_t (*Ks)[72]    = (bf16_t(*)[72])(smem + 4608);     // 9216 B  (phase C)
  bf16_t (*Vt)[168]   = (bf16_t(*)[168])(smem + 4608);    // 21504 B (phase D, same buf)
  bf16_t (*sbuf)[808] = (bf16_t(*)[808])(smem + 26112);   // 45248 B
  float  (*outc_s)[64] = (float(*)[64])(smem + 71360);    // 7168 B
  int*   sel_s = (int*)(smem + 78528);
  float* cw_s  = (float*)(smem + 78640);
  float* cs_s  = (float*)(smem + 78752);

  const long rowBase = (long)b * SEQ_ * QLD + h * 64;     // + token*QLD + {0,512,1024}

  // ---- Phase A: stage Q tile (28 rows) + zero rows 28-31 ----
  if (tid < 224){
    int q = tid >> 3, seg = tid & 7;
    uintx4 qv = *(const uintx4*)(qkvg + rowBase + (long)(i0 + q) * QLD + seg * 8);
    *(uintx4*)&Qs[q][seg * 8] = qv;
  } else {
    int u = tid - 224;
    int r = 28 + (u >> 3), seg = u & 7;
    *(uintx4*)&Qs[r][seg * 8] = (uintx4){0u, 0u, 0u, 0u};
  }
  __syncthreads();

  // ---- Phase B: compressed branch + gates + top-1 selection ----
  float g1r[7], g2r[7];
  int selr[7];
  {
    const float* CKp = ck + (long)b * NC_ * DIMC + h * 64 + lane;
    const float* CVp = cv + (long)b * NC_ * DIMC + h * 64 + lane;
    float k0 = CKp[0], k1 = CKp[512], k2 = CKp[1024];
    float v0 = CVp[0], v1 = CVp[512], v2 = CVp[1024];
#pragma unroll
    for (int qp = 0; qp < 7; qp++){
      int qg = w * 7 + qp;
      float qd = __bfloat162float(Qs[qg][lane]);
      float s0 = wsum(qd * k0) * scale;
      float s1 = wsum(qd * k1) * scale;
      float s2 = wsum(qd * k2) * scale;
      float m3 = fmaxf(s0, fmaxf(s1, s2));
      float e0 = __expf(s0 - m3), e1 = __expf(s1 - m3), e2 = __expf(s2 - m3);
      float inv = 1.0f / (e0 + e1 + e2);
      const bf16_t* grow = qkvg + (long)(b * SEQ_ + i0 + qg) * QLD + 1536 + h * 3;
      float g0 = sigmoidf_(__bfloat162float(grow[0]));
      g1r[qp] = sigmoidf_(__bfloat162float(grow[1]));
      g2r[qp] = sigmoidf_(__bfloat162float(grow[2]));
      outc_s[qg][lane] = g0 * (e0 * v0 + e1 * v1 + e2 * v2) * inv;
      selr[qp] = (s2 > s0) ? 1 : 0;   // imp1>imp0 <=> p2>p0 <=> s2>s0
      if (lane == 0) sel_s[qg] = selr[qp];
    }
  }

  // hoist Q A-fragments (chunk-invariant)
  bf16x8 a00 = *(bf16x8*)&Qs[l16][quad * 8];
  bf16x8 a01 = *(bf16x8*)&Qs[l16][32 + quad * 8];
  bf16x8 a10 = *(bf16x8*)&Qs[16 + l16][quad * 8];
  bf16x8 a11 = *(bf16x8*)&Qs[16 + l16][32 + quad * 8];

  // ---- Phase C: QK^T via MFMA, exp -> sbuf (14 chunks of 56 keys) ----
  for (int ch = 0; ch < 14; ch++){
    int c0 = ch * 56;
#pragma unroll
    for (int p = 0; p < 2; p++){
      int uu = tid + p * 256;
      int r = uu >> 3, seg = uu & 7;
      int tok = c0 + r; tok = tok > 783 ? 783 : tok;   // rows 56-63 duplicated, discarded
      uintx4 kv = *(const uintx4*)(qkvg + rowBase + (long)tok * QLD + 512 + seg * 8);
      *(uintx4*)&Ks[r][seg * 8] = kv;
    }
    __syncthreads();
    bf16x8 b0 = *(bf16x8*)&Ks[w * 16 + l16][quad * 8];
    bf16x8 b1 = *(bf16x8*)&Ks[w * 16 + l16][32 + quad * 8];
    floatx4 d0 = (floatx4)(0.0f), d1 = (floatx4)(0.0f);
    d0 = __builtin_amdgcn_mfma_f32_16x16x32_bf16(a00, b0, d0, 0, 0, 0);
    d0 = __builtin_amdgcn_mfma_f32_16x16x32_bf16(a01, b1, d0, 0, 0, 0);
    d1 = __builtin_amdgcn_mfma_f32_16x16x32_bf16(a10, b0, d1, 0, 0, 0);
    d1 = __builtin_amdgcn_mfma_f32_16x16x32_bf16(a11, b1, d1, 0, 0, 0);
    int tc = w * 16 + l16;
    if (tc < 56){
      int t = c0 + tc;
#pragma unroll
      for (int reg = 0; reg < 4; reg++){
        sbuf[quad * 4 + reg][t] = __float2bfloat16(__expf(d0[reg] * scale));
        int q2 = 16 + quad * 4 + reg;
        if (q2 < 28) sbuf[q2][t] = __float2bfloat16(__expf(d1[reg] * scale));
      }
    }
    __syncthreads();
  }

  // ---- row sums -> per-row coefficients ----
#pragma unroll
  for (int qp = 0; qp < 7; qp++){
    int q = w * 7 + qp;
    int iq = i0 + q;
    int lo = iq - 195; if (lo < 0) lo = 0;
    int hi = iq + 195; if (hi > 783) hi = 783;
    float sw = 0.0f;
    for (int t = lo + lane; t <= hi; t += 64) sw += __bfloat162float(sbuf[q][t]);
    sw = wsum(sw);
    int slo = selr[qp] * 392;
    float ss = 0.0f;
    for (int t = slo + lane; t < slo + 392; t += 64) ss += __bfloat162float(sbuf[q][t]);
    ss = wsum(ss);
    if (lane == 0){
      cw_s[q] = g2r[qp] / sw;
      cs_s[q] = g1r[qp] / ss;
    }
  }
  __syncthreads();

  // ---- build combined weight matrix W in place (zero cols 784..807) ----
  for (int q = 0; q < 28; q++){
    int iq = i0 + q;
    float cwv = cw_s[q], csv = cs_s[q];
    int sl = sel_s[q];
    for (int c = tid; c < 808; c += 256){
      float wv = 0.0f;
      if (c < 784){
        float e = __bfloat162float(sbuf[q][c]);
        float coef = 0.0f;
        if (c >= iq - 195 && c <= iq + 195) coef += cwv;
        if ((c >= 392 ? 1 : 0) == sl)       coef += csv;
        wv = e * coef;
      }
      sbuf[q][c] = __float2bfloat16(wv);
    }
  }
  __syncthreads();

  // ---- Phase D: out = W · V via MFMA (5 chunks of 160 tokens, V transposed-staged) ----
  floatx4 o0 = (floatx4)(0.0f), o1 = (floatx4)(0.0f);
  for (int ch = 0; ch < 5; ch++){
    int c0 = ch * 160;
#pragma unroll
    for (int p = 0; p < 5; p++){
      int u = tid + p * 256;           // 1280 units exactly
      int seg = u / 160;
      int t = u - seg * 160;
      int tok = c0 + t; tok = tok > 783 ? 783 : tok;   // W cols >=784 are zero
      uintx4 vv = *(const uintx4*)(qkvg + rowBase + (long)tok * QLD + 1024 + seg * 8);
      bf16_t tmp[8]; *(uintx4*)tmp = vv;
#pragma unroll
      for (int jj = 0; jj < 8; jj++) Vt[seg * 8 + jj][t] = tmp[jj];
    }
    __syncthreads();
#pragma unroll
    for (int ks = 0; ks < 5; ks++){
      int kc = c0 + ks * 32;
      bf16x8 av0 = *(bf16x8*)&sbuf[l16][kc + quad * 8];
      bf16x8 av1 = *(bf16x8*)&sbuf[16 + l16][kc + quad * 8];
      bf16x8 bv  = *(bf16x8*)&Vt[w * 16 + l16][ks * 32 + quad * 8];
      o0 = __builtin_amdgcn_mfma_f32_16x16x32_bf16(av0, bv, o0, 0, 0, 0);
      o1 = __builtin_amdgcn_mfma_f32_16x16x32_bf16(av1, bv, o1, 0, 0, 0);
    }
    __syncthreads();
  }

  // ---- epilogue: add compressed branch, write bf16 ----
  int d = w * 16 + l16;
#pragma unroll
  for (int reg = 0; reg < 4; reg++){
    int q = quad * 4 + reg;
    float o = o0[reg] + outc_s[q][d];
    oattn[((long)(b * SEQ_ + i0 + q)) * DIMC + h * 64 + d] = __float2bfloat16(o);
    int q2 = q + 16;
    if (q2 < 28){
      float o2 = o1[reg] + outc_s[q2][d];
      oattn[((long)(b * SEQ_ + i0 + q2)) * DIMC + h * 64 + d] = __float2bfloat16(o2);
    }
  }
}

// ---------------- host launcher ----------------
extern "C" void kernel_launch(void* const* d_in, const int* in_sizes, int n_in,
                              void* d_out, int out_size, void* d_ws, size_t ws_size,
                              hipStream_t stream){
  const float* xin  = (const float*)d_in[0];
  const float* pos  = (const float*)d_in[1];
  const float* angm = (const float*)d_in[2];
  const float* Wq   = (const float*)d_in[3];
  const float* Wk   = (const float*)d_in[4];
  const float* Wv   = (const float*)d_in[5];
  const float* Wo   = (const float*)d_in[6];
  const float* Wg   = (const float*)d_in[7];
  const float* fng  = (const float*)d_in[8];
  const float* fnb  = (const float*)d_in[9];
  const float* fw1  = (const float*)d_in[10];
  const float* fb1  = (const float*)d_in[11];
  const float* fw2  = (const float*)d_in[12];
  const float* fb2  = (const float*)d_in[13];

  // workspace layout: 64.1 MB total (BUFb/H1b share one region — disjoint live ranges)
  char* cw = (char*)d_ws;
  float* X = (float*)cw;             cw += (long)NTOK * 512 * 4;     // 12.85 MB
  bf16_t* XRb = (bf16_t*)cw;         cw += (long)NTOK * 512 * 2;     //  6.42 MB
  bf16_t* OAb = (bf16_t*)cw;         cw += (long)NTOK * 512 * 2;     //  6.42 MB
  bf16_t* SH  = (bf16_t*)cw;         cw += (long)NTOK * FF_ * 2;     // 25.69 MB (BUFb/H1b)
  float* CK = (float*)cw;            cw += (long)B_ * NC_ * DIMC * 4;
  float* CV = (float*)cw;            cw += (long)B_ * NC_ * DIMC * 4;
  bf16_t* Wqkvgb = (bf16_t*)cw;      cw += (long)2 * QLD * 512 * 2;  //  3.19 MB
  bf16_t* WOb    = (bf16_t*)cw;      cw += (long)2 * 512 * 512 * 2;  //  1.05 MB
  bf16_t* FW1b   = (bf16_t*)cw;      cw += (long)2 * FF_ * 512 * 2;  //  4.19 MB
  bf16_t* FW2b   = (bf16_t*)cw;      cw += (long)2 * 512 * FF_ * 2;  //  4.19 MB
  bf16_t* BUFb = SH;   // [NTOK, QLD]  (QKVG output; dies after k_attn)
  bf16_t* H1b  = SH;   // [NTOK, FF_]  (FF1 output; born after k_ln)

  // per-call weight conversion (deterministic, same work every call)
  k_wconv1<<<(2 * QLD * 512) / 256, 256, 0, stream>>>(Wq, Wk, Wv, Wg, Wqkvgb);
  k_wconv2<<<(2 * 512 * 512) / 256, 256, 0, stream>>>(Wo, WOb);
  k_cast<<<(2 * FF_ * 512) / 256, 256, 0, stream>>>(fw1, FW1b);
  k_cast<<<(2 * 512 * FF_) / 256, 256, 0, stream>>>(fw2, FW2b);

  k_init<<<12544, 256, 0, stream>>>(xin, pos, X);

  for (int l = 0; l < 2; l++){
    k_rms<<<NTOK, 256, 0, stream>>>(X, angm + (long)l * DIMC, XRb);

    // fused QKV+G GEMM: [6272,512] x [1560,512]^T -> BUFb [6272,1560] bf16
    k_mgemm<1, 0><<<25 * 104, 256, 0, stream>>>(
        XRb, Wqkvgb + (long)l * QLD * 512, nullptr, BUFb, nullptr, nullptr,
        NTOK, QLD, 512, QLD, 0);

    k_cpool<<<B_ * NC_, 512, 0, stream>>>(BUFb, CK, CV);

    dim3 ga(SEQ_ / TQ_, B_ * HEADS_);
    k_attn<<<ga, 256, 0, stream>>>(BUFb, CK, CV, OAb);

    // Wo GEMM: f32 out + residual into X
    k_mgemm<0, 0><<<8 * 104, 256, 0, stream>>>(
        OAb, WOb + (long)l * 512 * 512, X, nullptr, nullptr, X,
        NTOK, 512, 512, 512, 0);

    k_ln<<<NTOK, 256, 0, stream>>>(X, fng + (long)l * DIMC, fnb + (long)l * DIMC, XRb);

    // FF1 + GELU, bf16 out into H1b
    k_mgemm<1, 1><<<32 * 104, 256, 0, stream>>>(
        XRb, FW1b + (long)l * FF_ * 512, nullptr, H1b, fb1 + (long)l * FF_, nullptr,
        NTOK, FF_, 512, FF_, 0);
    // FF2, f32 out + residual into X
    k_mgemm<0, 0><<<8 * 104, 256, 0, stream>>>(
        H1b, FW2b + (long)l * 512 * FF_, X, nullptr, fb2 + (long)l * DIMC, X,
        NTOK, 512, FF_, 512, 0);
  }

  k_final<<<12544, 256, 0, stream>>>(X, (float*)d_out);
}

// Round 11
// 792.823 us; speedup vs baseline: 5.6793x; 1.0362x over previous
//
#include <hip/hip_runtime.h>
#include <hip/hip_bf16.h>
#include <math.h>

// ---- static config (matches reference) ----
#define B_      8
#define DIMC    512
#define SEQ_    784
#define HEADS_  8
#define DH_     64
#define NTOK    (B_*SEQ_)      // 6272
#define QLD     1560           // q(512) | k(512) | v(512) | gates(24)
#define WIN_    196
#define CBS_    392
#define CST_    196
#define NC_     3
#define EPSF    1e-5f
#define FF_     2048
#define TQ_     28             // queries per block (28*28 = 784)
#define MT_     98             // m-tiles (6272/64)

typedef __hip_bfloat16 bf16_t;
typedef __attribute__((ext_vector_type(8))) short bf16x8;
typedef __attribute__((ext_vector_type(4))) float floatx4;
typedef __attribute__((ext_vector_type(4))) unsigned int uintx4;

// ---------------- helpers ----------------
__device__ __forceinline__ float wsum(float x){
#pragma unroll
  for (int o = 32; o; o >>= 1) x += __shfl_xor(x, o, 64);
  return x;
}
__device__ __forceinline__ float geluf(float x){
  return 0.5f * x * (1.0f + erff(x * 0.70710678118654752f));
}
__device__ __forceinline__ float sigmoidf_(float x){
  return 1.0f / (1.0f + __expf(-x));
}

// ---------------- init: x[b,c,h,w] (f32) -> X[b,p,c] (f32) + pos ----------------
__global__ __launch_bounds__(256) void k_init(const float* __restrict__ xin,
                                              const float* __restrict__ pos,
                                              float* __restrict__ X){
  int idx = blockIdx.x * 256 + threadIdx.x;       // over NTOK*512 (exact)
  int c = idx & 511;
  int t = idx >> 9;          // b*784 + p
  int p = t % SEQ_;
  int b = t / SEQ_;
  float v = xin[((long)(b * DIMC + c)) * SEQ_ + p];
  X[idx] = v + pos[p];
}

// ---------------- final: X[b,p,c] -> out[b,c,h,w] f32 ----------------
__global__ __launch_bounds__(256) void k_final(const float* __restrict__ X,
                                               float* __restrict__ out){
  int idx = blockIdx.x * 256 + threadIdx.x;       // over B*DIMC*SEQ (exact)
  int p = idx % SEQ_;
  int t = idx / SEQ_;        // b*512 + c
  int c = t & 511;
  int b = t >> 9;
  out[idx] = X[((long)(b * SEQ_ + p)) * DIMC + c];
}

// ---------------- weight conversion: WQKVG [l][n 0..1559][k 0..511] bf16 (transposed) ----
__global__ __launch_bounds__(256) void k_wconv1(const float* __restrict__ Wq,
                                                const float* __restrict__ Wk,
                                                const float* __restrict__ Wv,
                                                const float* __restrict__ Wg,
                                                bf16_t* __restrict__ Wb){
  int idx = blockIdx.x * 256 + threadIdx.x;   // over 2*1560*512 (6240 blocks, exact)
  int k = idx & 511;
  int t = idx >> 9;
  int n = t % QLD;
  int l = t / QLD;
  float v;
  if (n < 1536){
    int which = n >> 9;
    int nn = n & 511;
    const float* W = (which == 0) ? Wq : ((which == 1) ? Wk : Wv);
    v = W[((long)(l * 512 + k)) * 512 + nn];
  } else {
    v = Wg[((long)(l * 512 + k)) * 24 + (n - 1536)];
  }
  Wb[idx] = __float2bfloat16(v);
}

// ---------------- WO transpose: Wb[l][n][k] = Wo[l][k][n] ----------------
__global__ __launch_bounds__(256) void k_wconv2(const float* __restrict__ Wo,
                                                bf16_t* __restrict__ Wb){
  int idx = blockIdx.x * 256 + threadIdx.x;   // over 2*512*512 (2048 blocks)
  int k = idx & 511;
  int t = idx >> 9;
  int n = t & 511;
  int l = t >> 9;
  Wb[idx] = __float2bfloat16(Wo[((long)(l * 512 + k)) * 512 + n]);
}

// ---------------- plain f32 -> bf16 cast ----------------
__global__ __launch_bounds__(256) void k_cast(const float* __restrict__ src,
                                              bf16_t* __restrict__ dst){
  int idx = blockIdx.x * 256 + threadIdx.x;
  dst[idx] = __float2bfloat16(src[idx]);
}

// ---------------- RMSNorm: f32 in -> bf16 out ----------------
__global__ __launch_bounds__(256) void k_rms(const float* __restrict__ X,
                                             const float* __restrict__ g,
                                             bf16_t* __restrict__ XR){
  int tok = blockIdx.x;
  int tid = threadIdx.x;
  const float* xr = X + (long)tok * DIMC;
  float v0 = xr[tid], v1 = xr[tid + 256];
  float ss = v0 * v0 + v1 * v1;
  ss = wsum(ss);
  __shared__ float red[4];
  if ((tid & 63) == 0) red[tid >> 6] = ss;
  __syncthreads();
  float tot = red[0] + red[1] + red[2] + red[3];
  float r = rsqrtf(tot * (1.0f / DIMC) + EPSF);
  XR[(long)tok * DIMC + tid]       = __float2bfloat16(v0 * r * g[tid]);
  XR[(long)tok * DIMC + tid + 256] = __float2bfloat16(v1 * r * g[tid + 256]);
}

// ---------------- LayerNorm: f32 in -> bf16 out ----------------
__global__ __launch_bounds__(256) void k_ln(const float* __restrict__ X,
                                            const float* __restrict__ g,
                                            const float* __restrict__ bb,
                                            bf16_t* __restrict__ XN){
  int tok = blockIdx.x;
  int tid = threadIdx.x;
  const float* xr = X + (long)tok * DIMC;
  float v0 = xr[tid], v1 = xr[tid + 256];
  float s = v0 + v1;
  float q = v0 * v0 + v1 * v1;
  s = wsum(s); q = wsum(q);
  __shared__ float r1[4], r2[4];
  if ((tid & 63) == 0){ r1[tid >> 6] = s; r2[tid >> 6] = q; }
  __syncthreads();
  float ts = r1[0] + r1[1] + r1[2] + r1[3];
  float tq = r2[0] + r2[1] + r2[2] + r2[3];
  float mean = ts * (1.0f / DIMC);
  float var  = tq * (1.0f / DIMC) - mean * mean;
  float rinv = rsqrtf(var + EPSF);
  XN[(long)tok * DIMC + tid]       = __float2bfloat16((v0 - mean) * rinv * g[tid]       + bb[tid]);
  XN[(long)tok * DIMC + tid + 256] = __float2bfloat16((v1 - mean) * rinv * g[tid + 256] + bb[tid + 256]);
}

// ---------------- bf16 MFMA GEMM (proven core + XCD-swizzled 1-D grid) ------
template<int OUTBF, int ACT>
__global__ __launch_bounds__(256) void k_mgemm(const bf16_t* __restrict__ A,
                                               const bf16_t* __restrict__ Bm,
                                               float* Cf,
                                               bf16_t* Cb,
                                               const float* __restrict__ bias,
                                               const float* res,
                                               int M, int N, int K, int ldc, int ccol){
  int id = blockIdx.x;
  int xcd = id & 7;
  int j = id >> 3;
  int nt = j / 13;
  int mt = xcd * 13 + (j - nt * 13);
  if (mt >= MT_) return;
  int bm = mt * 64, bn = nt * 64;

  __shared__ bf16_t As[64][40];   // 32 k + 8 pad
  __shared__ bf16_t Bs[64][40];
  int tid = threadIdx.x;
  int w = tid >> 6, lane = tid & 63;
  int wm = (w & 1) * 32, wn = (w >> 1) * 32;
  int quad = lane >> 4, l16 = lane & 15;

  int lrow = tid >> 2, lkc = (tid & 3) * 8;
  bool bok = (bn + lrow) < N;
  const bf16_t* ap = A + (long)(bm + lrow) * K + lkc;
  const bf16_t* bp = Bm + (long)(bok ? bn + lrow : 0) * K + lkc;

  floatx4 acc[2][2];
#pragma unroll
  for (int i = 0; i < 2; i++)
#pragma unroll
    for (int jj = 0; jj < 2; jj++) acc[i][jj] = (floatx4)(0.0f);

  for (int k0 = 0; k0 < K; k0 += 32){
    *(uintx4*)&As[lrow][lkc] = *(const uintx4*)(ap + k0);
    uintx4 bv = *(const uintx4*)(bp + k0);
    if (!bok) bv = (uintx4){0u,0u,0u,0u};
    *(uintx4*)&Bs[lrow][lkc] = bv;
    __syncthreads();
    bf16x8 a0 = *(bf16x8*)&As[wm + l16][quad * 8];
    bf16x8 a1 = *(bf16x8*)&As[wm + 16 + l16][quad * 8];
    bf16x8 b0 = *(bf16x8*)&Bs[wn + l16][quad * 8];
    bf16x8 b1 = *(bf16x8*)&Bs[wn + 16 + l16][quad * 8];
    acc[0][0] = __builtin_amdgcn_mfma_f32_16x16x32_bf16(a0, b0, acc[0][0], 0, 0, 0);
    acc[0][1] = __builtin_amdgcn_mfma_f32_16x16x32_bf16(a0, b1, acc[0][1], 0, 0, 0);
    acc[1][0] = __builtin_amdgcn_mfma_f32_16x16x32_bf16(a1, b0, acc[1][0], 0, 0, 0);
    acc[1][1] = __builtin_amdgcn_mfma_f32_16x16x32_bf16(a1, b1, acc[1][1], 0, 0, 0);
    __syncthreads();
  }
#pragma unroll
  for (int tm = 0; tm < 2; tm++){
#pragma unroll
    for (int tn = 0; tn < 2; tn++){
      int ncol = bn + wn + tn * 16 + l16;
      if (ncol >= N) continue;
#pragma unroll
      for (int reg = 0; reg < 4; reg++){
        long mrow = bm + wm + tm * 16 + quad * 4 + reg;
        float v = acc[tm][tn][reg];
        if (bias) v += bias[ncol];
        if (ACT == 1) v = geluf(v);
        long off = mrow * (long)ldc + ccol + ncol;
        if (res) v += res[off];
        if (OUTBF) Cb[off] = __float2bfloat16(v);
        else       Cf[off] = v;
      }
    }
  }
}

// ---------------- compressed-block mean pooling, vectorized + coalesced -------------
// grid 24 blocks x 512 threads. seg = tid&127 (8-ch segment over K|V 1024 ch),
// rg = tid>>7 (4 row groups). Deterministic 4-way LDS reduce.
__global__ __launch_bounds__(512) void k_cpool(const bf16_t* __restrict__ qkvg,
                                               float* __restrict__ ck,
                                               float* __restrict__ cv){
  int bj = blockIdx.x;
  int j = bj % NC_;
  int b = bj / NC_;
  int tid = threadIdx.x;
  int seg = tid & 127;
  int rg  = tid >> 7;
  __shared__ float part[4][1024];
  const bf16_t* base = qkvg + ((long)b * SEQ_ + (long)j * CST_) * QLD + 512;
  float acc[8] = {0.f,0.f,0.f,0.f,0.f,0.f,0.f,0.f};
  for (int r = rg; r < CBS_; r += 4){
    uintx4 v = *(const uintx4*)(base + (long)r * QLD + seg * 8);
    bf16_t tmp[8]; *(uintx4*)tmp = v;
#pragma unroll
    for (int q = 0; q < 8; q++) acc[q] += __bfloat162float(tmp[q]);
  }
#pragma unroll
  for (int q = 0; q < 8; q++) part[rg][seg * 8 + q] = acc[q];
  __syncthreads();
  for (int c = tid; c < 1024; c += 512){
    float s = (part[0][c] + part[1][c]) + (part[2][c] + part[3][c]);
    s *= (1.0f / CBS_);
    if (c < 512) ck[bj * DIMC + c] = s;
    else         cv[bj * DIMC + (c - 512)] = s;
  }
}

// ---------------- fused NSA attention v4: pipelined MFMA QK^T + combined-weight PV ---
__global__ __launch_bounds__(256) void k_attn(const bf16_t* __restrict__ qkvg,
                                              const float* __restrict__ ck,
                                              const float* __restrict__ cv,
                                              bf16_t* __restrict__ oattn){
  int tid = threadIdx.x;
  int w = tid >> 6, lane = tid & 63;
  int quad = lane >> 4, l16 = lane & 15;
  int i0 = blockIdx.x * TQ_;
  int bh = blockIdx.y;
  int h = bh & 7, b = bh >> 3;
  const float scale = 0.125f;

  __shared__ __align__(16) char smem[78864];
  bf16_t (*Qs)[72]    = (bf16_t(*)[72])(smem);            // 4608 B  (rows 28-31 zero)
  bf16_t (*Ks0)[72]   = (bf16_t(*)[72])(smem + 4608);     // 9216 B  (phase C dbuf 0)
  bf16_t (*Ks1)[72]   = (bf16_t(*)[72])(smem + 13824);    // 9216 B  (phase C dbuf 1)
  bf16_t (*Vt)[168]   = (bf16_t(*)[168])(smem + 4608);    // 21504 B (phase D, same region)
  bf16_t (*sbuf)[808] = (bf16_t(*)[808])(smem + 26112);   // 45248 B
  float  (*outc_s)[64] = (float(*)[64])(smem + 71360);    // 7168 B
  int*   sel_s = (int*)(smem + 78528);
  float* cw_s  = (float*)(smem + 78640);
  float* cs_s  = (float*)(smem + 78752);

  const long rowBase = (long)b * SEQ_ * QLD + h * 64;     // + token*QLD + {0,512,1024}

  // ---- Phase A: stage Q tile (28 rows) + zero rows 28-31 ----
  if (tid < 224){
    int q = tid >> 3, seg = tid & 7;
    uintx4 qv = *(const uintx4*)(qkvg + rowBase + (long)(i0 + q) * QLD + seg * 8);
    *(uintx4*)&Qs[q][seg * 8] = qv;
  } else {
    int u = tid - 224;
    int r = 28 + (u >> 3), seg = u & 7;
    *(uintx4*)&Qs[r][seg * 8] = (uintx4){0u, 0u, 0u, 0u};
  }
  __syncthreads();

  // ---- Phase B: compressed branch + gates + top-1 selection ----
  float g1r[7], g2r[7];
  int selr[7];
  {
    const float* CKp = ck + (long)b * NC_ * DIMC + h * 64 + lane;
    const float* CVp = cv + (long)b * NC_ * DIMC + h * 64 + lane;
    float k0 = CKp[0], k1 = CKp[512], k2 = CKp[1024];
    float v0 = CVp[0], v1 = CVp[512], v2 = CVp[1024];
#pragma unroll
    for (int qp = 0; qp < 7; qp++){
      int qg = w * 7 + qp;
      float qd = __bfloat162float(Qs[qg][lane]);
      float s0 = wsum(qd * k0) * scale;
      float s1 = wsum(qd * k1) * scale;
      float s2 = wsum(qd * k2) * scale;
      float m3 = fmaxf(s0, fmaxf(s1, s2));
      float e0 = __expf(s0 - m3), e1 = __expf(s1 - m3), e2 = __expf(s2 - m3);
      float inv = 1.0f / (e0 + e1 + e2);
      const bf16_t* grow = qkvg + (long)(b * SEQ_ + i0 + qg) * QLD + 1536 + h * 3;
      float g0 = sigmoidf_(__bfloat162float(grow[0]));
      g1r[qp] = sigmoidf_(__bfloat162float(grow[1]));
      g2r[qp] = sigmoidf_(__bfloat162float(grow[2]));
      outc_s[qg][lane] = g0 * (e0 * v0 + e1 * v1 + e2 * v2) * inv;
      selr[qp] = (s2 > s0) ? 1 : 0;   // imp1>imp0 <=> p2>p0 <=> s2>s0
      if (lane == 0) sel_s[qg] = selr[qp];
    }
  }

  // hoist Q A-fragments (chunk-invariant)
  bf16x8 a00 = *(bf16x8*)&Qs[l16][quad * 8];
  bf16x8 a01 = *(bf16x8*)&Qs[l16][32 + quad * 8];
  bf16x8 a10 = *(bf16x8*)&Qs[16 + l16][quad * 8];
  bf16x8 a11 = *(bf16x8*)&Qs[16 + l16][32 + quad * 8];

  // ---- Phase C: QK^T via MFMA, exp -> sbuf (14 chunks of 56 keys) ----
  // Double-buffered Ks + register prefetch: one barrier per chunk, global latency
  // hidden under the previous chunk's MFMA/epilogue.
  int r0i = tid >> 3, s0i = tid & 7;
  int r1i = (tid + 256) >> 3, s1i = (tid + 256) & 7;
  uintx4 kreg0, kreg1;
  {
    int t0 = r0i; if (t0 > 783) t0 = 783;
    int t1 = r1i; if (t1 > 783) t1 = 783;
    kreg0 = *(const uintx4*)(qkvg + rowBase + (long)t0 * QLD + 512 + s0i * 8);
    kreg1 = *(const uintx4*)(qkvg + rowBase + (long)t1 * QLD + 512 + s1i * 8);
  }
  for (int ch = 0; ch < 14; ch++){
    bf16_t (*Kb)[72] = (ch & 1) ? Ks1 : Ks0;
    *(uintx4*)&Kb[r0i][s0i * 8] = kreg0;
    *(uintx4*)&Kb[r1i][s1i * 8] = kreg1;
    if (ch + 1 < 14){
      int c0n = (ch + 1) * 56;
      int t0 = c0n + r0i; if (t0 > 783) t0 = 783;
      int t1 = c0n + r1i; if (t1 > 783) t1 = 783;
      kreg0 = *(const uintx4*)(qkvg + rowBase + (long)t0 * QLD + 512 + s0i * 8);
      kreg1 = *(const uintx4*)(qkvg + rowBase + (long)t1 * QLD + 512 + s1i * 8);
    }
    __syncthreads();
    bf16x8 b0 = *(bf16x8*)&Kb[w * 16 + l16][quad * 8];
    bf16x8 b1 = *(bf16x8*)&Kb[w * 16 + l16][32 + quad * 8];
    floatx4 d0 = (floatx4)(0.0f), d1 = (floatx4)(0.0f);
    d0 = __builtin_amdgcn_mfma_f32_16x16x32_bf16(a00, b0, d0, 0, 0, 0);
    d0 = __builtin_amdgcn_mfma_f32_16x16x32_bf16(a01, b1, d0, 0, 0, 0);
    d1 = __builtin_amdgcn_mfma_f32_16x16x32_bf16(a10, b0, d1, 0, 0, 0);
    d1 = __builtin_amdgcn_mfma_f32_16x16x32_bf16(a11, b1, d1, 0, 0, 0);
    int tc = w * 16 + l16;
    if (tc < 56){
      int t = ch * 56 + tc;
#pragma unroll
      for (int reg = 0; reg < 4; reg++){
        sbuf[quad * 4 + reg][t] = __float2bfloat16(__expf(d0[reg] * scale));
        int q2 = 16 + quad * 4 + reg;
        if (q2 < 28) sbuf[q2][t] = __float2bfloat16(__expf(d1[reg] * scale));
      }
    }
  }
  __syncthreads();   // sbuf fully written before row sums

  // ---- prefetch V chunk 0 (hidden under row-sums + build-W) ----
  uintx4 vreg[5];
  int vseg[5], vt[5];
#pragma unroll
  for (int p = 0; p < 5; p++){
    int u = tid + p * 256;
    vseg[p] = u / 160;
    vt[p] = u - vseg[p] * 160;
    int tok = vt[p]; if (tok > 783) tok = 783;
    vreg[p] = *(const uintx4*)(qkvg + rowBase + (long)tok * QLD + 1024 + vseg[p] * 8);
  }

  // ---- row sums -> per-row coefficients ----
#pragma unroll
  for (int qp = 0; qp < 7; qp++){
    int q = w * 7 + qp;
    int iq = i0 + q;
    int lo = iq - 195; if (lo < 0) lo = 0;
    int hi = iq + 195; if (hi > 783) hi = 783;
    float sw = 0.0f;
    for (int t = lo + lane; t <= hi; t += 64) sw += __bfloat162float(sbuf[q][t]);
    sw = wsum(sw);
    int slo = selr[qp] * 392;
    float ss = 0.0f;
    for (int t = slo + lane; t < slo + 392; t += 64) ss += __bfloat162float(sbuf[q][t]);
    ss = wsum(ss);
    if (lane == 0){
      cw_s[q] = g2r[qp] / sw;
      cs_s[q] = g1r[qp] / ss;
    }
  }
  __syncthreads();

  // ---- build combined weight matrix W in place (zero cols 784..807) ----
  for (int q = 0; q < 28; q++){
    int iq = i0 + q;
    float cwv = cw_s[q], csv = cs_s[q];
    int sl = sel_s[q];
    for (int c = tid; c < 808; c += 256){
      float wv = 0.0f;
      if (c < 784){
        float e = __bfloat162float(sbuf[q][c]);
        float coef = 0.0f;
        if (c >= iq - 195 && c <= iq + 195) coef += cwv;
        if ((c >= 392 ? 1 : 0) == sl)       coef += csv;
        wv = e * coef;
      }
      sbuf[q][c] = __float2bfloat16(wv);
    }
  }

  // ---- Phase D: out = W · V via MFMA (5 chunks of 160 tokens, reg-prefetched V) ----
  floatx4 o0 = (floatx4)(0.0f), o1 = (floatx4)(0.0f);
  for (int ch = 0; ch < 5; ch++){
    __syncthreads();   // Vt free (first iter: also covers build-W completion)
#pragma unroll
    for (int p = 0; p < 5; p++){
      bf16_t tmp[8]; *(uintx4*)tmp = vreg[p];
#pragma unroll
      for (int jj = 0; jj < 8; jj++) Vt[vseg[p] * 8 + jj][vt[p]] = tmp[jj];
    }
    if (ch + 1 < 5){
      int c0n = (ch + 1) * 160;
#pragma unroll
      for (int p = 0; p < 5; p++){
        int tok = c0n + vt[p]; if (tok > 783) tok = 783;
        vreg[p] = *(const uintx4*)(qkvg + rowBase + (long)tok * QLD + 1024 + vseg[p] * 8);
      }
    }
    __syncthreads();
    int c0 = ch * 160;
#pragma unroll
    for (int ks = 0; ks < 5; ks++){
      int kc = c0 + ks * 32;
      bf16x8 av0 = *(bf16x8*)&sbuf[l16][kc + quad * 8];
      bf16x8 av1 = *(bf16x8*)&sbuf[16 + l16][kc + quad * 8];
      bf16x8 bv  = *(bf16x8*)&Vt[w * 16 + l16][ks * 32 + quad * 8];
      o0 = __builtin_amdgcn_mfma_f32_16x16x32_bf16(av0, bv, o0, 0, 0, 0);
      o1 = __builtin_amdgcn_mfma_f32_16x16x32_bf16(av1, bv, o1, 0, 0, 0);
    }
  }

  // ---- epilogue: add compressed branch, write bf16 ----
  int d = w * 16 + l16;
#pragma unroll
  for (int reg = 0; reg < 4; reg++){
    int q = quad * 4 + reg;
    float o = o0[reg] + outc_s[q][d];
    oattn[((long)(b * SEQ_ + i0 + q)) * DIMC + h * 64 + d] = __float2bfloat16(o);
    int q2 = q + 16;
    if (q2 < 28){
      float o2 = o1[reg] + outc_s[q2][d];
      oattn[((long)(b * SEQ_ + i0 + q2)) * DIMC + h * 64 + d] = __float2bfloat16(o2);
    }
  }
}

// ---------------- host launcher ----------------
extern "C" void kernel_launch(void* const* d_in, const int* in_sizes, int n_in,
                              void* d_out, int out_size, void* d_ws, size_t ws_size,
                              hipStream_t stream){
  const float* xin  = (const float*)d_in[0];
  const float* pos  = (const float*)d_in[1];
  const float* angm = (const float*)d_in[2];
  const float* Wq   = (const float*)d_in[3];
  const float* Wk   = (const float*)d_in[4];
  const float* Wv   = (const float*)d_in[5];
  const float* Wo   = (const float*)d_in[6];
  const float* Wg   = (const float*)d_in[7];
  const float* fng  = (const float*)d_in[8];
  const float* fnb  = (const float*)d_in[9];
  const float* fw1  = (const float*)d_in[10];
  const float* fb1  = (const float*)d_in[11];
  const float* fw2  = (const float*)d_in[12];
  const float* fb2  = (const float*)d_in[13];

  // workspace layout: 64.1 MB total (BUFb/H1b share one region — disjoint live ranges)
  char* cw = (char*)d_ws;
  float* X = (float*)cw;             cw += (long)NTOK * 512 * 4;     // 12.85 MB
  bf16_t* XRb = (bf16_t*)cw;         cw += (long)NTOK * 512 * 2;     //  6.42 MB
  bf16_t* OAb = (bf16_t*)cw;         cw += (long)NTOK * 512 * 2;     //  6.42 MB
  bf16_t* SH  = (bf16_t*)cw;         cw += (long)NTOK * FF_ * 2;     // 25.69 MB (BUFb/H1b)
  float* CK = (float*)cw;            cw += (long)B_ * NC_ * DIMC * 4;
  float* CV = (float*)cw;            cw += (long)B_ * NC_ * DIMC * 4;
  bf16_t* Wqkvgb = (bf16_t*)cw;      cw += (long)2 * QLD * 512 * 2;  //  3.19 MB
  bf16_t* WOb    = (bf16_t*)cw;      cw += (long)2 * 512 * 512 * 2;  //  1.05 MB
  bf16_t* FW1b   = (bf16_t*)cw;      cw += (long)2 * FF_ * 512 * 2;  //  4.19 MB
  bf16_t* FW2b   = (bf16_t*)cw;      cw += (long)2 * 512 * FF_ * 2;  //  4.19 MB
  bf16_t* BUFb = SH;   // [NTOK, QLD]  (QKVG output; dies after k_attn)
  bf16_t* H1b  = SH;   // [NTOK, FF_]  (FF1 output; born after k_ln)

  // per-call weight conversion (deterministic, same work every call)
  k_wconv1<<<(2 * QLD * 512) / 256, 256, 0, stream>>>(Wq, Wk, Wv, Wg, Wqkvgb);
  k_wconv2<<<(2 * 512 * 512) / 256, 256, 0, stream>>>(Wo, WOb);
  k_cast<<<(2 * FF_ * 512) / 256, 256, 0, stream>>>(fw1, FW1b);
  k_cast<<<(2 * 512 * FF_) / 256, 256, 0, stream>>>(fw2, FW2b);

  k_init<<<12544, 256, 0, stream>>>(xin, pos, X);

  for (int l = 0; l < 2; l++){
    k_rms<<<NTOK, 256, 0, stream>>>(X, angm + (long)l * DIMC, XRb);

    // fused QKV+G GEMM: [6272,512] x [1560,512]^T -> BUFb [6272,1560] bf16
    k_mgemm<1, 0><<<25 * 104, 256, 0, stream>>>(
        XRb, Wqkvgb + (long)l * QLD * 512, nullptr, BUFb, nullptr, nullptr,
        NTOK, QLD, 512, QLD, 0);

    k_cpool<<<B_ * NC_, 512, 0, stream>>>(BUFb, CK, CV);

    dim3 ga(SEQ_ / TQ_, B_ * HEADS_);
    k_attn<<<ga, 256, 0, stream>>>(BUFb, CK, CV, OAb);

    // Wo GEMM: f32 out + residual into X
    k_mgemm<0, 0><<<8 * 104, 256, 0, stream>>>(
        OAb, WOb + (long)l * 512 * 512, X, nullptr, nullptr, X,
        NTOK, 512, 512, 512, 0);

    k_ln<<<NTOK, 256, 0, stream>>>(X, fng + (long)l * DIMC, fnb + (long)l * DIMC, XRb);

    // FF1 + GELU, bf16 out into H1b
    k_mgemm<1, 1><<<32 * 104, 256, 0, stream>>>(
        XRb, FW1b + (long)l * FF_ * 512, nullptr, H1b, fb1 + (long)l * FF_, nullptr,
        NTOK, FF_, 512, FF_, 0);
    // FF2, f32 out + residual into X
    k_mgemm<0, 0><<<8 * 104, 256, 0, stream>>>(
        H1b, FW2b + (long)l * 512 * FF_, X, nullptr, fb2 + (long)l * DIMC, X,
        NTOK, 512, FF_, 512, 0);
  }

  k_final<<<12544, 256, 0, stream>>>(X, (float*)d_out);
}

// Round 12
// 762.314 us; speedup vs baseline: 5.9066x; 1.0400x over previous
//
#include <hip/hip_runtime.h>
#include <hip/hip_bf16.h>
#include <math.h>

// ---- static config (matches reference) ----
#define B_      8
#define DIMC    512
#define SEQ_    784
#define HEADS_  8
#define DH_     64
#define NTOK    (B_*SEQ_)      // 6272
#define QLD     1560           // q(512) | k(512) | v(512) | gates(24)
#define WIN_    196
#define CBS_    392
#define CST_    196
#define NC_     3
#define EPSF    1e-5f
#define FF_     2048
#define TQ_     28             // queries per block (28*28 = 784)
#define MT_     98             // m-tiles (6272/64)

typedef __hip_bfloat16 bf16_t;
typedef __attribute__((ext_vector_type(8))) short bf16x8;
typedef __attribute__((ext_vector_type(4))) float floatx4;
typedef __attribute__((ext_vector_type(4))) unsigned int uintx4;

// ---------------- helpers ----------------
__device__ __forceinline__ float wsum(float x){
#pragma unroll
  for (int o = 32; o; o >>= 1) x += __shfl_xor(x, o, 64);
  return x;
}
__device__ __forceinline__ float geluf(float x){
  return 0.5f * x * (1.0f + erff(x * 0.70710678118654752f));
}
__device__ __forceinline__ float sigmoidf_(float x){
  return 1.0f / (1.0f + __expf(-x));
}

// ---------------- init: x[b,c,h,w] (f32) -> X[b,p,c] (f32) + pos ----------------
__global__ __launch_bounds__(256) void k_init(const float* __restrict__ xin,
                                              const float* __restrict__ pos,
                                              float* __restrict__ X){
  int idx = blockIdx.x * 256 + threadIdx.x;       // over NTOK*512 (exact)
  int c = idx & 511;
  int t = idx >> 9;          // b*784 + p
  int p = t % SEQ_;
  int b = t / SEQ_;
  float v = xin[((long)(b * DIMC + c)) * SEQ_ + p];
  X[idx] = v + pos[p];
}

// ---------------- final: X[b,p,c] -> out[b,c,h,w] f32 ----------------
__global__ __launch_bounds__(256) void k_final(const float* __restrict__ X,
                                               float* __restrict__ out){
  int idx = blockIdx.x * 256 + threadIdx.x;       // over B*DIMC*SEQ (exact)
  int p = idx % SEQ_;
  int t = idx / SEQ_;        // b*512 + c
  int c = t & 511;
  int b = t >> 9;
  out[idx] = X[((long)(b * SEQ_ + p)) * DIMC + c];
}

// ---------------- weight conversion: WQKVG [l][n 0..1559][k 0..511] bf16 (transposed) ----
__global__ __launch_bounds__(256) void k_wconv1(const float* __restrict__ Wq,
                                                const float* __restrict__ Wk,
                                                const float* __restrict__ Wv,
                                                const float* __restrict__ Wg,
                                                bf16_t* __restrict__ Wb){
  int idx = blockIdx.x * 256 + threadIdx.x;   // over 2*1560*512 (6240 blocks, exact)
  int k = idx & 511;
  int t = idx >> 9;
  int n = t % QLD;
  int l = t / QLD;
  float v;
  if (n < 1536){
    int which = n >> 9;
    int nn = n & 511;
    const float* W = (which == 0) ? Wq : ((which == 1) ? Wk : Wv);
    v = W[((long)(l * 512 + k)) * 512 + nn];
  } else {
    v = Wg[((long)(l * 512 + k)) * 24 + (n - 1536)];
  }
  Wb[idx] = __float2bfloat16(v);
}

// ---------------- WO transpose: Wb[l][n][k] = Wo[l][k][n] ----------------
__global__ __launch_bounds__(256) void k_wconv2(const float* __restrict__ Wo,
                                                bf16_t* __restrict__ Wb){
  int idx = blockIdx.x * 256 + threadIdx.x;   // over 2*512*512 (2048 blocks)
  int k = idx & 511;
  int t = idx >> 9;
  int n = t & 511;
  int l = t >> 9;
  Wb[idx] = __float2bfloat16(Wo[((long)(l * 512 + k)) * 512 + n]);
}

// ---------------- plain f32 -> bf16 cast ----------------
__global__ __launch_bounds__(256) void k_cast(const float* __restrict__ src,
                                              bf16_t* __restrict__ dst){
  int idx = blockIdx.x * 256 + threadIdx.x;
  dst[idx] = __float2bfloat16(src[idx]);
}

// ---------------- RMSNorm: f32 in -> bf16 out ----------------
__global__ __launch_bounds__(256) void k_rms(const float* __restrict__ X,
                                             const float* __restrict__ g,
                                             bf16_t* __restrict__ XR){
  int tok = blockIdx.x;
  int tid = threadIdx.x;
  const float* xr = X + (long)tok * DIMC;
  float v0 = xr[tid], v1 = xr[tid + 256];
  float ss = v0 * v0 + v1 * v1;
  ss = wsum(ss);
  __shared__ float red[4];
  if ((tid & 63) == 0) red[tid >> 6] = ss;
  __syncthreads();
  float tot = red[0] + red[1] + red[2] + red[3];
  float r = rsqrtf(tot * (1.0f / DIMC) + EPSF);
  XR[(long)tok * DIMC + tid]       = __float2bfloat16(v0 * r * g[tid]);
  XR[(long)tok * DIMC + tid + 256] = __float2bfloat16(v1 * r * g[tid + 256]);
}

// ---------------- LayerNorm: f32 in -> bf16 out ----------------
__global__ __launch_bounds__(256) void k_ln(const float* __restrict__ X,
                                            const float* __restrict__ g,
                                            const float* __restrict__ bb,
                                            bf16_t* __restrict__ XN){
  int tok = blockIdx.x;
  int tid = threadIdx.x;
  const float* xr = X + (long)tok * DIMC;
  float v0 = xr[tid], v1 = xr[tid + 256];
  float s = v0 + v1;
  float q = v0 * v0 + v1 * v1;
  s = wsum(s); q = wsum(q);
  __shared__ float r1[4], r2[4];
  if ((tid & 63) == 0){ r1[tid >> 6] = s; r2[tid >> 6] = q; }
  __syncthreads();
  float ts = r1[0] + r1[1] + r1[2] + r1[3];
  float tq = r2[0] + r2[1] + r2[2] + r2[3];
  float mean = ts * (1.0f / DIMC);
  float var  = tq * (1.0f / DIMC) - mean * mean;
  float rinv = rsqrtf(var + EPSF);
  XN[(long)tok * DIMC + tid]       = __float2bfloat16((v0 - mean) * rinv * g[tid]       + bb[tid]);
  XN[(long)tok * DIMC + tid + 256] = __float2bfloat16((v1 - mean) * rinv * g[tid + 256] + bb[tid + 256]);
}

// ---------------- bf16 MFMA GEMM: dbuf LDS + register prefetch, 1 barrier/chunk -----
template<int OUTBF, int ACT>
__global__ __launch_bounds__(256) void k_mgemm(const bf16_t* __restrict__ A,
                                               const bf16_t* __restrict__ Bm,
                                               float* Cf,
                                               bf16_t* Cb,
                                               const float* __restrict__ bias,
                                               const float* res,
                                               int M, int N, int K, int ldc, int ccol){
  int id = blockIdx.x;
  int xcd = id & 7;
  int j = id >> 3;
  int nt = j / 13;
  int mt = xcd * 13 + (j - nt * 13);
  if (mt >= MT_) return;
  int bm = mt * 64, bn = nt * 64;

  __shared__ bf16_t As[2][64][40];   // 32 k + 8 pad, double-buffered
  __shared__ bf16_t Bs[2][64][40];
  int tid = threadIdx.x;
  int w = tid >> 6, lane = tid & 63;
  int wm = (w & 1) * 32, wn = (w >> 1) * 32;
  int quad = lane >> 4, l16 = lane & 15;

  int lrow = tid >> 2, lkc = (tid & 3) * 8;
  bool bok = (bn + lrow) < N;
  const bf16_t* ap = A + (long)(bm + lrow) * K + lkc;
  const bf16_t* bp = Bm + (long)(bok ? bn + lrow : 0) * K + lkc;

  floatx4 acc[2][2];
#pragma unroll
  for (int i = 0; i < 2; i++)
#pragma unroll
    for (int jj = 0; jj < 2; jj++) acc[i][jj] = (floatx4)(0.0f);

  uintx4 areg = *(const uintx4*)ap;
  uintx4 breg = *(const uintx4*)bp;
  if (!bok) breg = (uintx4){0u,0u,0u,0u};

  int nch = K >> 5;
  for (int ch = 0; ch < nch; ch++){
    int buf = ch & 1;
    *(uintx4*)&As[buf][lrow][lkc] = areg;
    *(uintx4*)&Bs[buf][lrow][lkc] = breg;
    if (ch + 1 < nch){
      areg = *(const uintx4*)(ap + (ch + 1) * 32);
      breg = *(const uintx4*)(bp + (ch + 1) * 32);
      if (!bok) breg = (uintx4){0u,0u,0u,0u};
    }
    __syncthreads();
    bf16x8 a0 = *(bf16x8*)&As[buf][wm + l16][quad * 8];
    bf16x8 a1 = *(bf16x8*)&As[buf][wm + 16 + l16][quad * 8];
    bf16x8 b0 = *(bf16x8*)&Bs[buf][wn + l16][quad * 8];
    bf16x8 b1 = *(bf16x8*)&Bs[buf][wn + 16 + l16][quad * 8];
    acc[0][0] = __builtin_amdgcn_mfma_f32_16x16x32_bf16(a0, b0, acc[0][0], 0, 0, 0);
    acc[0][1] = __builtin_amdgcn_mfma_f32_16x16x32_bf16(a0, b1, acc[0][1], 0, 0, 0);
    acc[1][0] = __builtin_amdgcn_mfma_f32_16x16x32_bf16(a1, b0, acc[1][0], 0, 0, 0);
    acc[1][1] = __builtin_amdgcn_mfma_f32_16x16x32_bf16(a1, b1, acc[1][1], 0, 0, 0);
    // no trailing barrier: next iter writes the other buffer; re-write of this
    // buffer happens only after the next barrier, which is after all reads here.
  }
#pragma unroll
  for (int tm = 0; tm < 2; tm++){
#pragma unroll
    for (int tn = 0; tn < 2; tn++){
      int ncol = bn + wn + tn * 16 + l16;
      if (ncol >= N) continue;
#pragma unroll
      for (int reg = 0; reg < 4; reg++){
        long mrow = bm + wm + tm * 16 + quad * 4 + reg;
        float v = acc[tm][tn][reg];
        if (bias) v += bias[ncol];
        if (ACT == 1) v = geluf(v);
        long off = mrow * (long)ldc + ccol + ncol;
        if (res) v += res[off];
        if (OUTBF) Cb[off] = __float2bfloat16(v);
        else       Cf[off] = v;
      }
    }
  }
}

// ---------------- compressed-block mean pooling, vectorized + coalesced -------------
__global__ __launch_bounds__(512) void k_cpool(const bf16_t* __restrict__ qkvg,
                                               float* __restrict__ ck,
                                               float* __restrict__ cv){
  int bj = blockIdx.x;
  int j = bj % NC_;
  int b = bj / NC_;
  int tid = threadIdx.x;
  int seg = tid & 127;
  int rg  = tid >> 7;
  __shared__ float part[4][1024];
  const bf16_t* base = qkvg + ((long)b * SEQ_ + (long)j * CST_) * QLD + 512;
  float acc[8] = {0.f,0.f,0.f,0.f,0.f,0.f,0.f,0.f};
  for (int r = rg; r < CBS_; r += 4){
    uintx4 v = *(const uintx4*)(base + (long)r * QLD + seg * 8);
    bf16_t tmp[8]; *(uintx4*)tmp = v;
#pragma unroll
    for (int q = 0; q < 8; q++) acc[q] += __bfloat162float(tmp[q]);
  }
#pragma unroll
  for (int q = 0; q < 8; q++) part[rg][seg * 8 + q] = acc[q];
  __syncthreads();
  for (int c = tid; c < 1024; c += 512){
    float s = (part[0][c] + part[1][c]) + (part[2][c] + part[3][c]);
    s *= (1.0f / CBS_);
    if (c < 512) ck[bj * DIMC + c] = s;
    else         cv[bj * DIMC + (c - 512)] = s;
  }
}

// ---------------- fused NSA attention v5: XCD-swizzled grid + pipelined MFMA --------
// 1-D grid 1792 = 8 xcd x 8 bh x 28 tiles: each XCD owns 8 (b,h) pairs -> K/V
// working set 1.6 MB fits per-XCD L2 (4 MB); prefetches return at L2 latency.
__global__ __launch_bounds__(256) void k_attn(const bf16_t* __restrict__ qkvg,
                                              const float* __restrict__ ck,
                                              const float* __restrict__ cv,
                                              bf16_t* __restrict__ oattn){
  int tid = threadIdx.x;
  int w = tid >> 6, lane = tid & 63;
  int quad = lane >> 4, l16 = lane & 15;
  int id = blockIdx.x;
  int xcd = id & 7;
  int j = id >> 3;               // 0..223
  int bh = xcd * 8 + (j / 28);   // all 28 tiles of a bh on one XCD
  int i0 = (j % 28) * TQ_;
  int h = bh & 7, b = bh >> 3;
  const float scale = 0.125f;

  __shared__ __align__(16) char smem[78864];
  bf16_t (*Qs)[72]    = (bf16_t(*)[72])(smem);            // 4608 B  (rows 28-31 zero)
  bf16_t (*Ks0)[72]   = (bf16_t(*)[72])(smem + 4608);     // 9216 B  (phase C dbuf 0)
  bf16_t (*Ks1)[72]   = (bf16_t(*)[72])(smem + 13824);    // 9216 B  (phase C dbuf 1)
  bf16_t (*Vt)[168]   = (bf16_t(*)[168])(smem + 4608);    // 21504 B (phase D, same region)
  bf16_t (*sbuf)[808] = (bf16_t(*)[808])(smem + 26112);   // 45248 B
  float  (*outc_s)[64] = (float(*)[64])(smem + 71360);    // 7168 B
  int*   sel_s = (int*)(smem + 78528);
  float* cw_s  = (float*)(smem + 78640);
  float* cs_s  = (float*)(smem + 78752);

  const long rowBase = (long)b * SEQ_ * QLD + h * 64;     // + token*QLD + {0,512,1024}

  // ---- Phase A: stage Q tile (28 rows) + zero rows 28-31 ----
  if (tid < 224){
    int q = tid >> 3, seg = tid & 7;
    uintx4 qv = *(const uintx4*)(qkvg + rowBase + (long)(i0 + q) * QLD + seg * 8);
    *(uintx4*)&Qs[q][seg * 8] = qv;
  } else {
    int u = tid - 224;
    int r = 28 + (u >> 3), seg = u & 7;
    *(uintx4*)&Qs[r][seg * 8] = (uintx4){0u, 0u, 0u, 0u};
  }
  __syncthreads();

  // ---- Phase B: compressed branch + gates + top-1 selection ----
  float g1r[7], g2r[7];
  int selr[7];
  {
    const float* CKp = ck + (long)b * NC_ * DIMC + h * 64 + lane;
    const float* CVp = cv + (long)b * NC_ * DIMC + h * 64 + lane;
    float k0 = CKp[0], k1 = CKp[512], k2 = CKp[1024];
    float v0 = CVp[0], v1 = CVp[512], v2 = CVp[1024];
#pragma unroll
    for (int qp = 0; qp < 7; qp++){
      int qg = w * 7 + qp;
      float qd = __bfloat162float(Qs[qg][lane]);
      float s0 = wsum(qd * k0) * scale;
      float s1 = wsum(qd * k1) * scale;
      float s2 = wsum(qd * k2) * scale;
      float m3 = fmaxf(s0, fmaxf(s1, s2));
      float e0 = __expf(s0 - m3), e1 = __expf(s1 - m3), e2 = __expf(s2 - m3);
      float inv = 1.0f / (e0 + e1 + e2);
      const bf16_t* grow = qkvg + (long)(b * SEQ_ + i0 + qg) * QLD + 1536 + h * 3;
      float g0 = sigmoidf_(__bfloat162float(grow[0]));
      g1r[qp] = sigmoidf_(__bfloat162float(grow[1]));
      g2r[qp] = sigmoidf_(__bfloat162float(grow[2]));
      outc_s[qg][lane] = g0 * (e0 * v0 + e1 * v1 + e2 * v2) * inv;
      selr[qp] = (s2 > s0) ? 1 : 0;   // imp1>imp0 <=> p2>p0 <=> s2>s0
      if (lane == 0) sel_s[qg] = selr[qp];
    }
  }

  // hoist Q A-fragments (chunk-invariant)
  bf16x8 a00 = *(bf16x8*)&Qs[l16][quad * 8];
  bf16x8 a01 = *(bf16x8*)&Qs[l16][32 + quad * 8];
  bf16x8 a10 = *(bf16x8*)&Qs[16 + l16][quad * 8];
  bf16x8 a11 = *(bf16x8*)&Qs[16 + l16][32 + quad * 8];

  // ---- Phase C: QK^T via MFMA, exp -> sbuf (14 chunks of 56 keys, dbuf+prefetch) ----
  int r0i = tid >> 3, s0i = tid & 7;
  int r1i = (tid + 256) >> 3, s1i = (tid + 256) & 7;
  uintx4 kreg0, kreg1;
  {
    int t0 = r0i; if (t0 > 783) t0 = 783;
    int t1 = r1i; if (t1 > 783) t1 = 783;
    kreg0 = *(const uintx4*)(qkvg + rowBase + (long)t0 * QLD + 512 + s0i * 8);
    kreg1 = *(const uintx4*)(qkvg + rowBase + (long)t1 * QLD + 512 + s1i * 8);
  }
  for (int ch = 0; ch < 14; ch++){
    bf16_t (*Kb)[72] = (ch & 1) ? Ks1 : Ks0;
    *(uintx4*)&Kb[r0i][s0i * 8] = kreg0;
    *(uintx4*)&Kb[r1i][s1i * 8] = kreg1;
    if (ch + 1 < 14){
      int c0n = (ch + 1) * 56;
      int t0 = c0n + r0i; if (t0 > 783) t0 = 783;
      int t1 = c0n + r1i; if (t1 > 783) t1 = 783;
      kreg0 = *(const uintx4*)(qkvg + rowBase + (long)t0 * QLD + 512 + s0i * 8);
      kreg1 = *(const uintx4*)(qkvg + rowBase + (long)t1 * QLD + 512 + s1i * 8);
    }
    __syncthreads();
    bf16x8 b0 = *(bf16x8*)&Kb[w * 16 + l16][quad * 8];
    bf16x8 b1 = *(bf16x8*)&Kb[w * 16 + l16][32 + quad * 8];
    floatx4 d0 = (floatx4)(0.0f), d1 = (floatx4)(0.0f);
    d0 = __builtin_amdgcn_mfma_f32_16x16x32_bf16(a00, b0, d0, 0, 0, 0);
    d0 = __builtin_amdgcn_mfma_f32_16x16x32_bf16(a01, b1, d0, 0, 0, 0);
    d1 = __builtin_amdgcn_mfma_f32_16x16x32_bf16(a10, b0, d1, 0, 0, 0);
    d1 = __builtin_amdgcn_mfma_f32_16x16x32_bf16(a11, b1, d1, 0, 0, 0);
    int tc = w * 16 + l16;
    if (tc < 56){
      int t = ch * 56 + tc;
#pragma unroll
      for (int reg = 0; reg < 4; reg++){
        sbuf[quad * 4 + reg][t] = __float2bfloat16(__expf(d0[reg] * scale));
        int q2 = 16 + quad * 4 + reg;
        if (q2 < 28) sbuf[q2][t] = __float2bfloat16(__expf(d1[reg] * scale));
      }
    }
  }
  __syncthreads();   // sbuf fully written before row sums

  // ---- prefetch V chunk 0 (hidden under row-sums + build-W) ----
  uintx4 vreg[5];
  int vseg[5], vt[5];
#pragma unroll
  for (int p = 0; p < 5; p++){
    int u = tid + p * 256;
    vseg[p] = u / 160;
    vt[p] = u - vseg[p] * 160;
    int tok = vt[p]; if (tok > 783) tok = 783;
    vreg[p] = *(const uintx4*)(qkvg + rowBase + (long)tok * QLD + 1024 + vseg[p] * 8);
  }

  // ---- row sums -> per-row coefficients ----
#pragma unroll
  for (int qp = 0; qp < 7; qp++){
    int q = w * 7 + qp;
    int iq = i0 + q;
    int lo = iq - 195; if (lo < 0) lo = 0;
    int hi = iq + 195; if (hi > 783) hi = 783;
    float sw = 0.0f;
    for (int t = lo + lane; t <= hi; t += 64) sw += __bfloat162float(sbuf[q][t]);
    sw = wsum(sw);
    int slo = selr[qp] * 392;
    float ss = 0.0f;
    for (int t = slo + lane; t < slo + 392; t += 64) ss += __bfloat162float(sbuf[q][t]);
    ss = wsum(ss);
    if (lane == 0){
      cw_s[q] = g2r[qp] / sw;
      cs_s[q] = g1r[qp] / ss;
    }
  }
  __syncthreads();

  // ---- build combined weight matrix W in place (zero cols 784..807) ----
  for (int q = 0; q < 28; q++){
    int iq = i0 + q;
    float cwv = cw_s[q], csv = cs_s[q];
    int sl = sel_s[q];
    for (int c = tid; c < 808; c += 256){
      float wv = 0.0f;
      if (c < 784){
        float e = __bfloat162float(sbuf[q][c]);
        float coef = 0.0f;
        if (c >= iq - 195 && c <= iq + 195) coef += cwv;
        if ((c >= 392 ? 1 : 0) == sl)       coef += csv;
        wv = e * coef;
      }
      sbuf[q][c] = __float2bfloat16(wv);
    }
  }

  // ---- Phase D: out = W · V via MFMA (5 chunks of 160 tokens, reg-prefetched V) ----
  floatx4 o0 = (floatx4)(0.0f), o1 = (floatx4)(0.0f);
  for (int ch = 0; ch < 5; ch++){
    __syncthreads();   // Vt free (first iter: also covers build-W completion)
#pragma unroll
    for (int p = 0; p < 5; p++){
      bf16_t tmp[8]; *(uintx4*)tmp = vreg[p];
#pragma unroll
      for (int jj = 0; jj < 8; jj++) Vt[vseg[p] * 8 + jj][vt[p]] = tmp[jj];
    }
    if (ch + 1 < 5){
      int c0n = (ch + 1) * 160;
#pragma unroll
      for (int p = 0; p < 5; p++){
        int tok = c0n + vt[p]; if (tok > 783) tok = 783;
        vreg[p] = *(const uintx4*)(qkvg + rowBase + (long)tok * QLD + 1024 + vseg[p] * 8);
      }
    }
    __syncthreads();
    int c0 = ch * 160;
#pragma unroll
    for (int ks = 0; ks < 5; ks++){
      int kc = c0 + ks * 32;
      bf16x8 av0 = *(bf16x8*)&sbuf[l16][kc + quad * 8];
      bf16x8 av1 = *(bf16x8*)&sbuf[16 + l16][kc + quad * 8];
      bf16x8 bv  = *(bf16x8*)&Vt[w * 16 + l16][ks * 32 + quad * 8];
      o0 = __builtin_amdgcn_mfma_f32_16x16x32_bf16(av0, bv, o0, 0, 0, 0);
      o1 = __builtin_amdgcn_mfma_f32_16x16x32_bf16(av1, bv, o1, 0, 0, 0);
    }
  }

  // ---- epilogue: add compressed branch, write bf16 ----
  int d = w * 16 + l16;
#pragma unroll
  for (int reg = 0; reg < 4; reg++){
    int q = quad * 4 + reg;
    float o = o0[reg] + outc_s[q][d];
    oattn[((long)(b * SEQ_ + i0 + q)) * DIMC + h * 64 + d] = __float2bfloat16(o);
    int q2 = q + 16;
    if (q2 < 28){
      float o2 = o1[reg] + outc_s[q2][d];
      oattn[((long)(b * SEQ_ + i0 + q2)) * DIMC + h * 64 + d] = __float2bfloat16(o2);
    }
  }
}

// ---------------- host launcher ----------------
extern "C" void kernel_launch(void* const* d_in, const int* in_sizes, int n_in,
                              void* d_out, int out_size, void* d_ws, size_t ws_size,
                              hipStream_t stream){
  const float* xin  = (const float*)d_in[0];
  const float* pos  = (const float*)d_in[1];
  const float* angm = (const float*)d_in[2];
  const float* Wq   = (const float*)d_in[3];
  const float* Wk   = (const float*)d_in[4];
  const float* Wv   = (const float*)d_in[5];
  const float* Wo   = (const float*)d_in[6];
  const float* Wg   = (const float*)d_in[7];
  const float* fng  = (const float*)d_in[8];
  const float* fnb  = (const float*)d_in[9];
  const float* fw1  = (const float*)d_in[10];
  const float* fb1  = (const float*)d_in[11];
  const float* fw2  = (const float*)d_in[12];
  const float* fb2  = (const float*)d_in[13];

  // workspace layout: 64.1 MB total (BUFb/H1b share one region — disjoint live ranges)
  char* cw = (char*)d_ws;
  float* X = (float*)cw;             cw += (long)NTOK * 512 * 4;     // 12.85 MB
  bf16_t* XRb = (bf16_t*)cw;         cw += (long)NTOK * 512 * 2;     //  6.42 MB
  bf16_t* OAb = (bf16_t*)cw;         cw += (long)NTOK * 512 * 2;     //  6.42 MB
  bf16_t* SH  = (bf16_t*)cw;         cw += (long)NTOK * FF_ * 2;     // 25.69 MB (BUFb/H1b)
  float* CK = (float*)cw;            cw += (long)B_ * NC_ * DIMC * 4;
  float* CV = (float*)cw;            cw += (long)B_ * NC_ * DIMC * 4;
  bf16_t* Wqkvgb = (bf16_t*)cw;      cw += (long)2 * QLD * 512 * 2;  //  3.19 MB
  bf16_t* WOb    = (bf16_t*)cw;      cw += (long)2 * 512 * 512 * 2;  //  1.05 MB
  bf16_t* FW1b   = (bf16_t*)cw;      cw += (long)2 * FF_ * 512 * 2;  //  4.19 MB
  bf16_t* FW2b   = (bf16_t*)cw;      cw += (long)2 * 512 * FF_ * 2;  //  4.19 MB
  bf16_t* BUFb = SH;   // [NTOK, QLD]  (QKVG output; dies after k_attn)
  bf16_t* H1b  = SH;   // [NTOK, FF_]  (FF1 output; born after k_ln)

  // per-call weight conversion (deterministic, same work every call)
  k_wconv1<<<(2 * QLD * 512) / 256, 256, 0, stream>>>(Wq, Wk, Wv, Wg, Wqkvgb);
  k_wconv2<<<(2 * 512 * 512) / 256, 256, 0, stream>>>(Wo, WOb);
  k_cast<<<(2 * FF_ * 512) / 256, 256, 0, stream>>>(fw1, FW1b);
  k_cast<<<(2 * 512 * FF_) / 256, 256, 0, stream>>>(fw2, FW2b);

  k_init<<<12544, 256, 0, stream>>>(xin, pos, X);

  for (int l = 0; l < 2; l++){
    k_rms<<<NTOK, 256, 0, stream>>>(X, angm + (long)l * DIMC, XRb);

    // fused QKV+G GEMM: [6272,512] x [1560,512]^T -> BUFb [6272,1560] bf16
    k_mgemm<1, 0><<<25 * 104, 256, 0, stream>>>(
        XRb, Wqkvgb + (long)l * QLD * 512, nullptr, BUFb, nullptr, nullptr,
        NTOK, QLD, 512, QLD, 0);

    k_cpool<<<B_ * NC_, 512, 0, stream>>>(BUFb, CK, CV);

    k_attn<<<8 * 8 * 28, 256, 0, stream>>>(BUFb, CK, CV, OAb);

    // Wo GEMM: f32 out + residual into X
    k_mgemm<0, 0><<<8 * 104, 256, 0, stream>>>(
        OAb, WOb + (long)l * 512 * 512, X, nullptr, nullptr, X,
        NTOK, 512, 512, 512, 0);

    k_ln<<<NTOK, 256, 0, stream>>>(X, fng + (long)l * DIMC, fnb + (long)l * DIMC, XRb);

    // FF1 + GELU, bf16 out into H1b
    k_mgemm<1, 1><<<32 * 104, 256, 0, stream>>>(
        XRb, FW1b + (long)l * FF_ * 512, nullptr, H1b, fb1 + (long)l * FF_, nullptr,
        NTOK, FF_, 512, FF_, 0);
    // FF2, f32 out + residual into X
    k_mgemm<0, 0><<<8 * 104, 256, 0, stream>>>(
        H1b, FW2b + (long)l * 512 * FF_, X, nullptr, fb2 + (long)l * DIMC, X,
        NTOK, 512, FF_, 512, 0);
  }

  k_final<<<12544, 256, 0, stream>>>(X, (float*)d_out);
}